// Round 4
// baseline (418.394 us; speedup 1.0000x reference)
//
#include <hip/hip_runtime.h>
#include <hip/hip_bf16.h>

typedef __hip_bfloat16 bf16;
typedef __attribute__((ext_vector_type(8))) short s8v;   // 8 bf16 = 4 VGPRs
typedef __attribute__((ext_vector_type(4))) short s4v;   // 4 bf16 = 8 bytes
typedef __attribute__((ext_vector_type(4))) float f4v;

#define NPIX 4096
#define CDIM 256
#define MN_ELEMS (1 << 20)        // CDIM * NPIX
#define QKVSTR (320L * NPIX)      // qkv per-slot stride (elems)
#define QKTSTR (64L * NPIX)       // qkt per-slot stride (elems)

#if __has_builtin(__builtin_amdgcn_exp2f)
#define EXP2F(x) __builtin_amdgcn_exp2f(x)
#else
#define EXP2F(x) exp2f(x)
#endif

// ---- async global->LDS, 16B per lane (dest = wave-uniform base + lane*16) ---
typedef __attribute__((address_space(1))) const unsigned int g_u32;
typedef __attribute__((address_space(3))) unsigned int l_u32;
__device__ __forceinline__ void glds16(const void* g, void* l) {
  __builtin_amdgcn_global_load_lds((g_u32*)g, (l_u32*)l, 16, 0, 0);
}

// ---- 8-element loaders -> bf16x8 (s8v) --------------------------------------
__device__ inline s8v ld8(const bf16* p) { return *(const s8v*)p; }
__device__ inline s8v ld8(const float* p) {
  float4 f0 = *(const float4*)p;
  float4 f1 = *(const float4*)(p + 4);
  s8v r; bf16* e = (bf16*)&r;
  e[0] = __float2bfloat16(f0.x); e[1] = __float2bfloat16(f0.y);
  e[2] = __float2bfloat16(f0.z); e[3] = __float2bfloat16(f0.w);
  e[4] = __float2bfloat16(f1.x); e[5] = __float2bfloat16(f1.y);
  e[6] = __float2bfloat16(f1.z); e[7] = __float2bfloat16(f1.w);
  return r;
}

// ---------------------------------------------------------------------------
// Barrier-free fused flash attention.
// out[c][n] = sum_m V[c][m] exp(S[n][m]) / lsum[n],  S = q.k (q pre-scaled
// by log2e in proj_k, exp2 used here).
// qkt: [slot][4096][64] bf16 (q at d0..31, k at d32..63).
// Vg:  [c][m] m-contig at slot stride QKVSTR.  out: [slot][256][4096].
// Decomposition: block = (n-tile 64) x (c-block CB); 4 waves = wr(c-half) x
// wc(m-half).  Each wave computes S^T = mfma(K,Q) for ALL n x its m-half,
// exp2s it, and writes P into its PRIVATE LDS slab laid out in PV B-frag
// order ([st][b][oct][l15][16B]) -> writes and reads are both linear,
// conflict-free, and need NO __syncthreads (wave-local RAW via lgkmcnt).
// PV A-frags (V) and S-phase K-frags come straight from global (L2-hot);
// K is register-double-buffered (prefetch i+1 under PV(i)), V(i) issued at
// iter top hides under the S phase.  Main loop: ZERO barriers.
// Epilogue: cross-wc acc sum via LDS (reuses slabs) + rowsum combine.
// grid (64, 256/CB, nslots), 256 threads.  LDS: 32KB slabs + 512B sums.
// ---------------------------------------------------------------------------
#define ATTN_HALF(I, KFC, KFN)                                                \
  {                                                                           \
    s8v vfr[NC][2];                                                           \
    _Pragma("unroll") for (int cst = 0; cst < NC; ++cst)                      \
      _Pragma("unroll") for (int b = 0; b < 2; ++b)                           \
        vfr[cst][b] = *(const s8v*)(vp + (long)cst * 65536 + (long)(I) * 128 + b * 32); \
    _Pragma("unroll") for (int st = 0; st < 4; ++st) {                        \
      f4v sa[4];                                                              \
      __builtin_amdgcn_s_setprio(1);                                          \
      _Pragma("unroll") for (int nt = 0; nt < 4; ++nt) {                      \
        f4v zz = (f4v){0.f, 0.f, 0.f, 0.f};                                   \
        sa[nt] = __builtin_amdgcn_mfma_f32_16x16x32_bf16(KFC[nt], qf[st], zz, 0, 0, 0); \
      }                                                                       \
      __builtin_amdgcn_s_setprio(0);                                          \
      _Pragma("unroll") for (int nt = 0; nt < 4; ++nt) {                      \
        s4v pk; bf16* pe = (bf16*)&pk;                                        \
        float rsum = 0.f;                                                     \
        _Pragma("unroll") for (int r = 0; r < 4; ++r) {                       \
          float e = EXP2F(sa[nt][r]);                                         \
          rsum += e; pe[r] = __float2bfloat16(e);                             \
        }                                                                     \
        rs[st] += rsum;                                                       \
        *(s4v*)(slab + ((st * 2 + (nt >> 1)) * 4 + ((nt & 1) * 2 + (oct >> 1))) * 256 \
                + l15 * 16 + (oct & 1) * 8) = pk;                             \
      }                                                                       \
    }                                                                         \
    { const int inx = ((I) + 1) & 31;                                         \
      _Pragma("unroll") for (int nt = 0; nt < 4; ++nt)                        \
        KFN[nt] = *(const s8v*)(kp + (long)inx * 8192 + nt * 1024); }         \
    _Pragma("unroll") for (int b = 0; b < 2; ++b) {                           \
      s8v pf[4];                                                              \
      _Pragma("unroll") for (int st = 0; st < 4; ++st)                        \
        pf[st] = *(const s8v*)(slab + ((st * 2 + b) * 4 + oct) * 256 + l15 * 16); \
      __builtin_amdgcn_s_setprio(1);                                          \
      _Pragma("unroll") for (int cst = 0; cst < NC; ++cst)                    \
        _Pragma("unroll") for (int st = 0; st < 4; ++st)                      \
          acc[cst][st] = __builtin_amdgcn_mfma_f32_16x16x32_bf16(vfr[cst][b], pf[st], acc[cst][st], 0, 0, 0); \
      __builtin_amdgcn_s_setprio(0);                                          \
    }                                                                         \
  }

template<int CB>
__global__ __launch_bounds__(256) void fattn_k(
    const bf16* __restrict__ qkt, const bf16* __restrict__ Vg,
    bf16* __restrict__ out)
{
  constexpr int NC = CB / 32;          // c-subtiles per wave
  __shared__ __align__(16) bf16 p_s[4][4096];   // 8KB private slab per wave
  __shared__ float sums[2][64];

  const int tid = threadIdx.x;
  const int z = blockIdx.z;
  const int w = tid >> 6, lane = tid & 63;
  const int l15 = lane & 15, oct = lane >> 4;
  const int wr = w >> 1, wc = w & 1;
  const int n0 = blockIdx.x * 64;
  const int c0 = blockIdx.y * CB + wr * (CB / 2);
  const bf16* qk = qkt + (long)z * QKTSTR;
  const bf16* Vz = Vg + (long)z * QKVSTR;
  char* slab = (char*)&p_s[w][0];

  // Q fragments: all 64 n-rows of this block, d 0..31 (pre-scaled by log2e)
  s8v qf[4];
  #pragma unroll
  for (int st = 0; st < 4; ++st)
    qf[st] = *(const s8v*)(qk + (long)(n0 + st * 16 + l15) * 64 + oct * 8);

  // K: row m = i*128 + wc*64 + nt*16 + l15, d 32+oct*8  (direct global)
  const bf16* kp = qk + (long)(wc * 64 + l15) * 64 + 32 + oct * 8;
  // V: row c0 + cst*16 + l15, col i*128 + wc*64 + b*32 + oct*8
  const bf16* vp = Vz + (long)(c0 + l15) * 4096 + wc * 64 + oct * 8;

  f4v acc[NC][4];
  #pragma unroll
  for (int i = 0; i < NC; ++i)
    #pragma unroll
    for (int j = 0; j < 4; ++j) acc[i][j] = (f4v){0.f, 0.f, 0.f, 0.f};
  float rs[4] = {0.f, 0.f, 0.f, 0.f};

  s8v kfA[4], kfB[4];
  #pragma unroll
  for (int nt = 0; nt < 4; ++nt)
    kfA[nt] = *(const s8v*)(kp + nt * 1024);

  for (int ii = 0; ii < 16; ++ii) {
    ATTN_HALF(2 * ii,     kfA, kfB)
    ATTN_HALF(2 * ii + 1, kfB, kfA)
  }

  // ---- rowsum: reduce across octs; combine wc halves via LDS --------------
  #pragma unroll
  for (int st = 0; st < 4; ++st) {
    rs[st] += __shfl_xor(rs[st], 16);
    rs[st] += __shfl_xor(rs[st], 32);
  }
  if (wr == 0 && lane < 16) {
    #pragma unroll
    for (int st = 0; st < 4; ++st) sums[wc][st * 16 + l15] = rs[st];
  }
  __syncthreads();

  // ---- cross-wc accumulator sum (reuses slab memory) ----------------------
  float* red = (float*)&p_s[0][0];
  if (wc == 1) {
    #pragma unroll
    for (int cst = 0; cst < NC; ++cst)
      #pragma unroll
      for (int st = 0; st < 4; ++st)
        *(f4v*)&red[((wr * NC + cst) * 4 + st) * 256 + l15 * 16 + oct * 4] = acc[cst][st];
  }
  __syncthreads();
  if (wc == 0) {
    float rinv[4];
    #pragma unroll
    for (int st = 0; st < 4; ++st)
      rinv[st] = 1.f / (sums[0][st * 16 + l15] + sums[1][st * 16 + l15]);
    bf16* op = out + (long)z * ((long)CDIM * NPIX);
    #pragma unroll
    for (int cst = 0; cst < NC; ++cst)
      #pragma unroll
      for (int st = 0; st < 4; ++st) {
        f4v o = acc[cst][st] +
                *(const f4v*)&red[((wr * NC + cst) * 4 + st) * 256 + l15 * 16 + oct * 4];
        const int gn = n0 + st * 16 + l15;
        const int gc = c0 + cst * 16 + oct * 4;
        #pragma unroll
        for (int r = 0; r < 4; ++r)
          op[(long)(gc + r) * NPIX + gn] = __float2bfloat16(o[r] * rinv[st]);
      }
  }
}

// ---------------------------------------------------------------------------
// m97-class GEMM, BK=64 per barrier, batched split-K: z = slot*nsplit + slice.
// A: [M][K] k-contig (+slot*abat).  B: [N][K] k-contig (+slot*bbat).
// Cp: bf16 partials at z*M*N.  Tile 128x128, 4 waves (2x2).  (conv path only)
// ---------------------------------------------------------------------------
__global__ __launch_bounds__(256) void gemm128(
    const bf16* __restrict__ A, const bf16* __restrict__ Bm,
    bf16* __restrict__ Cp, int N, int K, int nchunk, int nsplit,
    long abat, long bbat)
{
  __shared__ bf16 a_s0[128 * 32], a_s1[128 * 32];
  __shared__ bf16 b_s0[128 * 32], b_s1[128 * 32];
  const int tid = threadIdx.x;
  const int z = blockIdx.z;
  const int bb = z / nsplit, ks = z - bb * nsplit;
  A  += bb * abat;
  Bm += bb * bbat;
  const int w = tid >> 6, lane = tid & 63;
  const int l15 = lane & 15, oct = lane >> 4;
  const int wr = w >> 1, wc = w & 1;
  const int m0 = blockIdx.y * 128, n0 = blockIdx.x * 128;
  const int kc0 = ks * nchunk, kc1 = kc0 + nchunk;

  const int srow = lane >> 2, skoff = (lane & 3) * 8;
  const long aRow0 = (long)(m0 + (w << 4) + srow) * K;
  const long aRow1 = (long)(m0 + ((w + 4) << 4) + srow) * K;
  const long bRow0 = (long)(n0 + (w << 4) + srow) * K;
  const long bRow1 = (long)(n0 + ((w + 4) << 4) + srow) * K;
  const int ldsOff0 = (w) * 512, ldsOff1 = (w + 4) * 512;

  f4v acc[4][4];
  #pragma unroll
  for (int i = 0; i < 4; ++i)
    #pragma unroll
    for (int j = 0; j < 4; ++j) acc[i][j] = (f4v){0.f, 0.f, 0.f, 0.f};

  for (int kc = kc0; kc < kc1; ++kc) {
    const int kb0 = kc * 64 + skoff;
    const int kb1 = kb0 + 32;
    glds16(A + aRow0 + kb0, a_s0 + ldsOff0);
    glds16(A + aRow1 + kb0, a_s0 + ldsOff1);
    glds16(A + aRow0 + kb1, a_s1 + ldsOff0);
    glds16(A + aRow1 + kb1, a_s1 + ldsOff1);
    glds16(Bm + bRow0 + kb0, b_s0 + ldsOff0);
    glds16(Bm + bRow1 + kb0, b_s0 + ldsOff1);
    glds16(Bm + bRow0 + kb1, b_s1 + ldsOff0);
    glds16(Bm + bRow1 + kb1, b_s1 + ldsOff1);
    __syncthreads();
    #pragma unroll
    for (int h = 0; h < 2; ++h) {
      const bf16* as = h ? a_s1 : a_s0;
      const bf16* bs = h ? b_s1 : b_s0;
      s8v af[4], bfv[4];
      #pragma unroll
      for (int st = 0; st < 4; ++st)
        af[st] = *(const s8v*)(as + (wr * 64 + st * 16 + l15) * 32 + oct * 8);
      #pragma unroll
      for (int nt = 0; nt < 4; ++nt)
        bfv[nt] = *(const s8v*)(bs + (wc * 64 + nt * 16 + l15) * 32 + oct * 8);
      #pragma unroll
      for (int st = 0; st < 4; ++st)
        #pragma unroll
        for (int nt = 0; nt < 4; ++nt)
          acc[st][nt] = __builtin_amdgcn_mfma_f32_16x16x32_bf16(af[st], bfv[nt], acc[st][nt], 0, 0, 0);
    }
    __syncthreads();
  }

  bf16* Cz = Cp + (long)z * ((long)gridDim.y * 128) * N;
  #pragma unroll
  for (int st = 0; st < 4; ++st) {
    const int gm = m0 + wr * 64 + st * 16 + oct * 4;
    #pragma unroll
    for (int nt = 0; nt < 4; ++nt) {
      const int gn = n0 + wc * 64 + nt * 16 + l15;
      #pragma unroll
      for (int r = 0; r < 4; ++r)
        Cz[(long)(gm + r) * N + gn] = __float2bfloat16(acc[st][nt][r]);
    }
  }
}

// ---------------------------------------------------------------------------
// Projection GEMM. z = slot; stage = z>>1 selects (A,bias,B) vs (A2,bias2,B2);
// batch = z&1 offsets B by bbat. QKT=1: rows gm<64 -> qkt transposed, with the
// q rows (gm<32) pre-scaled by log2(e) so fattn can use raw v_exp_f32.
// ---------------------------------------------------------------------------
template<int QKT, typename TBe>
__global__ __launch_bounds__(256) void proj_k(
    const float* __restrict__ A, const float* __restrict__ A2,
    const TBe* __restrict__ B1, const TBe* __restrict__ B2,
    const float* __restrict__ bias, const float* __restrict__ bias2,
    bf16* __restrict__ Cm, bf16* __restrict__ qkt,
    int M, int N, int K, long bbat, long cbat, int nchunk)
{
  __shared__ bf16 a_s[64][40];
  __shared__ bf16 b_s[64][40];
  const int tid = threadIdx.x;
  const int z = blockIdx.z, stage = z >> 1, bat = z & 1;
  const float* Au = stage ? A2 : A;
  const float* biasu = stage ? bias2 : bias;
  const TBe* Bm = (stage ? B2 : B1) + bat * bbat;
  Cm += z * cbat;
  if (QKT) qkt += z * QKTSTR;
  const int m0 = blockIdx.y * 64, n0 = blockIdx.x * 64;
  const int w = tid >> 6, lane = tid & 63;
  const int l15 = lane & 15, oct = lane >> 4;

  f4v acc[4];
  #pragma unroll
  for (int i = 0; i < 4; ++i) acc[i] = (f4v){0.f, 0.f, 0.f, 0.f};

  const int a_i0 = tid >> 2, a_i1 = (tid & 3) * 8;
  const int b_i0 = tid >> 3, b_i1 = (tid & 7) * 8;

  s8v pa, pb;
  auto ldA = [&](int kc, s8v& d) {
    if (m0 + a_i0 < M) d = ld8(Au + (long)(m0 + a_i0) * K + kc * 32 + a_i1);
    else d = (s8v){0,0,0,0,0,0,0,0};
  };
  auto ldB = [&](int kc, s8v& d) {
    d = ld8(Bm + (long)(kc * 32 + b_i0) * N + n0 + b_i1);
  };

  ldA(0, pa); ldB(0, pb);
  for (int kc = 0; kc < nchunk; ++kc) {
    *(s8v*)&a_s[a_i0][a_i1] = pa;
    {
      const bf16* e = (const bf16*)&pb;
      #pragma unroll
      for (int j = 0; j < 8; ++j) b_s[b_i1 + j][b_i0] = e[j];
    }
    __syncthreads();
    if (kc + 1 < nchunk) { ldA(kc + 1, pa); ldB(kc + 1, pb); }
    s8v af = *(const s8v*)&a_s[w * 16 + l15][oct * 8];
    #pragma unroll
    for (int nt = 0; nt < 4; ++nt) {
      s8v bfr = *(const s8v*)&b_s[nt * 16 + l15][oct * 8];
      acc[nt] = __builtin_amdgcn_mfma_f32_16x16x32_bf16(af, bfr, acc[nt], 0, 0, 0);
    }
    __syncthreads();
  }
  const int gm_base = m0 + w * 16 + oct * 4;
  #pragma unroll
  for (int nt = 0; nt < 4; ++nt) {
    const int gn = n0 + nt * 16 + l15;
    #pragma unroll
    for (int r = 0; r < 4; ++r) {
      int gm = gm_base + r;
      if (gm < M) {
        float vv = acc[nt][r] + biasu[gm];
        if (QKT && gm < 64) {
          float vv2 = (gm < 32) ? vv * 1.44269504f : vv;   // q *= log2(e)
          qkt[(long)gn * 64 + gm] = __float2bfloat16(vv2);
        } else {
          Cm[(long)gm * N + gn] = __float2bfloat16(vv);
        }
      }
    }
  }
}

// ---- split-K reducer + bias (conv), bf16 partials, 8 elems/thread ----------
__global__ __launch_bounds__(256) void reduce_bias_k(
    const bf16* __restrict__ part, const float* __restrict__ bias,
    bf16* __restrict__ out, int nsplit)
{
  const int g8 = (blockIdx.x * 256 + threadIdx.x) * 8;
  const int b = g8 >> 20, i = g8 & (MN_ELEMS - 1);
  const bf16* p0 = part + (long)b * nsplit * MN_ELEMS + i;
  float s[8];
  { s8v v = *(const s8v*)p0; const bf16* e = (const bf16*)&v;
    #pragma unroll
    for (int j = 0; j < 8; ++j) s[j] = __bfloat162float(e[j]); }
  for (int p = 1; p < nsplit; ++p) {
    s8v v = *(const s8v*)(p0 + (long)p * MN_ELEMS); const bf16* e = (const bf16*)&v;
    #pragma unroll
    for (int j = 0; j < 8; ++j) s[j] += __bfloat162float(e[j]);
  }
  float bv = bias[i >> 12];
  s8v o; bf16* eo = (bf16*)&o;
  #pragma unroll
  for (int j = 0; j < 8; ++j) eo[j] = __float2bfloat16(s[j] + bv);
  *(s8v*)(out + g8) = o;
}

// ---- concat q/k(/v) weights+biases into fp32 [M][256] + [M] -----------------
__global__ __launch_bounds__(256) void cat_k(
    const float* __restrict__ wq, const float* __restrict__ bq,
    const float* __restrict__ wk, const float* __restrict__ bk,
    const float* __restrict__ wv, const float* __restrict__ bv,
    float* __restrict__ wcat, float* __restrict__ bcat, int M)
{
  int idx = blockIdx.x * 256 + threadIdx.x;
  int total = M << 8;
  if (idx < total) {
    int r = idx >> 8, c = idx & 255;
    float v;
    if (r < 32) v = wq[r * 256 + c];
    else if (r < 64) v = wk[(r - 32) * 256 + c];
    else v = wv[(r - 64) * 256 + c];
    wcat[idx] = v;
  } else if (idx < total + M) {
    int r = idx - total;
    bcat[r] = (r < 32) ? bq[r] : (r < 64) ? bk[r - 32] : bv[r - 64];
  }
}

// ---- both convs' weights: fp32 [O][C][9] -> bf16 [O][j*256+c] ---------------
__global__ __launch_bounds__(256) void cvtw2_k(
    const float* __restrict__ w1, const float* __restrict__ w2,
    bf16* __restrict__ o1, bf16* __restrict__ o2)
{
  const float* in = blockIdx.y ? w2 : w1;
  bf16* out = blockIdx.y ? o2 : o1;
  int idx = blockIdx.x * 256 + threadIdx.x;
  int o = idx / 2304, r = idx % 2304;
  int j = r >> 8, c = r & 255;
  out[idx] = __float2bfloat16(in[(o * 256 + c) * 9 + j]);
}

// ---------------------------------------------------------------------------
// LDS-transpose im2col, K-reordered: colT[n][j*256+c], j = dy*3+dx.
// ---------------------------------------------------------------------------
__global__ __launch_bounds__(256) void im2colT2_k(const bf16* __restrict__ x,
                                                  bf16* __restrict__ colT)
{
  __shared__ bf16 lds[3 * 66 * 66];
  const int tid = threadIdx.x;
  const int h = blockIdx.x, c0 = blockIdx.y * 64;
  x    += (long)blockIdx.z * CDIM * NPIX;
  colT += (long)blockIdx.z * 2304L * NPIX;

  if (tid < 192) {
    int row = tid >> 6, c = tid & 63;
    lds[(row * 66 + 0) * 66 + c] = __float2bfloat16(0.f);
    lds[(row * 66 + 65) * 66 + c] = __float2bfloat16(0.f);
  }
  const int w2 = tid & 31, chi = tid >> 5;
  #pragma unroll
  for (int it = 0; it < 24; ++it) {
    int row = it >> 3, cg = it & 7;
    int c = cg * 8 + chi;
    int hh = h + row - 1;
    unsigned int pix = 0;
    if ((unsigned)hh < 64u)
      pix = *(const unsigned int*)(x + (long)(c0 + c) * 4096 + hh * 64 + w2 * 2);
    const bf16* pp = (const bf16*)&pix;
    lds[(row * 66 + (w2 * 2 + 1)) * 66 + c] = pp[0];
    lds[(row * 66 + (w2 * 2 + 2)) * 66 + c] = pp[1];
  }
  __syncthreads();
  const int cg8 = tid & 7, wq = tid >> 3;
  #pragma unroll
  for (int j = 0; j < 9; ++j) {
    const int dy = j / 3, dx = j % 3;
    #pragma unroll
    for (int half = 0; half < 2; ++half) {
      int w = wq + half * 32;
      s8v v = *(const s8v*)&lds[(dy * 66 + (w + dx)) * 66 + cg8 * 8];
      *(s8v*)(colT + (long)(h * 64 + w) * 2304 + j * 256 + c0 + cg8 * 8) = v;
    }
  }
}

// ---- 16-elem row load/store helpers ----------------------------------------
__device__ inline void ld16(const bf16* p, float* v) {
  s8v r0 = *(const s8v*)p, r1 = *(const s8v*)(p + 8);
  const bf16* e0 = (const bf16*)&r0; const bf16* e1 = (const bf16*)&r1;
  #pragma unroll
  for (int j = 0; j < 8; ++j) { v[j] = __bfloat162float(e0[j]); v[8 + j] = __bfloat162float(e1[j]); }
}
__device__ inline void ld16(const float* p, float* v) {
  #pragma unroll
  for (int q = 0; q < 4; ++q) {
    float4 f = *(const float4*)(p + q * 4);
    v[q * 4 + 0] = f.x; v[q * 4 + 1] = f.y; v[q * 4 + 2] = f.z; v[q * 4 + 3] = f.w;
  }
}
__device__ inline void st16(bf16* p, const float* v) {
  s8v o0, o1v; bf16* f0 = (bf16*)&o0; bf16* f1 = (bf16*)&o1v;
  #pragma unroll
  for (int j = 0; j < 8; ++j) { f0[j] = __float2bfloat16(v[j]); f1[j] = __float2bfloat16(v[8 + j]); }
  *(s8v*)p = o0; *(s8v*)(p + 8) = o1v;
}
__device__ inline void st16(float* p, const float* v) {
  #pragma unroll
  for (int q = 0; q < 4; ++q) {
    float4 f; f.x = v[q * 4 + 0]; f.y = v[q * 4 + 1]; f.z = v[q * 4 + 2]; f.w = v[q * 4 + 3];
    *(float4*)(p + q * 4) = f;
  }
}

// ---- fused InstanceNorm: out = inorm(g*a + b) per row of 4096 --------------
template<typename TAe, typename TBe, typename TOe, int G>
__global__ __launch_bounds__(256) void inorm_k(
    const TAe* __restrict__ a, const TBe* __restrict__ b,
    const float* __restrict__ g, TOe* __restrict__ out)
{
  __shared__ float red[8];
  const int tid = threadIdx.x;
  const long base = (long)blockIdx.x * NPIX + tid * 16;
  float gv = G ? *g : 1.f;
  float va[16], vbv[16], v[16];
  ld16(a + base, va);
  ld16(b + base, vbv);
  #pragma unroll
  for (int j = 0; j < 16; ++j) v[j] = gv * va[j] + vbv[j];
  float sum = 0.f, sq = 0.f;
  #pragma unroll
  for (int j = 0; j < 16; ++j) { sum += v[j]; sq += v[j] * v[j]; }
  #pragma unroll
  for (int s = 32; s; s >>= 1) { sum += __shfl_xor(sum, s); sq += __shfl_xor(sq, s); }
  if ((tid & 63) == 0) { red[tid >> 6] = sum; red[4 + (tid >> 6)] = sq; }
  __syncthreads();
  sum = red[0] + red[1] + red[2] + red[3];
  sq  = red[4] + red[5] + red[6] + red[7];
  float mean = sum * (1.f / NPIX);
  float var  = fmaxf(sq * (1.f / NPIX) - mean * mean, 0.f);
  float rstd = rsqrtf(var + 1e-5f);
  float o[16];
  #pragma unroll
  for (int j = 0; j < 16; ++j) o[j] = (v[j] - mean) * rstd;
  st16(out + base, o);
}

// ---- host-side helpers ------------------------------------------------------
static const long CN = (long)CDIM * NPIX;

// fused flash attention: one kernel per nb slots; CB picked so grid stays at
// 512 blocks (2 blocks/CU) for both the merged (nb=4) and stage-C (nb=2) runs.
static void attn_core(int nb, bf16* qkv, bf16* qkt, bf16* t0, hipStream_t stream)
{
  if (nb == 4)
    fattn_k<128><<<dim3(64, 2, 4), dim3(256), 0, stream>>>(qkt, qkv + 64 * NPIX, t0);
  else
    fattn_k<64><<<dim3(64, 4, 2), dim3(256), 0, stream>>>(qkt, qkv + 64 * NPIX, t0);
}

static void run_conv(const bf16* src, const bf16* wcvt, const float* cb,
                     bf16* colT, bf16* part, bf16* dst, hipStream_t stream)
{
  dim3 TB(256);
  im2colT2_k<<<dim3(64, 4, 2), TB, 0, stream>>>(src, colT);
  gemm128<<<dim3(32, 2, 8), TB, 0, stream>>>(wcvt, colT, part, NPIX, 2304, 9, 4,
                                             0L, 2304L * NPIX);
  reduce_bias_k<<<dim3(1024), TB, 0, stream>>>(part, cb, dst, 4);
}

// ---------------------------------------------------------------------------
extern "C" void kernel_launch(void* const* d_in, const int* in_sizes, int n_in,
                              void* d_out, int out_size, void* d_ws, size_t ws_size,
                              hipStream_t stream)
{
  (void)in_sizes; (void)n_in; (void)out_size; (void)ws_size;
  const float* x = (const float*)d_in[0];
  const float* y = (const float*)d_in[1];
  auto W = [&](int i) { return (const float*)d_in[i]; };

  char* wp = (char*)d_ws;
  auto take = [&](size_t nbytes) { char* p = wp; wp += (nbytes + 255) & ~(size_t)255; return p; };
  bf16*  qkv   = (bf16*)take((size_t)4 * QKVSTR * 2);
  bf16*  qkt   = (bf16*)take((size_t)4 * QKTSTR * 2);
  bf16*  t0    = (bf16*)take((size_t)4 * CN * 2);
  bf16*  u1    = (bf16*)take(2 * CN * 2);
  bf16*  u2    = (bf16*)take(2 * CN * 2);
  bf16*  u3    = (bf16*)take(2 * CN * 2);
  bf16*  u4    = (bf16*)take(2 * CN * 2);
  bf16*  colT  = (bf16*)take((size_t)2 * 2304L * NPIX * 2);   // 37.7 MiB
  bf16*  wcvt1 = (bf16*)take((size_t)589824 * 2);
  bf16*  wcvt2 = (bf16*)take((size_t)589824 * 2);
  float* wcat1 = (float*)take((size_t)81920 * 4);
  float* bcat1 = (float*)take(320 * 4);
  float* wcat2 = (float*)take((size_t)81920 * 4);
  float* bcat2 = (float*)take(320 * 4);
  float* wqk   = (float*)take((size_t)16384 * 4);
  float* bqk   = (float*)take(64 * 4);
  bf16*  part  = (bf16*)take((size_t)8 * MN_ELEMS * 2);       // conv split-K
  bf16*  cvout = qkv;                                         // conv out (aliased)

  dim3 TB(256);

  // ---- prep: weight concat/convert ----
  cat_k<<<dim3(322), TB, 0, stream>>>(W(2), W(3), W(4), W(5), W(6), W(7), wcat1, bcat1, 320);
  cat_k<<<dim3(322), TB, 0, stream>>>(W(9), W(10), W(11), W(12), W(13), W(14), wcat2, bcat2, 320);
  cat_k<<<dim3(65),  TB, 0, stream>>>(W(16), W(17), W(18), W(19), nullptr, nullptr, wqk, bqk, 64);
  cvtw2_k<<<dim3(2304, 2), TB, 0, stream>>>(W(23), W(25), wcvt1, wcvt2);

  // ---- stages A+B attention together: z = stage*2 + batch ----
  proj_k<1,float><<<dim3(64,5,4), TB, 0, stream>>>(
      wcat1, wcat2, x, y, bcat1, bcat2, qkv, qkt, 320, NPIX, 256, CN, QKVSTR, 8);
  attn_core(4, qkv, qkt, t0, stream);

  // ---- out_1 / out_3 inorms ----
  inorm_k<bf16,float,bf16,1><<<dim3(512), TB, 0, stream>>>(t0, x, W(8), u1);
  inorm_k<bf16,float,bf16,1><<<dim3(512), TB, 0, stream>>>(t0 + 2 * CN, y, W(15), u3);

  // ---- conv1 -> out_2 ----
  run_conv(u1, wcvt1, W(24), colT, part, cvout, stream);
  inorm_k<bf16,bf16,bf16,0><<<dim3(512), TB, 0, stream>>>(u1, cvout, nullptr, u2);

  // ---- stage C: q/k from out_2 (transposed), v from out_3 ----
  proj_k<1,bf16><<<dim3(64,1,2), TB, 0, stream>>>(
      wqk, wqk, u2, u2, bqk, bqk, qkv, qkt, 64, NPIX, 256, CN, QKVSTR, 8);
  proj_k<0,bf16><<<dim3(64,4,2), TB, 0, stream>>>(
      W(20), W(20), u3, u3, W(21), W(21), qkv + 64 * NPIX, qkt, 256, NPIX, 256, CN, QKVSTR, 8);
  attn_core(2, qkv, qkt, t0, stream);
  inorm_k<bf16,float,bf16,1><<<dim3(512), TB, 0, stream>>>(t0, y, W(22), u1);   // o1
  inorm_k<bf16,bf16,bf16,0><<<dim3(512), TB, 0, stream>>>(u1, u3, nullptr, u4); // o2
  run_conv(u4, wcvt2, W(26), colT, part, cvout, stream);
  inorm_k<bf16,bf16,float,0><<<dim3(512), TB, 0, stream>>>(u4, cvout, nullptr, (float*)d_out);
}

// Round 6
// 411.833 us; speedup vs baseline: 1.0159x; 1.0159x over previous
//
#include <hip/hip_runtime.h>
#include <hip/hip_bf16.h>

typedef __hip_bfloat16 bf16;
typedef __attribute__((ext_vector_type(8))) short s8v;   // 8 bf16 = 4 VGPRs
typedef __attribute__((ext_vector_type(4))) short s4v;   // 4 bf16 = 8 bytes
typedef __attribute__((ext_vector_type(4))) float f4v;

#define NPIX 4096
#define CDIM 256
#define MN_ELEMS (1 << 20)        // CDIM * NPIX
#define QKVSTR (320L * NPIX)      // qkv per-slot stride (elems)
#define QKTSTR (64L * NPIX)       // qkt per-slot stride (elems)

#if __has_builtin(__builtin_amdgcn_exp2f)
#define EXP2F(x) __builtin_amdgcn_exp2f(x)
#else
#define EXP2F(x) exp2f(x)
#endif

// ---- async global->LDS, 16B per lane (dest = wave-uniform base + lane*16) ---
typedef __attribute__((address_space(1))) const unsigned int g_u32;
typedef __attribute__((address_space(3))) unsigned int l_u32;
__device__ __forceinline__ void glds16(const void* g, void* l) {
  __builtin_amdgcn_global_load_lds((g_u32*)g, (l_u32*)l, 16, 0, 0);
}

// ---- 8-element loaders -> bf16x8 (s8v) --------------------------------------
__device__ inline s8v ld8(const bf16* p) { return *(const s8v*)p; }
__device__ inline s8v ld8(const float* p) {
  float4 f0 = *(const float4*)p;
  float4 f1 = *(const float4*)(p + 4);
  s8v r; bf16* e = (bf16*)&r;
  e[0] = __float2bfloat16(f0.x); e[1] = __float2bfloat16(f0.y);
  e[2] = __float2bfloat16(f0.z); e[3] = __float2bfloat16(f0.w);
  e[4] = __float2bfloat16(f1.x); e[5] = __float2bfloat16(f1.y);
  e[6] = __float2bfloat16(f1.z); e[7] = __float2bfloat16(f1.w);
  return r;
}

// ---------------------------------------------------------------------------
// Fused flash attention (R2 structure + dbuf + stage-at-top).
// out[c][n] = sum_m V[c][m] exp(S[n][m]) / lsum[n],  S = q.k (q pre-scaled
// by log2e in proj_k; exp2 here).
// qkt: [slot][4096][64] bf16 (q at d0..31, k at d32..63).
// Vg:  [c][m] m-contig at slot stride QKVSTR.  out: [slot][256][4096].
// Block: n-tile 64 x c-block CB, m streamed 64/step, 4 waves (wr x wc).
// S phase: wave (wr,wc) computes S^T = mfma(K,Q) for n[wr*32..+32) x
// m[wc*32..+32) (4 MFMA), exp2s, packs 4 m-consecutive vals -> swizzled
// ds_write_b64 into shared p_s[kk][n][32].  PV: wave (wr,wc) does
// c[wr*CB/2..) x n[wc*32..+32) x m64 from v_s + p_s (disjoint output, no
// cross-wave reduction).  K+V double-buffered in LDS; stage(i+1) is issued
// at the TOP of iter i so the compiler's vmcnt drain at barrier(1) has the
// whole S phase as cover, and barrier(2)'s drain is free.  2 barriers/step.
// Rowsum: in-register over oct, cross-wc combine via 512B sums buffer.
// grid (64, 256/CB, nslots), 256 thr.  LDS: CB=128 -> 48.5K, CB=64 -> 32.5K.
// ---------------------------------------------------------------------------
template<int CB>
__global__ __launch_bounds__(256) void fattn_k(
    const bf16* __restrict__ qkt, const bf16* __restrict__ Vg,
    bf16* __restrict__ out)
{
  constexpr int SC = CB / 32;              // c-frags per wave in PV
  __shared__ bf16 k_s[2][64 * 32];         // [buf][m 64][d 32]
  __shared__ bf16 v_s[2][2 * CB * 32];     // [buf][kk][c CB][m 32]
  __shared__ bf16 p_s[2 * 64 * 32];        // [kk][n 64][m 32] (swizzled rows)
  __shared__ float sums[2][64];

  const int tid = threadIdx.x;
  const int z = blockIdx.z;
  const int w = tid >> 6, lane = tid & 63;
  const int l15 = lane & 15, oct = lane >> 4;
  const int wr = w >> 1, wc = w & 1;
  const int n0 = blockIdx.x * 64;
  const int c0 = blockIdx.y * CB;
  const bf16* qk = qkt + (long)z * QKTSTR;
  const bf16* Vz = Vg + (long)z * QKVSTR;
  const int srow = lane >> 2, scol = (lane & 3) * 8;

  auto stageK = [&](int ms, int buf) {
    glds16(qk + (long)(ms * 64 + w * 16 + srow) * 64 + 32 + scol,
           &k_s[buf][(w * 16 + srow) * 32 + scol]);
  };
  auto stageV = [&](int ms, int buf) {
    #pragma unroll
    for (int kk = 0; kk < 2; ++kk)
      #pragma unroll
      for (int rg = 0; rg < CB / 64; ++rg)
        glds16(Vz + (long)(c0 + rg * 64 + w * 16 + srow) * 4096 + ms * 64 + kk * 32 + scol,
               &v_s[buf][kk * (CB * 32) + (rg * 64 + w * 16 + srow) * 32 + scol]);
  };

  // Q fragments direct from global (L2-hot, one-time): n = wr*32+st*16+l15
  s8v qf[2];
  #pragma unroll
  for (int st = 0; st < 2; ++st)
    qf[st] = *(const s8v*)(qk + (long)(n0 + wr * 32 + st * 16 + l15) * 64 + oct * 8);

  stageK(0, 0); stageV(0, 0);

  f4v acc[SC][2];
  #pragma unroll
  for (int i = 0; i < SC; ++i)
    #pragma unroll
    for (int j = 0; j < 2; ++j) acc[i][j] = (f4v){0.f, 0.f, 0.f, 0.f};
  float rs[2] = {0.f, 0.f};

  __syncthreads();   // stage(0) landed (compiler drains vmcnt before barrier)

  for (int i = 0; i < 64; ++i) {
    const int cur = i & 1;
    // ---- prefetch next m-step into the other buffer (cover = S phase) ----
    if (i < 63) { stageK(i + 1, cur ^ 1); stageV(i + 1, cur ^ 1); }

    // ---- S^T phase: sa[nt][st] = mfma(K,Q); exp2; pack; swizzled write ---
    s8v kf[2];
    #pragma unroll
    for (int nt = 0; nt < 2; ++nt)
      kf[nt] = *(const s8v*)&k_s[cur][(wc * 32 + nt * 16 + l15) * 32 + oct * 8];
    f4v sa[2][2];
    __builtin_amdgcn_s_setprio(1);
    #pragma unroll
    for (int nt = 0; nt < 2; ++nt)
      #pragma unroll
      for (int st = 0; st < 2; ++st) {
        f4v zz = (f4v){0.f, 0.f, 0.f, 0.f};
        sa[nt][st] = __builtin_amdgcn_mfma_f32_16x16x32_bf16(kf[nt], qf[st], zz, 0, 0, 0);
      }
    __builtin_amdgcn_s_setprio(0);
    #pragma unroll
    for (int st = 0; st < 2; ++st) {
      const int n = wr * 32 + st * 16 + l15;         // P row (lane-fixed)
      const int sw = ((n >> 1) & 3) << 4;            // intra-64B-row byte XOR
      #pragma unroll
      for (int nt = 0; nt < 2; ++nt) {
        // m = wc*32 + nt*16 + oct*4 + r  ->  kk = wc, m&31 = nt*16+oct*4+r
        int byte = wc * 4096 + n * 64 + nt * 32 + oct * 8;
        byte ^= sw;
        s4v pk; bf16* pe = (bf16*)&pk;
        float rsum = 0.f;
        #pragma unroll
        for (int r = 0; r < 4; ++r) {
          float e = EXP2F(sa[nt][st][r]);
          rsum += e;
          pe[r] = __float2bfloat16(e);
        }
        rs[st] += rsum;
        *(s4v*)((char*)p_s + byte) = pk;
      }
    }
    __syncthreads();   // (1) P visible; k_s(cur) reads done; stage draining

    // ---- PV phase: acc[c][n] += V[c][m] * P[n][m], K=64 ------------------
    #pragma unroll
    for (int kk = 0; kk < 2; ++kk) {
      s8v pf[2], vf[SC];
      #pragma unroll
      for (int j = 0; j < 2; ++j) {
        const int n = wc * 32 + j * 16 + l15;
        int byte = kk * 4096 + n * 64 + oct * 16;
        byte ^= ((n >> 1) & 3) << 4;
        pf[j] = *(const s8v*)((const char*)p_s + byte);
      }
      #pragma unroll
      for (int st = 0; st < SC; ++st)
        vf[st] = *(const s8v*)((const char*)&v_s[cur][0] + kk * (CB * 64)
                               + (wr * (CB / 2) + st * 16 + l15) * 64 + oct * 16);
      __builtin_amdgcn_s_setprio(1);
      #pragma unroll
      for (int st = 0; st < SC; ++st)
        #pragma unroll
        for (int j = 0; j < 2; ++j)
          acc[st][j] = __builtin_amdgcn_mfma_f32_16x16x32_bf16(vf[st], pf[j], acc[st][j], 0, 0, 0);
      __builtin_amdgcn_s_setprio(0);
    }
    __syncthreads();   // (2) p_s/v_s(cur) reads done; stage(i+1) landed
  }

  // ---- rowsum: reduce across octs, combine wc halves via LDS --------------
  #pragma unroll
  for (int st = 0; st < 2; ++st) {
    rs[st] += __shfl_xor(rs[st], 16);
    rs[st] += __shfl_xor(rs[st], 32);
  }
  if (oct == 0) {
    #pragma unroll
    for (int st = 0; st < 2; ++st)
      sums[wc][wr * 32 + st * 16 + l15] = rs[st];
  }
  __syncthreads();

  float rinv[2];
  #pragma unroll
  for (int j = 0; j < 2; ++j) {
    const int n = wc * 32 + j * 16 + l15;
    rinv[j] = 1.f / (sums[0][n] + sums[1][n]);
  }
  bf16* op = out + (long)z * ((long)CDIM * NPIX);
  #pragma unroll
  for (int st = 0; st < SC; ++st) {
    const int gc = c0 + wr * (CB / 2) + st * 16 + oct * 4;
    #pragma unroll
    for (int j = 0; j < 2; ++j) {
      const int gn = n0 + wc * 32 + j * 16 + l15;
      #pragma unroll
      for (int r = 0; r < 4; ++r)
        op[(long)(gc + r) * NPIX + gn] = __float2bfloat16(acc[st][j][r] * rinv[j]);
    }
  }
}

// ---------------------------------------------------------------------------
// m97-class GEMM, BK=64 per barrier, batched split-K: z = slot*nsplit + slice.
// A: [M][K] k-contig (+slot*abat).  B: [N][K] k-contig (+slot*bbat).
// Cp: bf16 partials at z*M*N.  Tile 128x128, 4 waves (2x2).  (conv path only)
// ---------------------------------------------------------------------------
__global__ __launch_bounds__(256) void gemm128(
    const bf16* __restrict__ A, const bf16* __restrict__ Bm,
    bf16* __restrict__ Cp, int N, int K, int nchunk, int nsplit,
    long abat, long bbat)
{
  __shared__ bf16 a_s0[128 * 32], a_s1[128 * 32];
  __shared__ bf16 b_s0[128 * 32], b_s1[128 * 32];
  const int tid = threadIdx.x;
  const int z = blockIdx.z;
  const int bb = z / nsplit, ks = z - bb * nsplit;
  A  += bb * abat;
  Bm += bb * bbat;
  const int w = tid >> 6, lane = tid & 63;
  const int l15 = lane & 15, oct = lane >> 4;
  const int wr = w >> 1, wc = w & 1;
  const int m0 = blockIdx.y * 128, n0 = blockIdx.x * 128;
  const int kc0 = ks * nchunk, kc1 = kc0 + nchunk;

  const int srow = lane >> 2, skoff = (lane & 3) * 8;
  const long aRow0 = (long)(m0 + (w << 4) + srow) * K;
  const long aRow1 = (long)(m0 + ((w + 4) << 4) + srow) * K;
  const long bRow0 = (long)(n0 + (w << 4) + srow) * K;
  const long bRow1 = (long)(n0 + ((w + 4) << 4) + srow) * K;
  const int ldsOff0 = (w) * 512, ldsOff1 = (w + 4) * 512;

  f4v acc[4][4];
  #pragma unroll
  for (int i = 0; i < 4; ++i)
    #pragma unroll
    for (int j = 0; j < 4; ++j) acc[i][j] = (f4v){0.f, 0.f, 0.f, 0.f};

  for (int kc = kc0; kc < kc1; ++kc) {
    const int kb0 = kc * 64 + skoff;
    const int kb1 = kb0 + 32;
    glds16(A + aRow0 + kb0, a_s0 + ldsOff0);
    glds16(A + aRow1 + kb0, a_s0 + ldsOff1);
    glds16(A + aRow0 + kb1, a_s1 + ldsOff0);
    glds16(A + aRow1 + kb1, a_s1 + ldsOff1);
    glds16(Bm + bRow0 + kb0, b_s0 + ldsOff0);
    glds16(Bm + bRow1 + kb0, b_s0 + ldsOff1);
    glds16(Bm + bRow0 + kb1, b_s1 + ldsOff0);
    glds16(Bm + bRow1 + kb1, b_s1 + ldsOff1);
    __syncthreads();
    #pragma unroll
    for (int h = 0; h < 2; ++h) {
      const bf16* as = h ? a_s1 : a_s0;
      const bf16* bs = h ? b_s1 : b_s0;
      s8v af[4], bfv[4];
      #pragma unroll
      for (int st = 0; st < 4; ++st)
        af[st] = *(const s8v*)(as + (wr * 64 + st * 16 + l15) * 32 + oct * 8);
      #pragma unroll
      for (int nt = 0; nt < 4; ++nt)
        bfv[nt] = *(const s8v*)(bs + (wc * 64 + nt * 16 + l15) * 32 + oct * 8);
      #pragma unroll
      for (int st = 0; st < 4; ++st)
        #pragma unroll
        for (int nt = 0; nt < 4; ++nt)
          acc[st][nt] = __builtin_amdgcn_mfma_f32_16x16x32_bf16(af[st], bfv[nt], acc[st][nt], 0, 0, 0);
    }
    __syncthreads();
  }

  bf16* Cz = Cp + (long)z * ((long)gridDim.y * 128) * N;
  #pragma unroll
  for (int st = 0; st < 4; ++st) {
    const int gm = m0 + wr * 64 + st * 16 + oct * 4;
    #pragma unroll
    for (int nt = 0; nt < 4; ++nt) {
      const int gn = n0 + wc * 64 + nt * 16 + l15;
      #pragma unroll
      for (int r = 0; r < 4; ++r)
        Cz[(long)(gm + r) * N + gn] = __float2bfloat16(acc[st][nt][r]);
    }
  }
}

// ---------------------------------------------------------------------------
// Projection GEMM. z = slot; stage = z>>1 selects (A,bias,B) vs (A2,bias2,B2);
// batch = z&1 offsets B by bbat. QKT=1: rows gm<64 -> qkt transposed, with the
// q rows (gm<32) pre-scaled by log2(e) so fattn can use raw v_exp_f32.
// ---------------------------------------------------------------------------
template<int QKT, typename TBe>
__global__ __launch_bounds__(256) void proj_k(
    const float* __restrict__ A, const float* __restrict__ A2,
    const TBe* __restrict__ B1, const TBe* __restrict__ B2,
    const float* __restrict__ bias, const float* __restrict__ bias2,
    bf16* __restrict__ Cm, bf16* __restrict__ qkt,
    int M, int N, int K, long bbat, long cbat, int nchunk)
{
  __shared__ bf16 a_s[64][40];
  __shared__ bf16 b_s[64][40];
  const int tid = threadIdx.x;
  const int z = blockIdx.z, stage = z >> 1, bat = z & 1;
  const float* Au = stage ? A2 : A;
  const float* biasu = stage ? bias2 : bias;
  const TBe* Bm = (stage ? B2 : B1) + bat * bbat;
  Cm += z * cbat;
  if (QKT) qkt += z * QKTSTR;
  const int m0 = blockIdx.y * 64, n0 = blockIdx.x * 64;
  const int w = tid >> 6, lane = tid & 63;
  const int l15 = lane & 15, oct = lane >> 4;

  f4v acc[4];
  #pragma unroll
  for (int i = 0; i < 4; ++i) acc[i] = (f4v){0.f, 0.f, 0.f, 0.f};

  const int a_i0 = tid >> 2, a_i1 = (tid & 3) * 8;
  const int b_i0 = tid >> 3, b_i1 = (tid & 7) * 8;

  s8v pa, pb;
  auto ldA = [&](int kc, s8v& d) {
    if (m0 + a_i0 < M) d = ld8(Au + (long)(m0 + a_i0) * K + kc * 32 + a_i1);
    else d = (s8v){0,0,0,0,0,0,0,0};
  };
  auto ldB = [&](int kc, s8v& d) {
    d = ld8(Bm + (long)(kc * 32 + b_i0) * N + n0 + b_i1);
  };

  ldA(0, pa); ldB(0, pb);
  for (int kc = 0; kc < nchunk; ++kc) {
    *(s8v*)&a_s[a_i0][a_i1] = pa;
    {
      const bf16* e = (const bf16*)&pb;
      #pragma unroll
      for (int j = 0; j < 8; ++j) b_s[b_i1 + j][b_i0] = e[j];
    }
    __syncthreads();
    if (kc + 1 < nchunk) { ldA(kc + 1, pa); ldB(kc + 1, pb); }
    s8v af = *(const s8v*)&a_s[w * 16 + l15][oct * 8];
    #pragma unroll
    for (int nt = 0; nt < 4; ++nt) {
      s8v bfr = *(const s8v*)&b_s[nt * 16 + l15][oct * 8];
      acc[nt] = __builtin_amdgcn_mfma_f32_16x16x32_bf16(af, bfr, acc[nt], 0, 0, 0);
    }
    __syncthreads();
  }
  const int gm_base = m0 + w * 16 + oct * 4;
  #pragma unroll
  for (int nt = 0; nt < 4; ++nt) {
    const int gn = n0 + nt * 16 + l15;
    #pragma unroll
    for (int r = 0; r < 4; ++r) {
      int gm = gm_base + r;
      if (gm < M) {
        float vv = acc[nt][r] + biasu[gm];
        if (QKT && gm < 64) {
          float vv2 = (gm < 32) ? vv * 1.44269504f : vv;   // q *= log2(e)
          qkt[(long)gn * 64 + gm] = __float2bfloat16(vv2);
        } else {
          Cm[(long)gm * N + gn] = __float2bfloat16(vv);
        }
      }
    }
  }
}

// ---- split-K reducer + bias (conv), bf16 partials, 8 elems/thread ----------
__global__ __launch_bounds__(256) void reduce_bias_k(
    const bf16* __restrict__ part, const float* __restrict__ bias,
    bf16* __restrict__ out, int nsplit)
{
  const int g8 = (blockIdx.x * 256 + threadIdx.x) * 8;
  const int b = g8 >> 20, i = g8 & (MN_ELEMS - 1);
  const bf16* p0 = part + (long)b * nsplit * MN_ELEMS + i;
  float s[8];
  { s8v v = *(const s8v*)p0; const bf16* e = (const bf16*)&v;
    #pragma unroll
    for (int j = 0; j < 8; ++j) s[j] = __bfloat162float(e[j]); }
  for (int p = 1; p < nsplit; ++p) {
    s8v v = *(const s8v*)(p0 + (long)p * MN_ELEMS); const bf16* e = (const bf16*)&v;
    #pragma unroll
    for (int j = 0; j < 8; ++j) s[j] += __bfloat162float(e[j]);
  }
  float bv = bias[i >> 12];
  s8v o; bf16* eo = (bf16*)&o;
  #pragma unroll
  for (int j = 0; j < 8; ++j) eo[j] = __float2bfloat16(s[j] + bv);
  *(s8v*)(out + g8) = o;
}

// ---- concat q/k(/v) weights+biases into fp32 [M][256] + [M] -----------------
__global__ __launch_bounds__(256) void cat_k(
    const float* __restrict__ wq, const float* __restrict__ bq,
    const float* __restrict__ wk, const float* __restrict__ bk,
    const float* __restrict__ wv, const float* __restrict__ bv,
    float* __restrict__ wcat, float* __restrict__ bcat, int M)
{
  int idx = blockIdx.x * 256 + threadIdx.x;
  int total = M << 8;
  if (idx < total) {
    int r = idx >> 8, c = idx & 255;
    float v;
    if (r < 32) v = wq[r * 256 + c];
    else if (r < 64) v = wk[(r - 32) * 256 + c];
    else v = wv[(r - 64) * 256 + c];
    wcat[idx] = v;
  } else if (idx < total + M) {
    int r = idx - total;
    bcat[r] = (r < 32) ? bq[r] : (r < 64) ? bk[r - 32] : bv[r - 64];
  }
}

// ---- both convs' weights: fp32 [O][C][9] -> bf16 [O][j*256+c] ---------------
__global__ __launch_bounds__(256) void cvtw2_k(
    const float* __restrict__ w1, const float* __restrict__ w2,
    bf16* __restrict__ o1, bf16* __restrict__ o2)
{
  const float* in = blockIdx.y ? w2 : w1;
  bf16* out = blockIdx.y ? o2 : o1;
  int idx = blockIdx.x * 256 + threadIdx.x;
  int o = idx / 2304, r = idx % 2304;
  int j = r >> 8, c = r & 255;
  out[idx] = __float2bfloat16(in[(o * 256 + c) * 9 + j]);
}

// ---------------------------------------------------------------------------
// LDS-transpose im2col, K-reordered: colT[n][j*256+c], j = dy*3+dx.
// ---------------------------------------------------------------------------
__global__ __launch_bounds__(256) void im2colT2_k(const bf16* __restrict__ x,
                                                  bf16* __restrict__ colT)
{
  __shared__ bf16 lds[3 * 66 * 66];
  const int tid = threadIdx.x;
  const int h = blockIdx.x, c0 = blockIdx.y * 64;
  x    += (long)blockIdx.z * CDIM * NPIX;
  colT += (long)blockIdx.z * 2304L * NPIX;

  if (tid < 192) {
    int row = tid >> 6, c = tid & 63;
    lds[(row * 66 + 0) * 66 + c] = __float2bfloat16(0.f);
    lds[(row * 66 + 65) * 66 + c] = __float2bfloat16(0.f);
  }
  const int w2 = tid & 31, chi = tid >> 5;
  #pragma unroll
  for (int it = 0; it < 24; ++it) {
    int row = it >> 3, cg = it & 7;
    int c = cg * 8 + chi;
    int hh = h + row - 1;
    unsigned int pix = 0;
    if ((unsigned)hh < 64u)
      pix = *(const unsigned int*)(x + (long)(c0 + c) * 4096 + hh * 64 + w2 * 2);
    const bf16* pp = (const bf16*)&pix;
    lds[(row * 66 + (w2 * 2 + 1)) * 66 + c] = pp[0];
    lds[(row * 66 + (w2 * 2 + 2)) * 66 + c] = pp[1];
  }
  __syncthreads();
  const int cg8 = tid & 7, wq = tid >> 3;
  #pragma unroll
  for (int j = 0; j < 9; ++j) {
    const int dy = j / 3, dx = j % 3;
    #pragma unroll
    for (int half = 0; half < 2; ++half) {
      int w = wq + half * 32;
      s8v v = *(const s8v*)&lds[(dy * 66 + (w + dx)) * 66 + cg8 * 8];
      *(s8v*)(colT + (long)(h * 64 + w) * 2304 + j * 256 + c0 + cg8 * 8) = v;
    }
  }
}

// ---- 16-elem row load/store helpers ----------------------------------------
__device__ inline void ld16(const bf16* p, float* v) {
  s8v r0 = *(const s8v*)p, r1 = *(const s8v*)(p + 8);
  const bf16* e0 = (const bf16*)&r0; const bf16* e1 = (const bf16*)&r1;
  #pragma unroll
  for (int j = 0; j < 8; ++j) { v[j] = __bfloat162float(e0[j]); v[8 + j] = __bfloat162float(e1[j]); }
}
__device__ inline void ld16(const float* p, float* v) {
  #pragma unroll
  for (int q = 0; q < 4; ++q) {
    float4 f = *(const float4*)(p + q * 4);
    v[q * 4 + 0] = f.x; v[q * 4 + 1] = f.y; v[q * 4 + 2] = f.z; v[q * 4 + 3] = f.w;
  }
}
__device__ inline void st16(bf16* p, const float* v) {
  s8v o0, o1v; bf16* f0 = (bf16*)&o0; bf16* f1 = (bf16*)&o1v;
  #pragma unroll
  for (int j = 0; j < 8; ++j) { f0[j] = __float2bfloat16(v[j]); f1[j] = __float2bfloat16(v[8 + j]); }
  *(s8v*)p = o0; *(s8v*)(p + 8) = o1v;
}
__device__ inline void st16(float* p, const float* v) {
  #pragma unroll
  for (int q = 0; q < 4; ++q) {
    float4 f; f.x = v[q * 4 + 0]; f.y = v[q * 4 + 1]; f.z = v[q * 4 + 2]; f.w = v[q * 4 + 3];
    *(float4*)(p + q * 4) = f;
  }
}

// ---- fused InstanceNorm: out = inorm(g*a + b) per row of 4096 --------------
template<typename TAe, typename TBe, typename TOe, int G>
__global__ __launch_bounds__(256) void inorm_k(
    const TAe* __restrict__ a, const TBe* __restrict__ b,
    const float* __restrict__ g, TOe* __restrict__ out)
{
  __shared__ float red[8];
  const int tid = threadIdx.x;
  const long base = (long)blockIdx.x * NPIX + tid * 16;
  float gv = G ? *g : 1.f;
  float va[16], vbv[16], v[16];
  ld16(a + base, va);
  ld16(b + base, vbv);
  #pragma unroll
  for (int j = 0; j < 16; ++j) v[j] = gv * va[j] + vbv[j];
  float sum = 0.f, sq = 0.f;
  #pragma unroll
  for (int j = 0; j < 16; ++j) { sum += v[j]; sq += v[j] * v[j]; }
  #pragma unroll
  for (int s = 32; s; s >>= 1) { sum += __shfl_xor(sum, s); sq += __shfl_xor(sq, s); }
  if ((tid & 63) == 0) { red[tid >> 6] = sum; red[4 + (tid >> 6)] = sq; }
  __syncthreads();
  sum = red[0] + red[1] + red[2] + red[3];
  sq  = red[4] + red[5] + red[6] + red[7];
  float mean = sum * (1.f / NPIX);
  float var  = fmaxf(sq * (1.f / NPIX) - mean * mean, 0.f);
  float rstd = rsqrtf(var + 1e-5f);
  float o[16];
  #pragma unroll
  for (int j = 0; j < 16; ++j) o[j] = (v[j] - mean) * rstd;
  st16(out + base, o);
}

// ---- host-side helpers ------------------------------------------------------
static const long CN = (long)CDIM * NPIX;

// fused flash attention: CB chosen so the grid stays at 512 blocks (2/CU).
static void attn_core(int nb, bf16* qkv, bf16* qkt, bf16* t0, hipStream_t stream)
{
  if (nb == 4)
    fattn_k<128><<<dim3(64, 2, 4), dim3(256), 0, stream>>>(qkt, qkv + 64 * NPIX, t0);
  else
    fattn_k<64><<<dim3(64, 4, 2), dim3(256), 0, stream>>>(qkt, qkv + 64 * NPIX, t0);
}

static void run_conv(const bf16* src, const bf16* wcvt, const float* cb,
                     bf16* colT, bf16* part, bf16* dst, hipStream_t stream)
{
  dim3 TB(256);
  im2colT2_k<<<dim3(64, 4, 2), TB, 0, stream>>>(src, colT);
  gemm128<<<dim3(32, 2, 8), TB, 0, stream>>>(wcvt, colT, part, NPIX, 2304, 9, 4,
                                             0L, 2304L * NPIX);
  reduce_bias_k<<<dim3(1024), TB, 0, stream>>>(part, cb, dst, 4);
}

// ---------------------------------------------------------------------------
extern "C" void kernel_launch(void* const* d_in, const int* in_sizes, int n_in,
                              void* d_out, int out_size, void* d_ws, size_t ws_size,
                              hipStream_t stream)
{
  (void)in_sizes; (void)n_in; (void)out_size; (void)ws_size;
  const float* x = (const float*)d_in[0];
  const float* y = (const float*)d_in[1];
  auto W = [&](int i) { return (const float*)d_in[i]; };

  char* wp = (char*)d_ws;
  auto take = [&](size_t nbytes) { char* p = wp; wp += (nbytes + 255) & ~(size_t)255; return p; };
  bf16*  qkv   = (bf16*)take((size_t)4 * QKVSTR * 2);
  bf16*  qkt   = (bf16*)take((size_t)4 * QKTSTR * 2);
  bf16*  t0    = (bf16*)take((size_t)4 * CN * 2);
  bf16*  u1    = (bf16*)take(2 * CN * 2);
  bf16*  u2    = (bf16*)take(2 * CN * 2);
  bf16*  u3    = (bf16*)take(2 * CN * 2);
  bf16*  u4    = (bf16*)take(2 * CN * 2);
  bf16*  colT  = (bf16*)take((size_t)2 * 2304L * NPIX * 2);   // 37.7 MiB
  bf16*  wcvt1 = (bf16*)take((size_t)589824 * 2);
  bf16*  wcvt2 = (bf16*)take((size_t)589824 * 2);
  float* wcat1 = (float*)take((size_t)81920 * 4);
  float* bcat1 = (float*)take(320 * 4);
  float* wcat2 = (float*)take((size_t)81920 * 4);
  float* bcat2 = (float*)take(320 * 4);
  float* wqk   = (float*)take((size_t)16384 * 4);
  float* bqk   = (float*)take(64 * 4);
  bf16*  part  = (bf16*)take((size_t)8 * MN_ELEMS * 2);       // conv split-K
  bf16*  cvout = qkv;                                         // conv out (aliased)

  dim3 TB(256);

  // ---- prep: weight concat/convert ----
  cat_k<<<dim3(322), TB, 0, stream>>>(W(2), W(3), W(4), W(5), W(6), W(7), wcat1, bcat1, 320);
  cat_k<<<dim3(322), TB, 0, stream>>>(W(9), W(10), W(11), W(12), W(13), W(14), wcat2, bcat2, 320);
  cat_k<<<dim3(65),  TB, 0, stream>>>(W(16), W(17), W(18), W(19), nullptr, nullptr, wqk, bqk, 64);
  cvtw2_k<<<dim3(2304, 2), TB, 0, stream>>>(W(23), W(25), wcvt1, wcvt2);

  // ---- stages A+B attention together: z = stage*2 + batch ----
  proj_k<1,float><<<dim3(64,5,4), TB, 0, stream>>>(
      wcat1, wcat2, x, y, bcat1, bcat2, qkv, qkt, 320, NPIX, 256, CN, QKVSTR, 8);
  attn_core(4, qkv, qkt, t0, stream);

  // ---- out_1 / out_3 inorms ----
  inorm_k<bf16,float,bf16,1><<<dim3(512), TB, 0, stream>>>(t0, x, W(8), u1);
  inorm_k<bf16,float,bf16,1><<<dim3(512), TB, 0, stream>>>(t0 + 2 * CN, y, W(15), u3);

  // ---- conv1 -> out_2 ----
  run_conv(u1, wcvt1, W(24), colT, part, cvout, stream);
  inorm_k<bf16,bf16,bf16,0><<<dim3(512), TB, 0, stream>>>(u1, cvout, nullptr, u2);

  // ---- stage C: q/k from out_2 (transposed), v from out_3 ----
  proj_k<1,bf16><<<dim3(64,1,2), TB, 0, stream>>>(
      wqk, wqk, u2, u2, bqk, bqk, qkv, qkt, 64, NPIX, 256, CN, QKVSTR, 8);
  proj_k<0,bf16><<<dim3(64,4,2), TB, 0, stream>>>(
      W(20), W(20), u3, u3, W(21), W(21), qkv + 64 * NPIX, qkt, 256, NPIX, 256, CN, QKVSTR, 8);
  attn_core(2, qkv, qkt, t0, stream);
  inorm_k<bf16,float,bf16,1><<<dim3(512), TB, 0, stream>>>(t0, y, W(22), u1);   // o1
  inorm_k<bf16,bf16,bf16,0><<<dim3(512), TB, 0, stream>>>(u1, u3, nullptr, u4); // o2
  run_conv(u4, wcvt2, W(26), colT, part, cvout, stream);
  inorm_k<bf16,bf16,float,0><<<dim3(512), TB, 0, stream>>>(u4, cvout, nullptr, (float*)d_out);
}

// Round 7
// 381.390 us; speedup vs baseline: 1.0970x; 1.0798x over previous
//
#include <hip/hip_runtime.h>
#include <hip/hip_bf16.h>

typedef __hip_bfloat16 bf16;
typedef __attribute__((ext_vector_type(8))) short s8v;   // 8 bf16 = 4 VGPRs
typedef __attribute__((ext_vector_type(4))) short s4v;   // 4 bf16 = 8 bytes
typedef __attribute__((ext_vector_type(4))) float f4v;

#define NPIX 4096
#define CDIM 256
#define MN_ELEMS (1 << 20)        // CDIM * NPIX
#define QKVSTR (320L * NPIX)      // qkv per-slot stride (elems)
#define QKTSTR (64L * NPIX)       // qkt per-slot stride (elems)

#if __has_builtin(__builtin_amdgcn_exp2f)
#define EXP2F(x) __builtin_amdgcn_exp2f(x)
#else
#define EXP2F(x) exp2f(x)
#endif

// ---- async global->LDS, 16B per lane (dest = wave-uniform base + lane*16) ---
typedef __attribute__((address_space(1))) const unsigned int g_u32;
typedef __attribute__((address_space(3))) unsigned int l_u32;
__device__ __forceinline__ void glds16(const void* g, void* l) {
  __builtin_amdgcn_global_load_lds((g_u32*)g, (l_u32*)l, 16, 0, 0);
}

// ---- 8-element loaders -> bf16x8 (s8v) --------------------------------------
__device__ inline s8v ld8(const bf16* p) { return *(const s8v*)p; }
__device__ inline s8v ld8(const float* p) {
  float4 f0 = *(const float4*)p;
  float4 f1 = *(const float4*)(p + 4);
  s8v r; bf16* e = (bf16*)&r;
  e[0] = __float2bfloat16(f0.x); e[1] = __float2bfloat16(f0.y);
  e[2] = __float2bfloat16(f0.z); e[3] = __float2bfloat16(f0.w);
  e[4] = __float2bfloat16(f1.x); e[5] = __float2bfloat16(f1.y);
  e[6] = __float2bfloat16(f1.z); e[7] = __float2bfloat16(f1.w);
  return r;
}

// ---------------------------------------------------------------------------
// Fused flash-style attention (R2 structure, measured 79 us merged).
// out[c][n] = sum_m V[c][m] exp(S[n][m]) / lsum[n]
// qkt: [slot][4096][64] bf16 (q*log2e at d0..31, k at d32..63).
// Vg:  rows [c][m] m-contig at slot stride QKVSTR.  out: [slot][256][4096].
// S computed TRANSPOSED (mfma(k,q)): lane holds 4 consecutive m at fixed n ->
// P written as swizzled ds_write_b64.  Swizzle: byte ^= ((n>>1)&3)<<4,
// intra-64B-row, same XOR on PV b128 reads.
// grid (4096/NT, 2, nslots), 256 threads = 4 waves (wr: n-half, wc: m-half).
// LDS: k_s 8K + v_s 32K + p_s 16K = 56 KB -> 2 blocks/CU.
// ---------------------------------------------------------------------------
template<int NT>
__global__ __launch_bounds__(256) void fattn_k(
    const bf16* __restrict__ qkt, const bf16* __restrict__ Vg,
    bf16* __restrict__ out)
{
  constexpr int SN = NT / 32;          // per-wave sub-tiles along n
  __shared__ bf16 k_s[128 * 32];       // [m 128][32] (d=32..63 of qkt)
  __shared__ bf16 v_s[4 * 128 * 32];   // [kk][c 128][32]
  __shared__ bf16 p_s[4 * NT * 32];    // [kk][n NT][32 m]; Q staged here first
  float* sums = (float*)k_s;           // [2 wc][NT] after final S phase

  const int tid = threadIdx.x;
  const int z = blockIdx.z;
  const int w = tid >> 6, lane = tid & 63;
  const int l15 = lane & 15, oct = lane >> 4;
  const int wr = w >> 1, wc = w & 1;
  const int n0 = blockIdx.x * NT, c0 = blockIdx.y * 128;
  const bf16* qk = qkt + (long)z * QKTSTR;
  const bf16* Vz = Vg + (long)z * QKVSTR;
  const int srow = lane >> 2, scol = (lane & 3) * 8;

  // ---- prologue: stage Q (into p_s, linear), K(0), V(0) ----
  #pragma unroll
  for (int g = 0; g < NT / 64; ++g)
    glds16(qk + (long)(n0 + g * 64 + (w << 4) + srow) * 64 + scol,
           p_s + g * 2048 + w * 512);
  glds16(qk + (long)((w << 4) + srow) * 64 + 32 + scol, k_s + w * 512);
  glds16(qk + (long)(64 + (w << 4) + srow) * 64 + 32 + scol, k_s + 2048 + w * 512);
  #pragma unroll
  for (int g = 0; g < 8; ++g) {
    const int kk = g & 3, rg = g >> 2;
    glds16(Vz + (long)(c0 + rg * 64 + (w << 4) + srow) * 4096 + kk * 32 + scol,
           v_s + kk * 4096 + rg * 2048 + w * 512);
  }
  __syncthreads();

  s8v qf[SN];
  #pragma unroll
  for (int st = 0; st < SN; ++st)
    qf[st] = *(const s8v*)(p_s + (wr * (NT / 2) + st * 16 + l15) * 32 + oct * 8);
  __syncthreads();   // all qf reads done before p_s is overwritten by P(0)

  f4v acc[4][SN];
  #pragma unroll
  for (int i = 0; i < 4; ++i)
    #pragma unroll
    for (int j = 0; j < SN; ++j) acc[i][j] = (f4v){0.f, 0.f, 0.f, 0.f};
  float rs[SN];
  #pragma unroll
  for (int st = 0; st < SN; ++st) rs[st] = 0.f;

  for (int i = 0; i < 32; ++i) {
    // ---- S^T phase: S[m][n] = k.q (pre-scaled by log2e), exp2, pack, write --
    s8v kf[4];
    #pragma unroll
    for (int nt = 0; nt < 4; ++nt)
      kf[nt] = *(const s8v*)(k_s + (wc * 64 + nt * 16 + l15) * 32 + oct * 8);
    #pragma unroll
    for (int st = 0; st < SN; ++st) {
      const int n = wr * (NT / 2) + st * 16 + l15;     // P row (lane-fixed)
      const int sw = ((n >> 1) & 3) << 4;              // intra-row byte XOR
      f4v sa[4];
      __builtin_amdgcn_s_setprio(1);
      #pragma unroll
      for (int nt = 0; nt < 4; ++nt) {
        f4v zz = (f4v){0.f, 0.f, 0.f, 0.f};
        sa[nt] = __builtin_amdgcn_mfma_f32_16x16x32_bf16(kf[nt], qf[st], zz, 0, 0, 0);
      }
      __builtin_amdgcn_s_setprio(0);
      #pragma unroll
      for (int nt = 0; nt < 4; ++nt) {
        const int kk = wc * 2 + (nt >> 1);             // m = wc*64+nt*16+oct*4+r
        int byte = kk * (NT * 64) + n * 64 + (nt & 1) * 32 + oct * 8;
        byte ^= sw;
        s4v pk; bf16* pe = (bf16*)&pk;
        float rsum = 0.f;
        #pragma unroll
        for (int r = 0; r < 4; ++r) {
          float e = EXP2F(sa[nt][r]);
          rsum += e;
          pe[r] = __float2bfloat16(e);
        }
        rs[st] += rsum;
        *(s4v*)((char*)p_s + byte) = pk;
      }
    }
    __syncthreads();   // (1) P ready; k_s reads done
    // ---- PV phase: acc[c][n] += V[c][m] * P[n][m], K=128 ----
    #pragma unroll
    for (int kk = 0; kk < 4; ++kk) {
      s8v vf[4], pf[SN];
      #pragma unroll
      for (int st = 0; st < 4; ++st)
        vf[st] = *(const s8v*)(v_s + kk * 4096 + (wr * 64 + st * 16 + l15) * 32 + oct * 8);
      #pragma unroll
      for (int nt = 0; nt < SN; ++nt) {
        const int n = wc * (NT / 2) + nt * 16 + l15;
        int byte = kk * (NT * 64) + n * 64 + oct * 16;
        byte ^= ((n >> 1) & 3) << 4;
        pf[nt] = *(const s8v*)((const char*)p_s + byte);
      }
      __builtin_amdgcn_s_setprio(1);
      #pragma unroll
      for (int st = 0; st < 4; ++st)
        #pragma unroll
        for (int nt = 0; nt < SN; ++nt)
          acc[st][nt] = __builtin_amdgcn_mfma_f32_16x16x32_bf16(vf[st], pf[nt], acc[st][nt], 0, 0, 0);
      __builtin_amdgcn_s_setprio(0);
    }
    __syncthreads();   // (2) v_s/p_s reads done by all waves -> safe to restage
    if (i < 31) {
      const int m1 = (i + 1) * 128;
      glds16(qk + (long)(m1 + (w << 4) + srow) * 64 + 32 + scol, k_s + w * 512);
      glds16(qk + (long)(m1 + 64 + (w << 4) + srow) * 64 + 32 + scol, k_s + 2048 + w * 512);
      #pragma unroll
      for (int g = 0; g < 8; ++g) {
        const int kk = g & 3, rg = g >> 2;
        glds16(Vz + (long)(c0 + rg * 64 + (w << 4) + srow) * 4096 + m1 + kk * 32 + scol,
               v_s + kk * 4096 + rg * 2048 + w * 512);
      }
      __syncthreads(); // (3) staged data landed (vmcnt drained by barrier)
    }
  }

  // ---- row-sum: lane holds partial for n=l15-row; reduce across octs -------
  #pragma unroll
  for (int st = 0; st < SN; ++st) {
    rs[st] += __shfl_xor(rs[st], 16);
    rs[st] += __shfl_xor(rs[st], 32);
  }
  if (lane < 16) {
    #pragma unroll
    for (int st = 0; st < SN; ++st)
      sums[wc * NT + wr * (NT / 2) + st * 16 + l15] = rs[st];
  }
  __syncthreads();

  float rinv[SN];
  #pragma unroll
  for (int nt = 0; nt < SN; ++nt) {
    const int n = wc * (NT / 2) + nt * 16 + l15;
    rinv[nt] = 1.f / (sums[n] + sums[NT + n]);
  }
  bf16* op = out + (long)z * ((long)CDIM * NPIX);
  #pragma unroll
  for (int st = 0; st < 4; ++st) {
    const int gc = c0 + wr * 64 + st * 16 + oct * 4;
    #pragma unroll
    for (int nt = 0; nt < SN; ++nt) {
      const int gn = n0 + wc * (NT / 2) + nt * 16 + l15;
      #pragma unroll
      for (int r = 0; r < 4; ++r)
        op[(long)(gc + r) * NPIX + gn] = __float2bfloat16(acc[st][nt][r] * rinv[nt]);
    }
  }
}

// ---------------------------------------------------------------------------
// Fused direct 3x3 conv: out[o][h*64+w] = bias[o] +
//   sum_{j=(dy,dx)} sum_c W[o][j*256+c] * Xpad[c][h+dy-1][w+dx-1]
// Replaces im2col + split-K GEMM + reduce: B-fragments are read straight from
// the padded LDS tile im2col used to build colT (layout [row 3][wpos 66][c 64],
// wpos stride 66 elems = 33 words -> bank-conflict-free b128 reads).
// W: wcvt [o][j*256+c] bf16 (k-contig, matches A-frag).  X: [c][4096] bf16.
// grid (64 h, 2 o-half, 2 batch), 512 threads = 8 waves; wave w owns o-rows
// o0+w*16..+16, all 64 pixels of row h.  4 c-chunk passes x (9 taps x 2 kc).
// LDS 26.1 KB.
// ---------------------------------------------------------------------------
__global__ __launch_bounds__(512) void conv_k(
    const bf16* __restrict__ x, const bf16* __restrict__ wcvt,
    const float* __restrict__ bias, bf16* __restrict__ out)
{
  __shared__ bf16 lds[3 * 66 * 66];   // [row][wpos][c(64, 2 pad)]
  const int tid = threadIdx.x;
  const int h = blockIdx.x;
  const int o0 = blockIdx.y * 128;
  x   += (long)blockIdx.z * CDIM * NPIX;
  out += (long)blockIdx.z * CDIM * NPIX;

  const int w = tid >> 6, lane = tid & 63;
  const int l15 = lane & 15, oct = lane >> 4;

  // zero the w-pad columns once (wpos 0 and 65; never overwritten by staging)
  if (tid < 192) {
    int row = tid >> 6, c = tid & 63;
    lds[(row * 66 + 0) * 66 + c] = __float2bfloat16(0.f);
    lds[(row * 66 + 65) * 66 + c] = __float2bfloat16(0.f);
  }

  f4v acc[4];
  #pragma unroll
  for (int nf = 0; nf < 4; ++nf) acc[nf] = (f4v){0.f, 0.f, 0.f, 0.f};

  const int w2 = tid & 31, chi = tid >> 5;   // staging: w2 pixel-pair, chi c-sub
  const long arow = (long)(o0 + w * 16 + l15) * 2304;

  for (int cg = 0; cg < 4; ++cg) {
    __syncthreads();   // pad/compute(cg-1) reads done before overwrite
    #pragma unroll
    for (int it = 0; it < 12; ++it) {
      int row = it >> 2, cgi = it & 3;
      int c = cgi * 16 + chi;
      int hh = h + row - 1;
      unsigned int pix = 0;
      if ((unsigned)hh < 64u)
        pix = *(const unsigned int*)(x + (long)(cg * 64 + c) * 4096 + hh * 64 + w2 * 2);
      const bf16* pp = (const bf16*)&pix;
      lds[(row * 66 + (w2 * 2 + 1)) * 66 + c] = pp[0];
      lds[(row * 66 + (w2 * 2 + 2)) * 66 + c] = pp[1];
    }
    __syncthreads();   // tile(cg) ready

    #pragma unroll
    for (int j = 0; j < 9; ++j) {
      const int dy = j / 3, dx = j % 3;
      #pragma unroll
      for (int kc = 0; kc < 2; ++kc) {
        s8v af = *(const s8v*)(wcvt + arow + j * 256 + cg * 64 + kc * 32 + oct * 8);
        s8v bfv[4];
        #pragma unroll
        for (int nf = 0; nf < 4; ++nf)
          bfv[nf] = *(const s8v*)&lds[(dy * 66 + (nf * 16 + l15 + dx)) * 66 + kc * 32 + oct * 8];
        #pragma unroll
        for (int nf = 0; nf < 4; ++nf)
          acc[nf] = __builtin_amdgcn_mfma_f32_16x16x32_bf16(af, bfv[nf], acc[nf], 0, 0, 0);
      }
    }
  }

  // ---- epilogue: + bias, store ----
  #pragma unroll
  for (int nf = 0; nf < 4; ++nf) {
    const int gn = h * 64 + nf * 16 + l15;
    const int go = o0 + w * 16 + oct * 4;
    #pragma unroll
    for (int r = 0; r < 4; ++r)
      out[(long)(go + r) * NPIX + gn] = __float2bfloat16(acc[nf][r] + bias[go + r]);
  }
}

// ---------------------------------------------------------------------------
// Projection GEMM. z = slot; stage = z>>1 selects (A,bias,B) vs (A2,bias2,B2);
// batch = z&1 offsets B by bbat. QKT=1: rows gm<64 -> qkt transposed, with the
// q rows (gm<32) pre-scaled by log2(e) so fattn can use raw v_exp_f32.
// ---------------------------------------------------------------------------
template<int QKT, typename TBe>
__global__ __launch_bounds__(256) void proj_k(
    const float* __restrict__ A, const float* __restrict__ A2,
    const TBe* __restrict__ B1, const TBe* __restrict__ B2,
    const float* __restrict__ bias, const float* __restrict__ bias2,
    bf16* __restrict__ Cm, bf16* __restrict__ qkt,
    int M, int N, int K, long bbat, long cbat, int nchunk)
{
  __shared__ bf16 a_s[64][40];
  __shared__ bf16 b_s[64][40];
  const int tid = threadIdx.x;
  const int z = blockIdx.z, stage = z >> 1, bat = z & 1;
  const float* Au = stage ? A2 : A;
  const float* biasu = stage ? bias2 : bias;
  const TBe* Bm = (stage ? B2 : B1) + bat * bbat;
  Cm += z * cbat;
  if (QKT) qkt += z * QKTSTR;
  const int m0 = blockIdx.y * 64, n0 = blockIdx.x * 64;
  const int w = tid >> 6, lane = tid & 63;
  const int l15 = lane & 15, oct = lane >> 4;

  f4v acc[4];
  #pragma unroll
  for (int i = 0; i < 4; ++i) acc[i] = (f4v){0.f, 0.f, 0.f, 0.f};

  const int a_i0 = tid >> 2, a_i1 = (tid & 3) * 8;
  const int b_i0 = tid >> 3, b_i1 = (tid & 7) * 8;

  s8v pa, pb;
  auto ldA = [&](int kc, s8v& d) {
    if (m0 + a_i0 < M) d = ld8(Au + (long)(m0 + a_i0) * K + kc * 32 + a_i1);
    else d = (s8v){0,0,0,0,0,0,0,0};
  };
  auto ldB = [&](int kc, s8v& d) {
    d = ld8(Bm + (long)(kc * 32 + b_i0) * N + n0 + b_i1);
  };

  ldA(0, pa); ldB(0, pb);
  for (int kc = 0; kc < nchunk; ++kc) {
    *(s8v*)&a_s[a_i0][a_i1] = pa;
    {
      const bf16* e = (const bf16*)&pb;
      #pragma unroll
      for (int j = 0; j < 8; ++j) b_s[b_i1 + j][b_i0] = e[j];
    }
    __syncthreads();
    if (kc + 1 < nchunk) { ldA(kc + 1, pa); ldB(kc + 1, pb); }
    s8v af = *(const s8v*)&a_s[w * 16 + l15][oct * 8];
    #pragma unroll
    for (int nt = 0; nt < 4; ++nt) {
      s8v bfr = *(const s8v*)&b_s[nt * 16 + l15][oct * 8];
      acc[nt] = __builtin_amdgcn_mfma_f32_16x16x32_bf16(af, bfr, acc[nt], 0, 0, 0);
    }
    __syncthreads();
  }
  const int gm_base = m0 + w * 16 + oct * 4;
  #pragma unroll
  for (int nt = 0; nt < 4; ++nt) {
    const int gn = n0 + nt * 16 + l15;
    #pragma unroll
    for (int r = 0; r < 4; ++r) {
      int gm = gm_base + r;
      if (gm < M) {
        float vv = acc[nt][r] + biasu[gm];
        if (QKT && gm < 64) {
          float vv2 = (gm < 32) ? vv * 1.44269504f : vv;   // q *= log2(e)
          qkt[(long)gn * 64 + gm] = __float2bfloat16(vv2);
        } else {
          Cm[(long)gm * N + gn] = __float2bfloat16(vv);
        }
      }
    }
  }
}

// ---- concat q/k(/v) weights+biases into fp32 [M][256] + [M] -----------------
__global__ __launch_bounds__(256) void cat_k(
    const float* __restrict__ wq, const float* __restrict__ bq,
    const float* __restrict__ wk, const float* __restrict__ bk,
    const float* __restrict__ wv, const float* __restrict__ bv,
    float* __restrict__ wcat, float* __restrict__ bcat, int M)
{
  int idx = blockIdx.x * 256 + threadIdx.x;
  int total = M << 8;
  if (idx < total) {
    int r = idx >> 8, c = idx & 255;
    float v;
    if (r < 32) v = wq[r * 256 + c];
    else if (r < 64) v = wk[(r - 32) * 256 + c];
    else v = wv[(r - 64) * 256 + c];
    wcat[idx] = v;
  } else if (idx < total + M) {
    int r = idx - total;
    bcat[r] = (r < 32) ? bq[r] : (r < 64) ? bk[r - 32] : bv[r - 64];
  }
}

// ---- both convs' weights: fp32 [O][C][9] -> bf16 [O][j*256+c] ---------------
__global__ __launch_bounds__(256) void cvtw2_k(
    const float* __restrict__ w1, const float* __restrict__ w2,
    bf16* __restrict__ o1, bf16* __restrict__ o2)
{
  const float* in = blockIdx.y ? w2 : w1;
  bf16* out = blockIdx.y ? o2 : o1;
  int idx = blockIdx.x * 256 + threadIdx.x;
  int o = idx / 2304, r = idx % 2304;
  int j = r >> 8, c = r & 255;
  out[idx] = __float2bfloat16(in[(o * 256 + c) * 9 + j]);
}

// ---- 16-elem row load/store helpers ----------------------------------------
__device__ inline void ld16(const bf16* p, float* v) {
  s8v r0 = *(const s8v*)p, r1 = *(const s8v*)(p + 8);
  const bf16* e0 = (const bf16*)&r0; const bf16* e1 = (const bf16*)&r1;
  #pragma unroll
  for (int j = 0; j < 8; ++j) { v[j] = __bfloat162float(e0[j]); v[8 + j] = __bfloat162float(e1[j]); }
}
__device__ inline void ld16(const float* p, float* v) {
  #pragma unroll
  for (int q = 0; q < 4; ++q) {
    float4 f = *(const float4*)(p + q * 4);
    v[q * 4 + 0] = f.x; v[q * 4 + 1] = f.y; v[q * 4 + 2] = f.z; v[q * 4 + 3] = f.w;
  }
}
__device__ inline void st16(bf16* p, const float* v) {
  s8v o0, o1v; bf16* f0 = (bf16*)&o0; bf16* f1 = (bf16*)&o1v;
  #pragma unroll
  for (int j = 0; j < 8; ++j) { f0[j] = __float2bfloat16(v[j]); f1[j] = __float2bfloat16(v[8 + j]); }
  *(s8v*)p = o0; *(s8v*)(p + 8) = o1v;
}
__device__ inline void st16(float* p, const float* v) {
  #pragma unroll
  for (int q = 0; q < 4; ++q) {
    float4 f; f.x = v[q * 4 + 0]; f.y = v[q * 4 + 1]; f.z = v[q * 4 + 2]; f.w = v[q * 4 + 3];
    *(float4*)(p + q * 4) = f;
  }
}

// ---- fused InstanceNorm: out = inorm(g*a + b) per row of 4096 --------------
template<typename TAe, typename TBe, typename TOe, int G>
__global__ __launch_bounds__(256) void inorm_k(
    const TAe* __restrict__ a, const TBe* __restrict__ b,
    const float* __restrict__ g, TOe* __restrict__ out)
{
  __shared__ float red[8];
  const int tid = threadIdx.x;
  const long base = (long)blockIdx.x * NPIX + tid * 16;
  float gv = G ? *g : 1.f;
  float va[16], vbv[16], v[16];
  ld16(a + base, va);
  ld16(b + base, vbv);
  #pragma unroll
  for (int j = 0; j < 16; ++j) v[j] = gv * va[j] + vbv[j];
  float sum = 0.f, sq = 0.f;
  #pragma unroll
  for (int j = 0; j < 16; ++j) { sum += v[j]; sq += v[j] * v[j]; }
  #pragma unroll
  for (int s = 32; s; s >>= 1) { sum += __shfl_xor(sum, s); sq += __shfl_xor(sq, s); }
  if ((tid & 63) == 0) { red[tid >> 6] = sum; red[4 + (tid >> 6)] = sq; }
  __syncthreads();
  sum = red[0] + red[1] + red[2] + red[3];
  sq  = red[4] + red[5] + red[6] + red[7];
  float mean = sum * (1.f / NPIX);
  float var  = fmaxf(sq * (1.f / NPIX) - mean * mean, 0.f);
  float rstd = rsqrtf(var + 1e-5f);
  float o[16];
  #pragma unroll
  for (int j = 0; j < 16; ++j) o[j] = (v[j] - mean) * rstd;
  st16(out + base, o);
}

// ---- host-side helpers ------------------------------------------------------
static const long CN = (long)CDIM * NPIX;

// fused flash attention: one kernel per nb slots (R2 structure)
static void attn_core(int nb, bf16* qkv, bf16* qkt, bf16* t0, hipStream_t stream)
{
  fattn_k<64><<<dim3(64, 2, nb), dim3(256), 0, stream>>>(qkt, qkv + 64 * NPIX, t0);
}

static void run_conv(const bf16* src, const bf16* wcvt, const float* cb,
                     bf16* dst, hipStream_t stream)
{
  conv_k<<<dim3(64, 2, 2), dim3(512), 0, stream>>>(src, wcvt, cb, dst);
}

// ---------------------------------------------------------------------------
extern "C" void kernel_launch(void* const* d_in, const int* in_sizes, int n_in,
                              void* d_out, int out_size, void* d_ws, size_t ws_size,
                              hipStream_t stream)
{
  (void)in_sizes; (void)n_in; (void)out_size; (void)ws_size;
  const float* x = (const float*)d_in[0];
  const float* y = (const float*)d_in[1];
  auto W = [&](int i) { return (const float*)d_in[i]; };

  char* wp = (char*)d_ws;
  auto take = [&](size_t nbytes) { char* p = wp; wp += (nbytes + 255) & ~(size_t)255; return p; };
  bf16*  qkv   = (bf16*)take((size_t)4 * QKVSTR * 2);
  bf16*  qkt   = (bf16*)take((size_t)4 * QKTSTR * 2);
  bf16*  t0    = (bf16*)take((size_t)4 * CN * 2);
  bf16*  u1    = (bf16*)take(2 * CN * 2);
  bf16*  u2    = (bf16*)take(2 * CN * 2);
  bf16*  u3    = (bf16*)take(2 * CN * 2);
  bf16*  u4    = (bf16*)take(2 * CN * 2);
  bf16*  wcvt1 = (bf16*)take((size_t)589824 * 2);
  bf16*  wcvt2 = (bf16*)take((size_t)589824 * 2);
  float* wcat1 = (float*)take((size_t)81920 * 4);
  float* bcat1 = (float*)take(320 * 4);
  float* wcat2 = (float*)take((size_t)81920 * 4);
  float* bcat2 = (float*)take(320 * 4);
  float* wqk   = (float*)take((size_t)16384 * 4);
  float* bqk   = (float*)take(64 * 4);
  bf16*  cvout = qkv;                                         // conv out (aliased)

  dim3 TB(256);

  // ---- prep: weight concat/convert ----
  cat_k<<<dim3(322), TB, 0, stream>>>(W(2), W(3), W(4), W(5), W(6), W(7), wcat1, bcat1, 320);
  cat_k<<<dim3(322), TB, 0, stream>>>(W(9), W(10), W(11), W(12), W(13), W(14), wcat2, bcat2, 320);
  cat_k<<<dim3(65),  TB, 0, stream>>>(W(16), W(17), W(18), W(19), nullptr, nullptr, wqk, bqk, 64);
  cvtw2_k<<<dim3(2304, 2), TB, 0, stream>>>(W(23), W(25), wcvt1, wcvt2);

  // ---- stages A+B attention together: z = stage*2 + batch ----
  proj_k<1,float><<<dim3(64,5,4), TB, 0, stream>>>(
      wcat1, wcat2, x, y, bcat1, bcat2, qkv, qkt, 320, NPIX, 256, CN, QKVSTR, 8);
  attn_core(4, qkv, qkt, t0, stream);

  // ---- out_1 / out_3 inorms ----
  inorm_k<bf16,float,bf16,1><<<dim3(512), TB, 0, stream>>>(t0, x, W(8), u1);
  inorm_k<bf16,float,bf16,1><<<dim3(512), TB, 0, stream>>>(t0 + 2 * CN, y, W(15), u3);

  // ---- conv1 -> out_2 ----
  run_conv(u1, wcvt1, W(24), cvout, stream);
  inorm_k<bf16,bf16,bf16,0><<<dim3(512), TB, 0, stream>>>(u1, cvout, nullptr, u2);

  // ---- stage C: q/k from out_2 (transposed), v from out_3 ----
  proj_k<1,bf16><<<dim3(64,1,2), TB, 0, stream>>>(
      wqk, wqk, u2, u2, bqk, bqk, qkv, qkt, 64, NPIX, 256, CN, QKVSTR, 8);
  proj_k<0,bf16><<<dim3(64,4,2), TB, 0, stream>>>(
      W(20), W(20), u3, u3, W(21), W(21), qkv + 64 * NPIX, qkt, 256, NPIX, 256, CN, QKVSTR, 8);
  attn_core(2, qkv, qkt, t0, stream);
  inorm_k<bf16,float,bf16,1><<<dim3(512), TB, 0, stream>>>(t0, y, W(22), u1);   // o1
  inorm_k<bf16,bf16,bf16,0><<<dim3(512), TB, 0, stream>>>(u1, u3, nullptr, u4); // o2
  run_conv(u4, wcvt2, W(26), cvout, stream);
  inorm_k<bf16,bf16,float,0><<<dim3(512), TB, 0, stream>>>(u4, cvout, nullptr, (float*)d_out);
}

// Round 8
// 366.675 us; speedup vs baseline: 1.1410x; 1.0401x over previous
//
#include <hip/hip_runtime.h>
#include <hip/hip_bf16.h>

typedef __hip_bfloat16 bf16;
typedef __attribute__((ext_vector_type(8))) short s8v;   // 8 bf16 = 4 VGPRs
typedef __attribute__((ext_vector_type(4))) short s4v;   // 4 bf16 = 8 bytes
typedef __attribute__((ext_vector_type(4))) float f4v;

#define NPIX 4096
#define CDIM 256
#define MN_ELEMS (1 << 20)        // CDIM * NPIX
#define QKVSTR (320L * NPIX)      // qkv per-slot stride (elems)
#define QKTSTR (64L * NPIX)       // qkt per-slot stride (elems)

#if __has_builtin(__builtin_amdgcn_exp2f)
#define EXP2F(x) __builtin_amdgcn_exp2f(x)
#else
#define EXP2F(x) exp2f(x)
#endif

// ---- async global->LDS, 16B per lane (dest = wave-uniform base + lane*16) ---
typedef __attribute__((address_space(1))) const unsigned int g_u32;
typedef __attribute__((address_space(3))) unsigned int l_u32;
__device__ __forceinline__ void glds16(const void* g, void* l) {
  __builtin_amdgcn_global_load_lds((g_u32*)g, (l_u32*)l, 16, 0, 0);
}

// ---- 8-element loaders -> bf16x8 (s8v) --------------------------------------
__device__ inline s8v ld8(const bf16* p) { return *(const s8v*)p; }
__device__ inline s8v ld8(const float* p) {
  float4 f0 = *(const float4*)p;
  float4 f1 = *(const float4*)(p + 4);
  s8v r; bf16* e = (bf16*)&r;
  e[0] = __float2bfloat16(f0.x); e[1] = __float2bfloat16(f0.y);
  e[2] = __float2bfloat16(f0.z); e[3] = __float2bfloat16(f0.w);
  e[4] = __float2bfloat16(f1.x); e[5] = __float2bfloat16(f1.y);
  e[6] = __float2bfloat16(f1.z); e[7] = __float2bfloat16(f1.w);
  return r;
}

// ---------------------------------------------------------------------------
// Fused flash-style attention — R2 math/layout, 8 thin waves (512 threads).
// out[c][n] = sum_m V[c][m] exp(S[n][m]) / lsum[n]
// qkt: [slot][4096][64] bf16 (q*log2e at d0..31, k at d32..63).
// Vg:  rows [c][m] m-contig at slot stride QKVSTR.  out: [slot][256][4096].
// S computed TRANSPOSED (mfma(k,q)); P written as swizzled ds_write_b64 into
// p_s[kk][n 64][m 32] (byte ^= ((n>>1)&3)<<4 on both sides).
// Wave roles (w = tid>>6, 8 waves):
//   S : (wr2 = w>>2: n-half) x (wc2 = w&3: m-quarter)  -> 4 MFMA + 16 exp
//   PV: (w>>1: c-quarter)    x (w&1: n-half)           -> 16 MFMA
// Same tiles as the 4-wave version, half the per-wave work -> 2x waves/SIMD
// (merged: 2 blocks/CU x 8 waves = 4 waves/SIMD) to hide the barrier drains.
// grid (64, 2, nslots), 512 threads.  LDS: k_s 8K + v_s 32K + p_s 16K = 56K.
// ---------------------------------------------------------------------------
__global__ __launch_bounds__(512) void fattn_k(
    const bf16* __restrict__ qkt, const bf16* __restrict__ Vg,
    bf16* __restrict__ out)
{
  __shared__ bf16 k_s[128 * 32];       // [m 128][32] (d=32..63 of qkt)
  __shared__ bf16 v_s[4 * 128 * 32];   // [kk][c 128][32]
  __shared__ bf16 p_s[4 * 64 * 32];    // [kk][n 64][32 m]; Q staged here first
  float* sums = (float*)k_s;           // [4 m-quarter][64 n] after loop

  const int tid = threadIdx.x;
  const int z = blockIdx.z;
  const int w = tid >> 6, lane = tid & 63;
  const int l15 = lane & 15, oct = lane >> 4;
  const int wr2 = w >> 2, wc2 = w & 3;     // S roles
  const int pc = w >> 1, pn = w & 1;       // PV roles
  const int n0 = blockIdx.x * 64, c0 = blockIdx.y * 128;
  const bf16* qk = qkt + (long)z * QKTSTR;
  const bf16* Vz = Vg + (long)z * QKVSTR;
  const int t2 = tid >> 2, t3 = (tid & 3) * 8;

  // ---- prologue: stage Q (tid<256 -> p_s rows 0..63), K(0), V(0) ----
  if (tid < 256)
    glds16(qk + (long)(n0 + t2) * 64 + t3, p_s + tid * 8);
  glds16(qk + (long)t2 * 64 + 32 + t3, k_s + tid * 8);
  #pragma unroll
  for (int g = 0; g < 4; ++g)
    glds16(Vz + (long)(c0 + t2) * 4096 + g * 32 + t3, v_s + g * 4096 + tid * 8);
  __syncthreads();

  s8v qf[2];
  #pragma unroll
  for (int st = 0; st < 2; ++st)
    qf[st] = *(const s8v*)(p_s + (wr2 * 32 + st * 16 + l15) * 32 + oct * 8);
  __syncthreads();   // all qf reads done before p_s is overwritten by P(0)

  f4v acc[2][2];
  #pragma unroll
  for (int i = 0; i < 2; ++i)
    #pragma unroll
    for (int j = 0; j < 2; ++j) acc[i][j] = (f4v){0.f, 0.f, 0.f, 0.f};
  float rs[2] = {0.f, 0.f};

  for (int i = 0; i < 32; ++i) {
    // ---- S^T phase: S[m][n] = k.q (q pre-scaled by log2e), exp2, pack -----
    s8v kf[2];
    #pragma unroll
    for (int nt = 0; nt < 2; ++nt)
      kf[nt] = *(const s8v*)(k_s + (wc2 * 32 + nt * 16 + l15) * 32 + oct * 8);
    #pragma unroll
    for (int st = 0; st < 2; ++st) {
      const int n = wr2 * 32 + st * 16 + l15;          // P row (lane-fixed)
      const int sw = ((n >> 1) & 3) << 4;              // intra-row byte XOR
      f4v sa[2];
      __builtin_amdgcn_s_setprio(1);
      #pragma unroll
      for (int nt = 0; nt < 2; ++nt) {
        f4v zz = (f4v){0.f, 0.f, 0.f, 0.f};
        sa[nt] = __builtin_amdgcn_mfma_f32_16x16x32_bf16(kf[nt], qf[st], zz, 0, 0, 0);
      }
      __builtin_amdgcn_s_setprio(0);
      #pragma unroll
      for (int nt = 0; nt < 2; ++nt) {
        // m = wc2*32 + nt*16 + oct*4 + r  ->  kk = wc2
        int byte = wc2 * 4096 + n * 64 + nt * 32 + oct * 8;
        byte ^= sw;
        s4v pk; bf16* pe = (bf16*)&pk;
        float rsum = 0.f;
        #pragma unroll
        for (int r = 0; r < 4; ++r) {
          float e = EXP2F(sa[nt][r]);
          rsum += e;
          pe[r] = __float2bfloat16(e);
        }
        rs[st] += rsum;
        *(s4v*)((char*)p_s + byte) = pk;
      }
    }
    __syncthreads();   // (1) P ready; k_s reads done
    // ---- PV phase: acc[c][n] += V[c][m] * P[n][m], K=128 ------------------
    #pragma unroll
    for (int kk = 0; kk < 4; ++kk) {
      s8v vf[2], pf[2];
      #pragma unroll
      for (int st = 0; st < 2; ++st)
        vf[st] = *(const s8v*)(v_s + kk * 4096 + (pc * 32 + st * 16 + l15) * 32 + oct * 8);
      #pragma unroll
      for (int nt = 0; nt < 2; ++nt) {
        const int n = pn * 32 + nt * 16 + l15;
        int byte = kk * 4096 + n * 64 + oct * 16;
        byte ^= ((n >> 1) & 3) << 4;
        pf[nt] = *(const s8v*)((const char*)p_s + byte);
      }
      __builtin_amdgcn_s_setprio(1);
      #pragma unroll
      for (int st = 0; st < 2; ++st)
        #pragma unroll
        for (int nt = 0; nt < 2; ++nt)
          acc[st][nt] = __builtin_amdgcn_mfma_f32_16x16x32_bf16(vf[st], pf[nt], acc[st][nt], 0, 0, 0);
      __builtin_amdgcn_s_setprio(0);
    }
    __syncthreads();   // (2) v_s/p_s reads done by all waves -> safe to restage
    if (i < 31) {
      const int m1 = (i + 1) * 128;
      glds16(qk + (long)(m1 + t2) * 64 + 32 + t3, k_s + tid * 8);
      #pragma unroll
      for (int g = 0; g < 4; ++g)
        glds16(Vz + (long)(c0 + t2) * 4096 + m1 + g * 32 + t3, v_s + g * 4096 + tid * 8);
      __syncthreads(); // (3) staged data landed (vmcnt drained by barrier)
    }
  }

  // ---- row-sum: reduce over octs, combine 4 m-quarters via LDS ------------
  #pragma unroll
  for (int st = 0; st < 2; ++st) {
    rs[st] += __shfl_xor(rs[st], 16);
    rs[st] += __shfl_xor(rs[st], 32);
  }
  if (lane < 16) {
    #pragma unroll
    for (int st = 0; st < 2; ++st)
      sums[wc2 * 64 + wr2 * 32 + st * 16 + l15] = rs[st];
  }
  __syncthreads();

  float rinv[2];
  #pragma unroll
  for (int nt = 0; nt < 2; ++nt) {
    const int n = pn * 32 + nt * 16 + l15;
    rinv[nt] = 1.f / (sums[n] + sums[64 + n] + sums[128 + n] + sums[192 + n]);
  }
  bf16* op = out + (long)z * ((long)CDIM * NPIX);
  #pragma unroll
  for (int st = 0; st < 2; ++st) {
    const int gc = c0 + pc * 32 + st * 16 + oct * 4;
    #pragma unroll
    for (int nt = 0; nt < 2; ++nt) {
      const int gn = n0 + pn * 32 + nt * 16 + l15;
      #pragma unroll
      for (int r = 0; r < 4; ++r)
        op[(long)(gc + r) * NPIX + gn] = __float2bfloat16(acc[st][nt][r] * rinv[nt]);
    }
  }
}

// ---------------------------------------------------------------------------
// Fused direct 3x3 conv: out[o][h*64+w] = bias[o] +
//   sum_{j=(dy,dx)} sum_c W[o][j*256+c] * Xpad[c][h+dy-1][w+dx-1]
// B-fragments read straight from the padded LDS tile ([row 3][wpos 66][c 64],
// wpos stride 66 elems = 33 words -> bank-conflict-free b128 reads).
// W: wcvt [o][j*256+c] bf16 (k-contig, matches A-frag).  X: [c][4096] bf16.
// grid (64 h, 2 o-half, 2 batch), 512 threads = 8 waves; wave w owns o-rows
// o0+w*16..+16, all 64 pixels of row h.  4 c-chunk passes x (9 taps x 2 kc).
// LDS 26.1 KB.
// ---------------------------------------------------------------------------
__global__ __launch_bounds__(512) void conv_k(
    const bf16* __restrict__ x, const bf16* __restrict__ wcvt,
    const float* __restrict__ bias, bf16* __restrict__ out)
{
  __shared__ bf16 lds[3 * 66 * 66];   // [row][wpos][c(64, 2 pad)]
  const int tid = threadIdx.x;
  const int h = blockIdx.x;
  const int o0 = blockIdx.y * 128;
  x   += (long)blockIdx.z * CDIM * NPIX;
  out += (long)blockIdx.z * CDIM * NPIX;

  const int w = tid >> 6, lane = tid & 63;
  const int l15 = lane & 15, oct = lane >> 4;

  // zero the w-pad columns once (wpos 0 and 65; never overwritten by staging)
  if (tid < 192) {
    int row = tid >> 6, c = tid & 63;
    lds[(row * 66 + 0) * 66 + c] = __float2bfloat16(0.f);
    lds[(row * 66 + 65) * 66 + c] = __float2bfloat16(0.f);
  }

  f4v acc[4];
  #pragma unroll
  for (int nf = 0; nf < 4; ++nf) acc[nf] = (f4v){0.f, 0.f, 0.f, 0.f};

  const int w2 = tid & 31, chi = tid >> 5;   // staging: w2 pixel-pair, chi c-sub
  const long arow = (long)(o0 + w * 16 + l15) * 2304;

  for (int cg = 0; cg < 4; ++cg) {
    __syncthreads();   // pad/compute(cg-1) reads done before overwrite
    #pragma unroll
    for (int it = 0; it < 12; ++it) {
      int row = it >> 2, cgi = it & 3;
      int c = cgi * 16 + chi;
      int hh = h + row - 1;
      unsigned int pix = 0;
      if ((unsigned)hh < 64u)
        pix = *(const unsigned int*)(x + (long)(cg * 64 + c) * 4096 + hh * 64 + w2 * 2);
      const bf16* pp = (const bf16*)&pix;
      lds[(row * 66 + (w2 * 2 + 1)) * 66 + c] = pp[0];
      lds[(row * 66 + (w2 * 2 + 2)) * 66 + c] = pp[1];
    }
    __syncthreads();   // tile(cg) ready

    #pragma unroll
    for (int j = 0; j < 9; ++j) {
      const int dy = j / 3, dx = j % 3;
      #pragma unroll
      for (int kc = 0; kc < 2; ++kc) {
        s8v af = *(const s8v*)(wcvt + arow + j * 256 + cg * 64 + kc * 32 + oct * 8);
        s8v bfv[4];
        #pragma unroll
        for (int nf = 0; nf < 4; ++nf)
          bfv[nf] = *(const s8v*)&lds[(dy * 66 + (nf * 16 + l15 + dx)) * 66 + kc * 32 + oct * 8];
        #pragma unroll
        for (int nf = 0; nf < 4; ++nf)
          acc[nf] = __builtin_amdgcn_mfma_f32_16x16x32_bf16(af, bfv[nf], acc[nf], 0, 0, 0);
      }
    }
  }

  // ---- epilogue: + bias, store ----
  #pragma unroll
  for (int nf = 0; nf < 4; ++nf) {
    const int gn = h * 64 + nf * 16 + l15;
    const int go = o0 + w * 16 + oct * 4;
    #pragma unroll
    for (int r = 0; r < 4; ++r)
      out[(long)(go + r) * NPIX + gn] = __float2bfloat16(acc[nf][r] + bias[go + r]);
  }
}

// ---------------------------------------------------------------------------
// Projection GEMM. z = slot; stage = z>>1 selects (A,bias,B) vs (A2,bias2,B2);
// batch = z&1 offsets B by bbat. QKT=1: rows gm<64 -> qkt transposed, with the
// q rows (gm<32) pre-scaled by log2(e) so fattn can use raw v_exp_f32.
// ---------------------------------------------------------------------------
template<int QKT, typename TBe>
__global__ __launch_bounds__(256) void proj_k(
    const float* __restrict__ A, const float* __restrict__ A2,
    const TBe* __restrict__ B1, const TBe* __restrict__ B2,
    const float* __restrict__ bias, const float* __restrict__ bias2,
    bf16* __restrict__ Cm, bf16* __restrict__ qkt,
    int M, int N, int K, long bbat, long cbat, int nchunk)
{
  __shared__ bf16 a_s[64][40];
  __shared__ bf16 b_s[64][40];
  const int tid = threadIdx.x;
  const int z = blockIdx.z, stage = z >> 1, bat = z & 1;
  const float* Au = stage ? A2 : A;
  const float* biasu = stage ? bias2 : bias;
  const TBe* Bm = (stage ? B2 : B1) + bat * bbat;
  Cm += z * cbat;
  if (QKT) qkt += z * QKTSTR;
  const int m0 = blockIdx.y * 64, n0 = blockIdx.x * 64;
  const int w = tid >> 6, lane = tid & 63;
  const int l15 = lane & 15, oct = lane >> 4;

  f4v acc[4];
  #pragma unroll
  for (int i = 0; i < 4; ++i) acc[i] = (f4v){0.f, 0.f, 0.f, 0.f};

  const int a_i0 = tid >> 2, a_i1 = (tid & 3) * 8;
  const int b_i0 = tid >> 3, b_i1 = (tid & 7) * 8;

  s8v pa, pb;
  auto ldA = [&](int kc, s8v& d) {
    if (m0 + a_i0 < M) d = ld8(Au + (long)(m0 + a_i0) * K + kc * 32 + a_i1);
    else d = (s8v){0,0,0,0,0,0,0,0};
  };
  auto ldB = [&](int kc, s8v& d) {
    d = ld8(Bm + (long)(kc * 32 + b_i0) * N + n0 + b_i1);
  };

  ldA(0, pa); ldB(0, pb);
  for (int kc = 0; kc < nchunk; ++kc) {
    *(s8v*)&a_s[a_i0][a_i1] = pa;
    {
      const bf16* e = (const bf16*)&pb;
      #pragma unroll
      for (int j = 0; j < 8; ++j) b_s[b_i1 + j][b_i0] = e[j];
    }
    __syncthreads();
    if (kc + 1 < nchunk) { ldA(kc + 1, pa); ldB(kc + 1, pb); }
    s8v af = *(const s8v*)&a_s[w * 16 + l15][oct * 8];
    #pragma unroll
    for (int nt = 0; nt < 4; ++nt) {
      s8v bfr = *(const s8v*)&b_s[nt * 16 + l15][oct * 8];
      acc[nt] = __builtin_amdgcn_mfma_f32_16x16x32_bf16(af, bfr, acc[nt], 0, 0, 0);
    }
    __syncthreads();
  }
  const int gm_base = m0 + w * 16 + oct * 4;
  #pragma unroll
  for (int nt = 0; nt < 4; ++nt) {
    const int gn = n0 + nt * 16 + l15;
    #pragma unroll
    for (int r = 0; r < 4; ++r) {
      int gm = gm_base + r;
      if (gm < M) {
        float vv = acc[nt][r] + biasu[gm];
        if (QKT && gm < 64) {
          float vv2 = (gm < 32) ? vv * 1.44269504f : vv;   // q *= log2(e)
          qkt[(long)gn * 64 + gm] = __float2bfloat16(vv2);
        } else {
          Cm[(long)gm * N + gn] = __float2bfloat16(vv);
        }
      }
    }
  }
}

// ---- concat q/k(/v) weights+biases into fp32 [M][256] + [M] -----------------
__global__ __launch_bounds__(256) void cat_k(
    const float* __restrict__ wq, const float* __restrict__ bq,
    const float* __restrict__ wk, const float* __restrict__ bk,
    const float* __restrict__ wv, const float* __restrict__ bv,
    float* __restrict__ wcat, float* __restrict__ bcat, int M)
{
  int idx = blockIdx.x * 256 + threadIdx.x;
  int total = M << 8;
  if (idx < total) {
    int r = idx >> 8, c = idx & 255;
    float v;
    if (r < 32) v = wq[r * 256 + c];
    else if (r < 64) v = wk[(r - 32) * 256 + c];
    else v = wv[(r - 64) * 256 + c];
    wcat[idx] = v;
  } else if (idx < total + M) {
    int r = idx - total;
    bcat[r] = (r < 32) ? bq[r] : (r < 64) ? bk[r - 32] : bv[r - 64];
  }
}

// ---- both convs' weights: fp32 [O][C][9] -> bf16 [O][j*256+c] ---------------
__global__ __launch_bounds__(256) void cvtw2_k(
    const float* __restrict__ w1, const float* __restrict__ w2,
    bf16* __restrict__ o1, bf16* __restrict__ o2)
{
  const float* in = blockIdx.y ? w2 : w1;
  bf16* out = blockIdx.y ? o2 : o1;
  int idx = blockIdx.x * 256 + threadIdx.x;
  int o = idx / 2304, r = idx % 2304;
  int j = r >> 8, c = r & 255;
  out[idx] = __float2bfloat16(in[(o * 256 + c) * 9 + j]);
}

// ---- 16-elem row load/store helpers ----------------------------------------
__device__ inline void ld16(const bf16* p, float* v) {
  s8v r0 = *(const s8v*)p, r1 = *(const s8v*)(p + 8);
  const bf16* e0 = (const bf16*)&r0; const bf16* e1 = (const bf16*)&r1;
  #pragma unroll
  for (int j = 0; j < 8; ++j) { v[j] = __bfloat162float(e0[j]); v[8 + j] = __bfloat162float(e1[j]); }
}
__device__ inline void ld16(const float* p, float* v) {
  #pragma unroll
  for (int q = 0; q < 4; ++q) {
    float4 f = *(const float4*)(p + q * 4);
    v[q * 4 + 0] = f.x; v[q * 4 + 1] = f.y; v[q * 4 + 2] = f.z; v[q * 4 + 3] = f.w;
  }
}
__device__ inline void st16(bf16* p, const float* v) {
  s8v o0, o1v; bf16* f0 = (bf16*)&o0; bf16* f1 = (bf16*)&o1v;
  #pragma unroll
  for (int j = 0; j < 8; ++j) { f0[j] = __float2bfloat16(v[j]); f1[j] = __float2bfloat16(v[8 + j]); }
  *(s8v*)p = o0; *(s8v*)(p + 8) = o1v;
}
__device__ inline void st16(float* p, const float* v) {
  #pragma unroll
  for (int q = 0; q < 4; ++q) {
    float4 f; f.x = v[q * 4 + 0]; f.y = v[q * 4 + 1]; f.z = v[q * 4 + 2]; f.w = v[q * 4 + 3];
    *(float4*)(p + q * 4) = f;
  }
}

// ---- fused InstanceNorm: out = inorm(g*a + b) per row of 4096 --------------
template<typename TAe, typename TBe, typename TOe, int G>
__global__ __launch_bounds__(256) void inorm_k(
    const TAe* __restrict__ a, const TBe* __restrict__ b,
    const float* __restrict__ g, TOe* __restrict__ out)
{
  __shared__ float red[8];
  const int tid = threadIdx.x;
  const long base = (long)blockIdx.x * NPIX + tid * 16;
  float gv = G ? *g : 1.f;
  float va[16], vbv[16], v[16];
  ld16(a + base, va);
  ld16(b + base, vbv);
  #pragma unroll
  for (int j = 0; j < 16; ++j) v[j] = gv * va[j] + vbv[j];
  float sum = 0.f, sq = 0.f;
  #pragma unroll
  for (int j = 0; j < 16; ++j) { sum += v[j]; sq += v[j] * v[j]; }
  #pragma unroll
  for (int s = 32; s; s >>= 1) { sum += __shfl_xor(sum, s); sq += __shfl_xor(sq, s); }
  if ((tid & 63) == 0) { red[tid >> 6] = sum; red[4 + (tid >> 6)] = sq; }
  __syncthreads();
  sum = red[0] + red[1] + red[2] + red[3];
  sq  = red[4] + red[5] + red[6] + red[7];
  float mean = sum * (1.f / NPIX);
  float var  = fmaxf(sq * (1.f / NPIX) - mean * mean, 0.f);
  float rstd = rsqrtf(var + 1e-5f);
  float o[16];
  #pragma unroll
  for (int j = 0; j < 16; ++j) o[j] = (v[j] - mean) * rstd;
  st16(out + base, o);
}

// ---- host-side helpers ------------------------------------------------------
static const long CN = (long)CDIM * NPIX;

// fused flash attention: one kernel per nb slots
static void attn_core(int nb, bf16* qkv, bf16* qkt, bf16* t0, hipStream_t stream)
{
  fattn_k<<<dim3(64, 2, nb), dim3(512), 0, stream>>>(qkt, qkv + 64 * NPIX, t0);
}

static void run_conv(const bf16* src, const bf16* wcvt, const float* cb,
                     bf16* dst, hipStream_t stream)
{
  conv_k<<<dim3(64, 2, 2), dim3(512), 0, stream>>>(src, wcvt, cb, dst);
}

// ---------------------------------------------------------------------------
extern "C" void kernel_launch(void* const* d_in, const int* in_sizes, int n_in,
                              void* d_out, int out_size, void* d_ws, size_t ws_size,
                              hipStream_t stream)
{
  (void)in_sizes; (void)n_in; (void)out_size; (void)ws_size;
  const float* x = (const float*)d_in[0];
  const float* y = (const float*)d_in[1];
  auto W = [&](int i) { return (const float*)d_in[i]; };

  char* wp = (char*)d_ws;
  auto take = [&](size_t nbytes) { char* p = wp; wp += (nbytes + 255) & ~(size_t)255; return p; };
  bf16*  qkv   = (bf16*)take((size_t)4 * QKVSTR * 2);
  bf16*  qkt   = (bf16*)take((size_t)4 * QKTSTR * 2);
  bf16*  t0    = (bf16*)take((size_t)4 * CN * 2);
  bf16*  u1    = (bf16*)take(2 * CN * 2);
  bf16*  u2    = (bf16*)take(2 * CN * 2);
  bf16*  u3    = (bf16*)take(2 * CN * 2);
  bf16*  u4    = (bf16*)take(2 * CN * 2);
  bf16*  wcvt1 = (bf16*)take((size_t)589824 * 2);
  bf16*  wcvt2 = (bf16*)take((size_t)589824 * 2);
  float* wcat1 = (float*)take((size_t)81920 * 4);
  float* bcat1 = (float*)take(320 * 4);
  float* wcat2 = (float*)take((size_t)81920 * 4);
  float* bcat2 = (float*)take(320 * 4);
  float* wqk   = (float*)take((size_t)16384 * 4);
  float* bqk   = (float*)take(64 * 4);
  bf16*  cvout = qkv;                                         // conv out (aliased)

  dim3 TB(256);

  // ---- prep: weight concat/convert ----
  cat_k<<<dim3(322), TB, 0, stream>>>(W(2), W(3), W(4), W(5), W(6), W(7), wcat1, bcat1, 320);
  cat_k<<<dim3(322), TB, 0, stream>>>(W(9), W(10), W(11), W(12), W(13), W(14), wcat2, bcat2, 320);
  cat_k<<<dim3(65),  TB, 0, stream>>>(W(16), W(17), W(18), W(19), nullptr, nullptr, wqk, bqk, 64);
  cvtw2_k<<<dim3(2304, 2), TB, 0, stream>>>(W(23), W(25), wcvt1, wcvt2);

  // ---- stages A+B attention together: z = stage*2 + batch ----
  proj_k<1,float><<<dim3(64,5,4), TB, 0, stream>>>(
      wcat1, wcat2, x, y, bcat1, bcat2, qkv, qkt, 320, NPIX, 256, CN, QKVSTR, 8);
  attn_core(4, qkv, qkt, t0, stream);

  // ---- out_1 / out_3 inorms ----
  inorm_k<bf16,float,bf16,1><<<dim3(512), TB, 0, stream>>>(t0, x, W(8), u1);
  inorm_k<bf16,float,bf16,1><<<dim3(512), TB, 0, stream>>>(t0 + 2 * CN, y, W(15), u3);

  // ---- conv1 -> out_2 ----
  run_conv(u1, wcvt1, W(24), cvout, stream);
  inorm_k<bf16,bf16,bf16,0><<<dim3(512), TB, 0, stream>>>(u1, cvout, nullptr, u2);

  // ---- stage C: q/k from out_2 (transposed), v from out_3 ----
  proj_k<1,bf16><<<dim3(64,1,2), TB, 0, stream>>>(
      wqk, wqk, u2, u2, bqk, bqk, qkv, qkt, 64, NPIX, 256, CN, QKVSTR, 8);
  proj_k<0,bf16><<<dim3(64,4,2), TB, 0, stream>>>(
      W(20), W(20), u3, u3, W(21), W(21), qkv + 64 * NPIX, qkt, 256, NPIX, 256, CN, QKVSTR, 8);
  attn_core(2, qkv, qkt, t0, stream);
  inorm_k<bf16,float,bf16,1><<<dim3(512), TB, 0, stream>>>(t0, y, W(22), u1);   // o1
  inorm_k<bf16,bf16,bf16,0><<<dim3(512), TB, 0, stream>>>(u1, u3, nullptr, u4); // o2
  run_conv(u4, wcvt2, W(26), cvout, stream);
  inorm_k<bf16,bf16,float,0><<<dim3(512), TB, 0, stream>>>(u4, cvout, nullptr, (float*)d_out);
}

// Round 9
// 355.894 us; speedup vs baseline: 1.1756x; 1.0303x over previous
//
#include <hip/hip_runtime.h>
#include <hip/hip_bf16.h>

typedef __hip_bfloat16 bf16;
typedef __attribute__((ext_vector_type(8))) short s8v;   // 8 bf16 = 4 VGPRs
typedef __attribute__((ext_vector_type(4))) short s4v;   // 4 bf16 = 8 bytes
typedef __attribute__((ext_vector_type(4))) float f4v;

#define NPIX 4096
#define CDIM 256
#define MN_ELEMS (1 << 20)        // CDIM * NPIX
#define QKVSTR (320L * NPIX)      // qkv per-slot stride (elems)
#define QKTSTR (64L * NPIX)       // qkt per-slot stride (elems)

#if __has_builtin(__builtin_amdgcn_exp2f)
#define EXP2F(x) __builtin_amdgcn_exp2f(x)
#else
#define EXP2F(x) exp2f(x)
#endif

// ---- async global->LDS, 16B per lane (dest = wave-uniform base + lane*16) ---
typedef __attribute__((address_space(1))) const unsigned int g_u32;
typedef __attribute__((address_space(3))) unsigned int l_u32;
__device__ __forceinline__ void glds16(const void* g, void* l) {
  __builtin_amdgcn_global_load_lds((g_u32*)g, (l_u32*)l, 16, 0, 0);
}

// ---- 8-element loaders -> bf16x8 (s8v) --------------------------------------
__device__ inline s8v ld8(const bf16* p) { return *(const s8v*)p; }
__device__ inline s8v ld8(const float* p) {
  float4 f0 = *(const float4*)p;
  float4 f1 = *(const float4*)(p + 4);
  s8v r; bf16* e = (bf16*)&r;
  e[0] = __float2bfloat16(f0.x); e[1] = __float2bfloat16(f0.y);
  e[2] = __float2bfloat16(f0.z); e[3] = __float2bfloat16(f0.w);
  e[4] = __float2bfloat16(f1.x); e[5] = __float2bfloat16(f1.y);
  e[6] = __float2bfloat16(f1.z); e[7] = __float2bfloat16(f1.w);
  return r;
}

// ---------------------------------------------------------------------------
// Fused flash-style attention — 8 thin waves (512 thr), ALL LDS streams
// XOR-swizzled to <=2-way bank conflicts.
// out[c][n] = sum_m V[c][m] exp(S[n][m]) / lsum[n]
// qkt: [slot][4096][64] bf16 (q*log2e at d0..31, k at d32..63).
// Vg:  rows [c][m] m-contig at slot stride QKVSTR.  out: [slot][256][4096].
// Swizzle (all [row][32-elem] tiles): byte-in-row ^= ((row>>1)&3)<<4.
// k_s/v_s/Q are filled by glds16 (linear LDS dest) with the PER-LANE GLOBAL
// SOURCE column pre-permuted by the same XOR (rule #21 / m173 pattern) —
// coalescing unaffected (permutation stays within each 64B segment).
// Wave roles (w = tid>>6, 8 waves):
//   S : (wr2 = w>>2: n-half) x (wc2 = w&3: m-quarter)  -> 4 MFMA + 16 exp
//   PV: (pc = w>>1: c-quarter of CB) x (pn = w&1: n-half)
// grid (64, 256/CB, nslots), 512 threads.
// LDS: CB=128 -> 8+32+16 = 56K (2 blk/CU); CB=64 -> 8+16+16 = 40K.
// ---------------------------------------------------------------------------
template<int CB>
__global__ __launch_bounds__(512) void fattn_k(
    const bf16* __restrict__ qkt, const bf16* __restrict__ Vg,
    bf16* __restrict__ out)
{
  constexpr int SC = CB / 64;          // PV c-frags per wave
  __shared__ bf16 k_s[128 * 32];       // [m 128][32] (d=32..63, swizzled rows)
  __shared__ bf16 v_s[4 * CB * 32];    // [kk][c CB][32] (swizzled rows)
  __shared__ bf16 p_s[4 * 64 * 32];    // [kk][n 64][32 m] (swizzled rows)
  float* sums = (float*)k_s;           // [4 m-quarter][64 n] after loop

  const int tid = threadIdx.x;
  const int z = blockIdx.z;
  const int w = tid >> 6, lane = tid & 63;
  const int l15 = lane & 15, oct = lane >> 4;
  const int wr2 = w >> 2, wc2 = w & 3;     // S roles
  const int pc = w >> 1, pn = w & 1;       // PV roles
  const int n0 = blockIdx.x * 64, c0 = blockIdx.y * CB;
  const bf16* qk = qkt + (long)z * QKTSTR;
  const bf16* Vz = Vg + (long)z * QKVSTR;

  // staging source column pre-swizzle: row = tid>>2 (mod rows), quarter = tid&3
  const int t2 = tid >> 2;
  const int kq3 = ((tid & 3) ^ ((t2 >> 1) & 3)) * 8;      // for k_s / Q (row=t2)
  const int vrow = t2 & (CB - 1);                          // v_s row
  const int vq3 = ((tid & 3) ^ ((vrow >> 1) & 3)) * 8;     // for v_s

  auto stageK = [&](int m) {
    glds16(qk + (long)(m + t2) * 64 + 32 + kq3, k_s + tid * 8);
  };
  auto stageV = [&](int m) {
    #pragma unroll
    for (int it = 0; it < CB / 32; ++it) {
      const int flat = it * 4096 + tid * 8;
      const int g = flat / (CB * 32);
      glds16(Vz + (long)(c0 + vrow) * 4096 + m + g * 32 + vq3, v_s + flat);
    }
  };

  // ---- prologue: stage Q (tid<256 -> p_s rows 0..63, swizzled), K(0), V(0) --
  if (tid < 256)
    glds16(qk + (long)(n0 + t2) * 64 + kq3, p_s + tid * 8);
  stageK(0);
  stageV(0);
  __syncthreads();

  s8v qf[2];
  #pragma unroll
  for (int st = 0; st < 2; ++st) {
    const int row = wr2 * 32 + st * 16 + l15;
    int byte = row * 64 + oct * 16;
    byte ^= ((row >> 1) & 3) << 4;
    qf[st] = *(const s8v*)((const char*)p_s + byte);
  }
  __syncthreads();   // all qf reads done before p_s is overwritten by P(0)

  f4v acc[SC][2];
  #pragma unroll
  for (int i = 0; i < SC; ++i)
    #pragma unroll
    for (int j = 0; j < 2; ++j) acc[i][j] = (f4v){0.f, 0.f, 0.f, 0.f};
  float rs[2] = {0.f, 0.f};

  for (int i = 0; i < 32; ++i) {
    // ---- S^T phase: S[m][n] = k.q (q pre-scaled by log2e), exp2, pack -----
    s8v kf[2];
    #pragma unroll
    for (int nt = 0; nt < 2; ++nt) {
      const int row = wc2 * 32 + nt * 16 + l15;
      int byte = row * 64 + oct * 16;
      byte ^= ((row >> 1) & 3) << 4;
      kf[nt] = *(const s8v*)((const char*)k_s + byte);
    }
    #pragma unroll
    for (int st = 0; st < 2; ++st) {
      const int n = wr2 * 32 + st * 16 + l15;          // P row (lane-fixed)
      const int sw = ((n >> 1) & 3) << 4;              // intra-row byte XOR
      f4v sa[2];
      __builtin_amdgcn_s_setprio(1);
      #pragma unroll
      for (int nt = 0; nt < 2; ++nt) {
        f4v zz = (f4v){0.f, 0.f, 0.f, 0.f};
        sa[nt] = __builtin_amdgcn_mfma_f32_16x16x32_bf16(kf[nt], qf[st], zz, 0, 0, 0);
      }
      __builtin_amdgcn_s_setprio(0);
      #pragma unroll
      for (int nt = 0; nt < 2; ++nt) {
        // m = wc2*32 + nt*16 + oct*4 + r  ->  kk = wc2
        int byte = wc2 * 4096 + n * 64 + nt * 32 + oct * 8;
        byte ^= sw;
        s4v pk; bf16* pe = (bf16*)&pk;
        float rsum = 0.f;
        #pragma unroll
        for (int r = 0; r < 4; ++r) {
          float e = EXP2F(sa[nt][r]);
          rsum += e;
          pe[r] = __float2bfloat16(e);
        }
        rs[st] += rsum;
        *(s4v*)((char*)p_s + byte) = pk;
      }
    }
    __syncthreads();   // (1) P ready; k_s reads done
    // ---- PV phase: acc[c][n] += V[c][m] * P[n][m], K=128 ------------------
    #pragma unroll
    for (int kk = 0; kk < 4; ++kk) {
      s8v vf[SC], pf[2];
      #pragma unroll
      for (int st = 0; st < SC; ++st) {
        const int row = pc * (CB / 4) + st * 16 + l15;
        int byte = kk * (CB * 64) + row * 64 + oct * 16;
        byte ^= ((row >> 1) & 3) << 4;
        vf[st] = *(const s8v*)((const char*)v_s + byte);
      }
      #pragma unroll
      for (int nt = 0; nt < 2; ++nt) {
        const int n = pn * 32 + nt * 16 + l15;
        int byte = kk * 4096 + n * 64 + oct * 16;
        byte ^= ((n >> 1) & 3) << 4;
        pf[nt] = *(const s8v*)((const char*)p_s + byte);
      }
      __builtin_amdgcn_s_setprio(1);
      #pragma unroll
      for (int st = 0; st < SC; ++st)
        #pragma unroll
        for (int nt = 0; nt < 2; ++nt)
          acc[st][nt] = __builtin_amdgcn_mfma_f32_16x16x32_bf16(vf[st], pf[nt], acc[st][nt], 0, 0, 0);
      __builtin_amdgcn_s_setprio(0);
    }
    __syncthreads();   // (2) v_s/p_s reads done by all waves -> safe to restage
    if (i < 31) {
      const int m1 = (i + 1) * 128;
      stageK(m1);
      stageV(m1);
      __syncthreads(); // (3) staged data landed (vmcnt drained by barrier)
    }
  }

  // ---- row-sum: reduce over octs, combine 4 m-quarters via LDS ------------
  #pragma unroll
  for (int st = 0; st < 2; ++st) {
    rs[st] += __shfl_xor(rs[st], 16);
    rs[st] += __shfl_xor(rs[st], 32);
  }
  if (lane < 16) {
    #pragma unroll
    for (int st = 0; st < 2; ++st)
      sums[wc2 * 64 + wr2 * 32 + st * 16 + l15] = rs[st];
  }
  __syncthreads();

  float rinv[2];
  #pragma unroll
  for (int nt = 0; nt < 2; ++nt) {
    const int n = pn * 32 + nt * 16 + l15;
    rinv[nt] = 1.f / (sums[n] + sums[64 + n] + sums[128 + n] + sums[192 + n]);
  }
  bf16* op = out + (long)z * ((long)CDIM * NPIX);
  #pragma unroll
  for (int st = 0; st < SC; ++st) {
    const int gc = c0 + pc * (CB / 4) + st * 16 + oct * 4;
    #pragma unroll
    for (int nt = 0; nt < 2; ++nt) {
      const int gn = n0 + pn * 32 + nt * 16 + l15;
      #pragma unroll
      for (int r = 0; r < 4; ++r)
        op[(long)(gc + r) * NPIX + gn] = __float2bfloat16(acc[st][nt][r] * rinv[nt]);
    }
  }
}

// ---------------------------------------------------------------------------
// Fused direct 3x3 conv: out[o][h*64+w] = bias[o] +
//   sum_{j=(dy,dx)} sum_c W[o][j*256+c] * Xpad[c][h+dy-1][w+dx-1]
// B-fragments read straight from the padded LDS tile ([row 3][wpos 66][c 64],
// wpos stride 66 elems = 33 words -> bank-conflict-free b128 reads).
// W: wcvt [o][j*256+c] bf16 (k-contig, matches A-frag).  X: [c][4096] bf16.
// grid (64 h, 2 o-half, 2 batch), 512 threads = 8 waves; wave w owns o-rows
// o0+w*16..+16, all 64 pixels of row h.  4 c-chunk passes x (9 taps x 2 kc).
// LDS 26.1 KB.
// ---------------------------------------------------------------------------
__global__ __launch_bounds__(512) void conv_k(
    const bf16* __restrict__ x, const bf16* __restrict__ wcvt,
    const float* __restrict__ bias, bf16* __restrict__ out)
{
  __shared__ bf16 lds[3 * 66 * 66];   // [row][wpos][c(64, 2 pad)]
  const int tid = threadIdx.x;
  const int h = blockIdx.x;
  const int o0 = blockIdx.y * 128;
  x   += (long)blockIdx.z * CDIM * NPIX;
  out += (long)blockIdx.z * CDIM * NPIX;

  const int w = tid >> 6, lane = tid & 63;
  const int l15 = lane & 15, oct = lane >> 4;

  // zero the w-pad columns once (wpos 0 and 65; never overwritten by staging)
  if (tid < 192) {
    int row = tid >> 6, c = tid & 63;
    lds[(row * 66 + 0) * 66 + c] = __float2bfloat16(0.f);
    lds[(row * 66 + 65) * 66 + c] = __float2bfloat16(0.f);
  }

  f4v acc[4];
  #pragma unroll
  for (int nf = 0; nf < 4; ++nf) acc[nf] = (f4v){0.f, 0.f, 0.f, 0.f};

  const int w2 = tid & 31, chi = tid >> 5;   // staging: w2 pixel-pair, chi c-sub
  const long arow = (long)(o0 + w * 16 + l15) * 2304;

  for (int cg = 0; cg < 4; ++cg) {
    __syncthreads();   // pad/compute(cg-1) reads done before overwrite
    #pragma unroll
    for (int it = 0; it < 12; ++it) {
      int row = it >> 2, cgi = it & 3;
      int c = cgi * 16 + chi;
      int hh = h + row - 1;
      unsigned int pix = 0;
      if ((unsigned)hh < 64u)
        pix = *(const unsigned int*)(x + (long)(cg * 64 + c) * 4096 + hh * 64 + w2 * 2);
      const bf16* pp = (const bf16*)&pix;
      lds[(row * 66 + (w2 * 2 + 1)) * 66 + c] = pp[0];
      lds[(row * 66 + (w2 * 2 + 2)) * 66 + c] = pp[1];
    }
    __syncthreads();   // tile(cg) ready

    #pragma unroll
    for (int j = 0; j < 9; ++j) {
      const int dy = j / 3, dx = j % 3;
      #pragma unroll
      for (int kc = 0; kc < 2; ++kc) {
        s8v af = *(const s8v*)(wcvt + arow + j * 256 + cg * 64 + kc * 32 + oct * 8);
        s8v bfv[4];
        #pragma unroll
        for (int nf = 0; nf < 4; ++nf)
          bfv[nf] = *(const s8v*)&lds[(dy * 66 + (nf * 16 + l15 + dx)) * 66 + kc * 32 + oct * 8];
        #pragma unroll
        for (int nf = 0; nf < 4; ++nf)
          acc[nf] = __builtin_amdgcn_mfma_f32_16x16x32_bf16(af, bfv[nf], acc[nf], 0, 0, 0);
      }
    }
  }

  // ---- epilogue: + bias, store ----
  #pragma unroll
  for (int nf = 0; nf < 4; ++nf) {
    const int gn = h * 64 + nf * 16 + l15;
    const int go = o0 + w * 16 + oct * 4;
    #pragma unroll
    for (int r = 0; r < 4; ++r)
      out[(long)(go + r) * NPIX + gn] = __float2bfloat16(acc[nf][r] + bias[go + r]);
  }
}

// ---------------------------------------------------------------------------
// Projection GEMM. z = slot; stage = z>>1 selects (A,bias,B) vs (A2,bias2,B2);
// batch = z&1 offsets B by bbat. QKT=1: rows gm<64 -> qkt transposed, with the
// q rows (gm<32) pre-scaled by log2(e) so fattn can use raw v_exp_f32.
// ---------------------------------------------------------------------------
template<int QKT, typename TBe>
__global__ __launch_bounds__(256) void proj_k(
    const float* __restrict__ A, const float* __restrict__ A2,
    const TBe* __restrict__ B1, const TBe* __restrict__ B2,
    const float* __restrict__ bias, const float* __restrict__ bias2,
    bf16* __restrict__ Cm, bf16* __restrict__ qkt,
    int M, int N, int K, long bbat, long cbat, int nchunk)
{
  __shared__ bf16 a_s[64][40];
  __shared__ bf16 b_s[64][40];
  const int tid = threadIdx.x;
  const int z = blockIdx.z, stage = z >> 1, bat = z & 1;
  const float* Au = stage ? A2 : A;
  const float* biasu = stage ? bias2 : bias;
  const TBe* Bm = (stage ? B2 : B1) + bat * bbat;
  Cm += z * cbat;
  if (QKT) qkt += z * QKTSTR;
  const int m0 = blockIdx.y * 64, n0 = blockIdx.x * 64;
  const int w = tid >> 6, lane = tid & 63;
  const int l15 = lane & 15, oct = lane >> 4;

  f4v acc[4];
  #pragma unroll
  for (int i = 0; i < 4; ++i) acc[i] = (f4v){0.f, 0.f, 0.f, 0.f};

  const int a_i0 = tid >> 2, a_i1 = (tid & 3) * 8;
  const int b_i0 = tid >> 3, b_i1 = (tid & 7) * 8;

  s8v pa, pb;
  auto ldA = [&](int kc, s8v& d) {
    if (m0 + a_i0 < M) d = ld8(Au + (long)(m0 + a_i0) * K + kc * 32 + a_i1);
    else d = (s8v){0,0,0,0,0,0,0,0};
  };
  auto ldB = [&](int kc, s8v& d) {
    d = ld8(Bm + (long)(kc * 32 + b_i0) * N + n0 + b_i1);
  };

  ldA(0, pa); ldB(0, pb);
  for (int kc = 0; kc < nchunk; ++kc) {
    *(s8v*)&a_s[a_i0][a_i1] = pa;
    {
      const bf16* e = (const bf16*)&pb;
      #pragma unroll
      for (int j = 0; j < 8; ++j) b_s[b_i1 + j][b_i0] = e[j];
    }
    __syncthreads();
    if (kc + 1 < nchunk) { ldA(kc + 1, pa); ldB(kc + 1, pb); }
    s8v af = *(const s8v*)&a_s[w * 16 + l15][oct * 8];
    #pragma unroll
    for (int nt = 0; nt < 4; ++nt) {
      s8v bfr = *(const s8v*)&b_s[nt * 16 + l15][oct * 8];
      acc[nt] = __builtin_amdgcn_mfma_f32_16x16x32_bf16(af, bfr, acc[nt], 0, 0, 0);
    }
    __syncthreads();
  }
  const int gm_base = m0 + w * 16 + oct * 4;
  #pragma unroll
  for (int nt = 0; nt < 4; ++nt) {
    const int gn = n0 + nt * 16 + l15;
    #pragma unroll
    for (int r = 0; r < 4; ++r) {
      int gm = gm_base + r;
      if (gm < M) {
        float vv = acc[nt][r] + biasu[gm];
        if (QKT && gm < 64) {
          float vv2 = (gm < 32) ? vv * 1.44269504f : vv;   // q *= log2(e)
          qkt[(long)gn * 64 + gm] = __float2bfloat16(vv2);
        } else {
          Cm[(long)gm * N + gn] = __float2bfloat16(vv);
        }
      }
    }
  }
}

// ---- concat q/k(/v) weights+biases into fp32 [M][256] + [M] -----------------
__global__ __launch_bounds__(256) void cat_k(
    const float* __restrict__ wq, const float* __restrict__ bq,
    const float* __restrict__ wk, const float* __restrict__ bk,
    const float* __restrict__ wv, const float* __restrict__ bv,
    float* __restrict__ wcat, float* __restrict__ bcat, int M)
{
  int idx = blockIdx.x * 256 + threadIdx.x;
  int total = M << 8;
  if (idx < total) {
    int r = idx >> 8, c = idx & 255;
    float v;
    if (r < 32) v = wq[r * 256 + c];
    else if (r < 64) v = wk[(r - 32) * 256 + c];
    else v = wv[(r - 64) * 256 + c];
    wcat[idx] = v;
  } else if (idx < total + M) {
    int r = idx - total;
    bcat[r] = (r < 32) ? bq[r] : (r < 64) ? bk[r - 32] : bv[r - 64];
  }
}

// ---- both convs' weights: fp32 [O][C][9] -> bf16 [O][j*256+c] ---------------
__global__ __launch_bounds__(256) void cvtw2_k(
    const float* __restrict__ w1, const float* __restrict__ w2,
    bf16* __restrict__ o1, bf16* __restrict__ o2)
{
  const float* in = blockIdx.y ? w2 : w1;
  bf16* out = blockIdx.y ? o2 : o1;
  int idx = blockIdx.x * 256 + threadIdx.x;
  int o = idx / 2304, r = idx % 2304;
  int j = r >> 8, c = r & 255;
  out[idx] = __float2bfloat16(in[(o * 256 + c) * 9 + j]);
}

// ---- 16-elem row load/store helpers ----------------------------------------
__device__ inline void ld16(const bf16* p, float* v) {
  s8v r0 = *(const s8v*)p, r1 = *(const s8v*)(p + 8);
  const bf16* e0 = (const bf16*)&r0; const bf16* e1 = (const bf16*)&r1;
  #pragma unroll
  for (int j = 0; j < 8; ++j) { v[j] = __bfloat162float(e0[j]); v[8 + j] = __bfloat162float(e1[j]); }
}
__device__ inline void ld16(const float* p, float* v) {
  #pragma unroll
  for (int q = 0; q < 4; ++q) {
    float4 f = *(const float4*)(p + q * 4);
    v[q * 4 + 0] = f.x; v[q * 4 + 1] = f.y; v[q * 4 + 2] = f.z; v[q * 4 + 3] = f.w;
  }
}
__device__ inline void st16(bf16* p, const float* v) {
  s8v o0, o1v; bf16* f0 = (bf16*)&o0; bf16* f1 = (bf16*)&o1v;
  #pragma unroll
  for (int j = 0; j < 8; ++j) { f0[j] = __float2bfloat16(v[j]); f1[j] = __float2bfloat16(v[8 + j]); }
  *(s8v*)p = o0; *(s8v*)(p + 8) = o1v;
}
__device__ inline void st16(float* p, const float* v) {
  #pragma unroll
  for (int q = 0; q < 4; ++q) {
    float4 f; f.x = v[q * 4 + 0]; f.y = v[q * 4 + 1]; f.z = v[q * 4 + 2]; f.w = v[q * 4 + 3];
    *(float4*)(p + q * 4) = f;
  }
}

// ---- fused InstanceNorm: out = inorm(g*a + b) per row of 4096 --------------
template<typename TAe, typename TBe, typename TOe, int G>
__global__ __launch_bounds__(256) void inorm_k(
    const TAe* __restrict__ a, const TBe* __restrict__ b,
    const float* __restrict__ g, TOe* __restrict__ out)
{
  __shared__ float red[8];
  const int tid = threadIdx.x;
  const long base = (long)blockIdx.x * NPIX + tid * 16;
  float gv = G ? *g : 1.f;
  float va[16], vbv[16], v[16];
  ld16(a + base, va);
  ld16(b + base, vbv);
  #pragma unroll
  for (int j = 0; j < 16; ++j) v[j] = gv * va[j] + vbv[j];
  float sum = 0.f, sq = 0.f;
  #pragma unroll
  for (int j = 0; j < 16; ++j) { sum += v[j]; sq += v[j] * v[j]; }
  #pragma unroll
  for (int s = 32; s; s >>= 1) { sum += __shfl_xor(sum, s); sq += __shfl_xor(sq, s); }
  if ((tid & 63) == 0) { red[tid >> 6] = sum; red[4 + (tid >> 6)] = sq; }
  __syncthreads();
  sum = red[0] + red[1] + red[2] + red[3];
  sq  = red[4] + red[5] + red[6] + red[7];
  float mean = sum * (1.f / NPIX);
  float var  = fmaxf(sq * (1.f / NPIX) - mean * mean, 0.f);
  float rstd = rsqrtf(var + 1e-5f);
  float o[16];
  #pragma unroll
  for (int j = 0; j < 16; ++j) o[j] = (v[j] - mean) * rstd;
  st16(out + base, o);
}

// ---- host-side helpers ------------------------------------------------------
static const long CN = (long)CDIM * NPIX;

// fused flash attention: CB picked so both launches are 512 blocks (2/CU).
static void attn_core(int nb, bf16* qkv, bf16* qkt, bf16* t0, hipStream_t stream)
{
  if (nb == 4)
    fattn_k<128><<<dim3(64, 2, 4), dim3(512), 0, stream>>>(qkt, qkv + 64 * NPIX, t0);
  else
    fattn_k<64><<<dim3(64, 4, 2), dim3(512), 0, stream>>>(qkt, qkv + 64 * NPIX, t0);
}

static void run_conv(const bf16* src, const bf16* wcvt, const float* cb,
                     bf16* dst, hipStream_t stream)
{
  conv_k<<<dim3(64, 2, 2), dim3(512), 0, stream>>>(src, wcvt, cb, dst);
}

// ---------------------------------------------------------------------------
extern "C" void kernel_launch(void* const* d_in, const int* in_sizes, int n_in,
                              void* d_out, int out_size, void* d_ws, size_t ws_size,
                              hipStream_t stream)
{
  (void)in_sizes; (void)n_in; (void)out_size; (void)ws_size;
  const float* x = (const float*)d_in[0];
  const float* y = (const float*)d_in[1];
  auto W = [&](int i) { return (const float*)d_in[i]; };

  char* wp = (char*)d_ws;
  auto take = [&](size_t nbytes) { char* p = wp; wp += (nbytes + 255) & ~(size_t)255; return p; };
  bf16*  qkv   = (bf16*)take((size_t)4 * QKVSTR * 2);
  bf16*  qkt   = (bf16*)take((size_t)4 * QKTSTR * 2);
  bf16*  t0    = (bf16*)take((size_t)4 * CN * 2);
  bf16*  u1    = (bf16*)take(2 * CN * 2);
  bf16*  u2    = (bf16*)take(2 * CN * 2);
  bf16*  u3    = (bf16*)take(2 * CN * 2);
  bf16*  u4    = (bf16*)take(2 * CN * 2);
  bf16*  wcvt1 = (bf16*)take((size_t)589824 * 2);
  bf16*  wcvt2 = (bf16*)take((size_t)589824 * 2);
  float* wcat1 = (float*)take((size_t)81920 * 4);
  float* bcat1 = (float*)take(320 * 4);
  float* wcat2 = (float*)take((size_t)81920 * 4);
  float* bcat2 = (float*)take(320 * 4);
  float* wqk   = (float*)take((size_t)16384 * 4);
  float* bqk   = (float*)take(64 * 4);
  bf16*  cvout = qkv;                                         // conv out (aliased)

  dim3 TB(256);

  // ---- prep: weight concat/convert ----
  cat_k<<<dim3(322), TB, 0, stream>>>(W(2), W(3), W(4), W(5), W(6), W(7), wcat1, bcat1, 320);
  cat_k<<<dim3(322), TB, 0, stream>>>(W(9), W(10), W(11), W(12), W(13), W(14), wcat2, bcat2, 320);
  cat_k<<<dim3(65),  TB, 0, stream>>>(W(16), W(17), W(18), W(19), nullptr, nullptr, wqk, bqk, 64);
  cvtw2_k<<<dim3(2304, 2), TB, 0, stream>>>(W(23), W(25), wcvt1, wcvt2);

  // ---- stages A+B attention together: z = stage*2 + batch ----
  proj_k<1,float><<<dim3(64,5,4), TB, 0, stream>>>(
      wcat1, wcat2, x, y, bcat1, bcat2, qkv, qkt, 320, NPIX, 256, CN, QKVSTR, 8);
  attn_core(4, qkv, qkt, t0, stream);

  // ---- out_1 / out_3 inorms ----
  inorm_k<bf16,float,bf16,1><<<dim3(512), TB, 0, stream>>>(t0, x, W(8), u1);
  inorm_k<bf16,float,bf16,1><<<dim3(512), TB, 0, stream>>>(t0 + 2 * CN, y, W(15), u3);

  // ---- conv1 -> out_2 ----
  run_conv(u1, wcvt1, W(24), cvout, stream);
  inorm_k<bf16,bf16,bf16,0><<<dim3(512), TB, 0, stream>>>(u1, cvout, nullptr, u2);

  // ---- stage C: q/k from out_2 (transposed), v from out_3 ----
  proj_k<1,bf16><<<dim3(64,1,2), TB, 0, stream>>>(
      wqk, wqk, u2, u2, bqk, bqk, qkv, qkt, 64, NPIX, 256, CN, QKVSTR, 8);
  proj_k<0,bf16><<<dim3(64,4,2), TB, 0, stream>>>(
      W(20), W(20), u3, u3, W(21), W(21), qkv + 64 * NPIX, qkt, 256, NPIX, 256, CN, QKVSTR, 8);
  attn_core(2, qkv, qkt, t0, stream);
  inorm_k<bf16,float,bf16,1><<<dim3(512), TB, 0, stream>>>(t0, y, W(22), u1);   // o1
  inorm_k<bf16,bf16,bf16,0><<<dim3(512), TB, 0, stream>>>(u1, u3, nullptr, u4); // o2
  run_conv(u4, wcvt2, W(26), cvout, stream);
  inorm_k<bf16,bf16,float,0><<<dim3(512), TB, 0, stream>>>(u4, cvout, nullptr, (float*)d_out);
}

// Round 10
// 352.815 us; speedup vs baseline: 1.1859x; 1.0087x over previous
//
#include <hip/hip_runtime.h>
#include <hip/hip_bf16.h>

typedef __hip_bfloat16 bf16;
typedef __attribute__((ext_vector_type(8))) short s8v;   // 8 bf16 = 4 VGPRs
typedef __attribute__((ext_vector_type(4))) short s4v;   // 4 bf16 = 8 bytes
typedef __attribute__((ext_vector_type(4))) float f4v;

#define NPIX 4096
#define CDIM 256
#define MN_ELEMS (1 << 20)        // CDIM * NPIX
#define QKVSTR (320L * NPIX)      // qkv per-slot stride (elems)
#define QKTSTR (64L * NPIX)       // qkt per-slot stride (elems)

#if __has_builtin(__builtin_amdgcn_exp2f)
#define EXP2F(x) __builtin_amdgcn_exp2f(x)
#else
#define EXP2F(x) exp2f(x)
#endif

// ---- async global->LDS, 16B per lane (dest = wave-uniform base + lane*16) ---
typedef __attribute__((address_space(1))) const unsigned int g_u32;
typedef __attribute__((address_space(3))) unsigned int l_u32;
__device__ __forceinline__ void glds16(const void* g, void* l) {
  __builtin_amdgcn_global_load_lds((g_u32*)g, (l_u32*)l, 16, 0, 0);
}

// ---- 8-element loaders -> bf16x8 (s8v) --------------------------------------
__device__ inline s8v ld8(const bf16* p) { return *(const s8v*)p; }
__device__ inline s8v ld8(const float* p) {
  float4 f0 = *(const float4*)p;
  float4 f1 = *(const float4*)(p + 4);
  s8v r; bf16* e = (bf16*)&r;
  e[0] = __float2bfloat16(f0.x); e[1] = __float2bfloat16(f0.y);
  e[2] = __float2bfloat16(f0.z); e[3] = __float2bfloat16(f0.w);
  e[4] = __float2bfloat16(f1.x); e[5] = __float2bfloat16(f1.y);
  e[6] = __float2bfloat16(f1.z); e[7] = __float2bfloat16(f1.w);
  return r;
}

// ---------------------------------------------------------------------------
// Fused flash-style attention — 8 thin waves (512 thr), all LDS streams
// XOR-swizzled, counted-vmcnt pipeline (2 raw barriers/iter, K dbuf).
// out[c][n] = sum_m V[c][m] exp(S[n][m]) / lsum[n]
// qkt: [slot][4096][64] bf16 (q*log2e at d0..31, k at d32..63).
// Vg:  rows [c][m] m-contig at slot stride QKVSTR.  out: [slot][256][4096].
// Swizzle (all [row][32-elem] tiles): byte-in-row ^= ((row>>1)&3)<<4; k/v/Q
// staged via glds16 with per-lane GLOBAL source column pre-permuted (m173).
// Pipeline per iter (m201 pattern: raw s_barrier = NO implicit vmcnt drain):
//   top: issue stageK(i+1 -> alt buffer)         [in flight all iter]
//   S-phase (k_s[cur] reads, MFMA, exp2, p_s writes)
//   W1: s_waitcnt vmcnt(1) lgkmcnt(0); sched_barrier; s_barrier
//       -> V(i) landed (cover = S phase), K(i+1) stays in flight, P visible
//   PV-phase (v_s, p_s reads)
//   W2: s_waitcnt vmcnt(0); sched_barrier; s_barrier
//       -> K(i+1) landed (cover = S+PV)
//   tail: issue stageV(i+1)                       [drains at next W1]
// Wave roles (w = tid>>6): S: (w>>2 n-half) x (w&3 m-quarter);
// PV: (w>>1 c-quarter of CB) x (w&1 n-half).
// grid (64, 256/CB, nslots), 512 threads.
// LDS: CB=128 -> 16+32+16+1 = 65K (2 blk/CU); CB=64 -> 16+16+16+1 = 49K.
// ---------------------------------------------------------------------------
template<int CB>
__global__ __launch_bounds__(512) void fattn_k(
    const bf16* __restrict__ qkt, const bf16* __restrict__ Vg,
    bf16* __restrict__ out)
{
  constexpr int SC = CB / 64;          // PV c-frags per wave
  __shared__ bf16 k_s[2][128 * 32];    // [buf][m 128][32] (swizzled rows)
  __shared__ bf16 v_s[4 * CB * 32];    // [kk][c CB][32] (swizzled rows)
  __shared__ bf16 p_s[4 * 64 * 32];    // [kk][n 64][32 m] (swizzled rows)
  __shared__ float sums[4 * 64];       // [m-quarter][n]

  const int tid = threadIdx.x;
  const int z = blockIdx.z;
  const int w = tid >> 6, lane = tid & 63;
  const int l15 = lane & 15, oct = lane >> 4;
  const int wr2 = w >> 2, wc2 = w & 3;     // S roles
  const int pc = w >> 1, pn = w & 1;       // PV roles
  const int n0 = blockIdx.x * 64, c0 = blockIdx.y * CB;
  const bf16* qk = qkt + (long)z * QKTSTR;
  const bf16* Vz = Vg + (long)z * QKVSTR;

  // staging source column pre-swizzle: row = tid>>2, quarter = tid&3
  const int t2 = tid >> 2;
  const int kq3 = ((tid & 3) ^ ((t2 >> 1) & 3)) * 8;      // for k_s / Q (row=t2)
  const int vrow = t2 & (CB - 1);                          // v_s row
  const int vq3 = ((tid & 3) ^ ((vrow >> 1) & 3)) * 8;     // for v_s

  auto stageK = [&](int m, int buf) {
    glds16(qk + (long)(m + t2) * 64 + 32 + kq3, &k_s[buf][tid * 8]);
  };
  auto stageV = [&](int m) {
    #pragma unroll
    for (int it = 0; it < CB / 32; ++it) {
      const int flat = it * 4096 + tid * 8;
      const int g = flat / (CB * 32);
      glds16(Vz + (long)(c0 + vrow) * 4096 + m + g * 32 + vq3, v_s + flat);
    }
  };

  // ---- prologue: stage Q (tid<256 -> p_s rows 0..63, swizzled), K(0), V(0) --
  if (tid < 256)
    glds16(qk + (long)(n0 + t2) * 64 + kq3, p_s + tid * 8);
  stageK(0, 0);
  stageV(0);
  __syncthreads();   // full drain once (prologue)

  s8v qf[2];
  #pragma unroll
  for (int st = 0; st < 2; ++st) {
    const int row = wr2 * 32 + st * 16 + l15;
    int byte = row * 64 + oct * 16;
    byte ^= ((row >> 1) & 3) << 4;
    qf[st] = *(const s8v*)((const char*)p_s + byte);
  }
  __syncthreads();   // all qf reads done before p_s is overwritten by P(0)

  f4v acc[SC][2];
  #pragma unroll
  for (int i = 0; i < SC; ++i)
    #pragma unroll
    for (int j = 0; j < 2; ++j) acc[i][j] = (f4v){0.f, 0.f, 0.f, 0.f};
  float rs[2] = {0.f, 0.f};

  for (int i = 0; i < 32; ++i) {
    const int cur = i & 1;
    if (i < 31) stageK((i + 1) * 128, cur ^ 1);   // in flight across this iter

    // ---- S^T phase: S[m][n] = k.q (q pre-scaled by log2e), exp2, pack -----
    s8v kf[2];
    #pragma unroll
    for (int nt = 0; nt < 2; ++nt) {
      const int row = wc2 * 32 + nt * 16 + l15;
      int byte = row * 64 + oct * 16;
      byte ^= ((row >> 1) & 3) << 4;
      kf[nt] = *(const s8v*)((const char*)&k_s[cur][0] + byte);
    }
    #pragma unroll
    for (int st = 0; st < 2; ++st) {
      const int n = wr2 * 32 + st * 16 + l15;          // P row (lane-fixed)
      const int sw = ((n >> 1) & 3) << 4;              // intra-row byte XOR
      f4v sa[2];
      __builtin_amdgcn_s_setprio(1);
      #pragma unroll
      for (int nt = 0; nt < 2; ++nt) {
        f4v zz = (f4v){0.f, 0.f, 0.f, 0.f};
        sa[nt] = __builtin_amdgcn_mfma_f32_16x16x32_bf16(kf[nt], qf[st], zz, 0, 0, 0);
      }
      __builtin_amdgcn_s_setprio(0);
      #pragma unroll
      for (int nt = 0; nt < 2; ++nt) {
        // m = wc2*32 + nt*16 + oct*4 + r  ->  kk = wc2
        int byte = wc2 * 4096 + n * 64 + nt * 32 + oct * 8;
        byte ^= sw;
        s4v pk; bf16* pe = (bf16*)&pk;
        float rsum = 0.f;
        #pragma unroll
        for (int r = 0; r < 4; ++r) {
          float e = EXP2F(sa[nt][r]);
          rsum += e;
          pe[r] = __float2bfloat16(e);
        }
        rs[st] += rsum;
        *(s4v*)((char*)p_s + byte) = pk;
      }
    }
    // ---- W1: V(i) landed + P visible; K(i+1) stays in flight --------------
    if (i < 31) asm volatile("s_waitcnt vmcnt(1) lgkmcnt(0)" ::: "memory");
    else        asm volatile("s_waitcnt vmcnt(0) lgkmcnt(0)" ::: "memory");
    __builtin_amdgcn_sched_barrier(0);
    __builtin_amdgcn_s_barrier();

    // ---- PV phase: acc[c][n] += V[c][m] * P[n][m], K=128 ------------------
    #pragma unroll
    for (int kk = 0; kk < 4; ++kk) {
      s8v vf[SC], pf[2];
      #pragma unroll
      for (int st = 0; st < SC; ++st) {
        const int row = pc * (CB / 4) + st * 16 + l15;
        int byte = kk * (CB * 64) + row * 64 + oct * 16;
        byte ^= ((row >> 1) & 3) << 4;
        vf[st] = *(const s8v*)((const char*)v_s + byte);
      }
      #pragma unroll
      for (int nt = 0; nt < 2; ++nt) {
        const int n = pn * 32 + nt * 16 + l15;
        int byte = kk * 4096 + n * 64 + oct * 16;
        byte ^= ((n >> 1) & 3) << 4;
        pf[nt] = *(const s8v*)((const char*)p_s + byte);
      }
      __builtin_amdgcn_s_setprio(1);
      #pragma unroll
      for (int st = 0; st < SC; ++st)
        #pragma unroll
        for (int nt = 0; nt < 2; ++nt)
          acc[st][nt] = __builtin_amdgcn_mfma_f32_16x16x32_bf16(vf[st], pf[nt], acc[st][nt], 0, 0, 0);
      __builtin_amdgcn_s_setprio(0);
    }
    // ---- W2: K(i+1) landed (cover = S+PV); then restage V -----------------
    asm volatile("s_waitcnt vmcnt(0)" ::: "memory");
    __builtin_amdgcn_sched_barrier(0);
    __builtin_amdgcn_s_barrier();

    if (i < 31) stageV((i + 1) * 128);   // drains at next iter's W1
  }

  // ---- row-sum: reduce over octs, combine 4 m-quarters via LDS ------------
  #pragma unroll
  for (int st = 0; st < 2; ++st) {
    rs[st] += __shfl_xor(rs[st], 16);
    rs[st] += __shfl_xor(rs[st], 32);
  }
  if (lane < 16) {
    #pragma unroll
    for (int st = 0; st < 2; ++st)
      sums[wc2 * 64 + wr2 * 32 + st * 16 + l15] = rs[st];
  }
  __syncthreads();

  float rinv[2];
  #pragma unroll
  for (int nt = 0; nt < 2; ++nt) {
    const int n = pn * 32 + nt * 16 + l15;
    rinv[nt] = 1.f / (sums[n] + sums[64 + n] + sums[128 + n] + sums[192 + n]);
  }
  bf16* op = out + (long)z * ((long)CDIM * NPIX);
  #pragma unroll
  for (int st = 0; st < SC; ++st) {
    const int gc = c0 + pc * (CB / 4) + st * 16 + oct * 4;
    #pragma unroll
    for (int nt = 0; nt < 2; ++nt) {
      const int gn = n0 + pn * 32 + nt * 16 + l15;
      #pragma unroll
      for (int r = 0; r < 4; ++r)
        op[(long)(gc + r) * NPIX + gn] = __float2bfloat16(acc[st][nt][r] * rinv[nt]);
    }
  }
}

// ---------------------------------------------------------------------------
// Fused direct 3x3 conv: out[o][h*64+w] = bias[o] +
//   sum_{j=(dy,dx)} sum_c W[o][j*256+c] * Xpad[c][h+dy-1][w+dx-1]
// B-fragments read straight from the padded LDS tile ([row 3][wpos 66][c 64],
// wpos stride 66 elems = 33 words -> bank-conflict-free b128 reads).
// W: wcvt [o][j*256+c] bf16 (k-contig, matches A-frag).  X: [c][4096] bf16.
// grid (64 h, 2 o-half, 2 batch), 512 threads = 8 waves; wave w owns o-rows
// o0+w*16..+16, all 64 pixels of row h.  4 c-chunk passes x (9 taps x 2 kc).
// LDS 26.1 KB.
// ---------------------------------------------------------------------------
__global__ __launch_bounds__(512) void conv_k(
    const bf16* __restrict__ x, const bf16* __restrict__ wcvt,
    const float* __restrict__ bias, bf16* __restrict__ out)
{
  __shared__ bf16 lds[3 * 66 * 66];   // [row][wpos][c(64, 2 pad)]
  const int tid = threadIdx.x;
  const int h = blockIdx.x;
  const int o0 = blockIdx.y * 128;
  x   += (long)blockIdx.z * CDIM * NPIX;
  out += (long)blockIdx.z * CDIM * NPIX;

  const int w = tid >> 6, lane = tid & 63;
  const int l15 = lane & 15, oct = lane >> 4;

  // zero the w-pad columns once (wpos 0 and 65; never overwritten by staging)
  if (tid < 192) {
    int row = tid >> 6, c = tid & 63;
    lds[(row * 66 + 0) * 66 + c] = __float2bfloat16(0.f);
    lds[(row * 66 + 65) * 66 + c] = __float2bfloat16(0.f);
  }

  f4v acc[4];
  #pragma unroll
  for (int nf = 0; nf < 4; ++nf) acc[nf] = (f4v){0.f, 0.f, 0.f, 0.f};

  const int w2 = tid & 31, chi = tid >> 5;   // staging: w2 pixel-pair, chi c-sub
  const long arow = (long)(o0 + w * 16 + l15) * 2304;

  for (int cg = 0; cg < 4; ++cg) {
    __syncthreads();   // pad/compute(cg-1) reads done before overwrite
    #pragma unroll
    for (int it = 0; it < 12; ++it) {
      int row = it >> 2, cgi = it & 3;
      int c = cgi * 16 + chi;
      int hh = h + row - 1;
      unsigned int pix = 0;
      if ((unsigned)hh < 64u)
        pix = *(const unsigned int*)(x + (long)(cg * 64 + c) * 4096 + hh * 64 + w2 * 2);
      const bf16* pp = (const bf16*)&pix;
      lds[(row * 66 + (w2 * 2 + 1)) * 66 + c] = pp[0];
      lds[(row * 66 + (w2 * 2 + 2)) * 66 + c] = pp[1];
    }
    __syncthreads();   // tile(cg) ready

    #pragma unroll
    for (int j = 0; j < 9; ++j) {
      const int dy = j / 3, dx = j % 3;
      #pragma unroll
      for (int kc = 0; kc < 2; ++kc) {
        s8v af = *(const s8v*)(wcvt + arow + j * 256 + cg * 64 + kc * 32 + oct * 8);
        s8v bfv[4];
        #pragma unroll
        for (int nf = 0; nf < 4; ++nf)
          bfv[nf] = *(const s8v*)&lds[(dy * 66 + (nf * 16 + l15 + dx)) * 66 + kc * 32 + oct * 8];
        #pragma unroll
        for (int nf = 0; nf < 4; ++nf)
          acc[nf] = __builtin_amdgcn_mfma_f32_16x16x32_bf16(af, bfv[nf], acc[nf], 0, 0, 0);
      }
    }
  }

  // ---- epilogue: + bias, store ----
  #pragma unroll
  for (int nf = 0; nf < 4; ++nf) {
    const int gn = h * 64 + nf * 16 + l15;
    const int go = o0 + w * 16 + oct * 4;
    #pragma unroll
    for (int r = 0; r < 4; ++r)
      out[(long)(go + r) * NPIX + gn] = __float2bfloat16(acc[nf][r] + bias[go + r]);
  }
}

// ---------------------------------------------------------------------------
// Projection GEMM. z = slot; stage = z>>1 selects (A,bias,B) vs (A2,bias2,B2);
// batch = z&1 offsets B by bbat. QKT=1: rows gm<64 -> qkt transposed, with the
// q rows (gm<32) pre-scaled by log2(e) so fattn can use raw v_exp_f32.
// ---------------------------------------------------------------------------
template<int QKT, typename TBe>
__global__ __launch_bounds__(256) void proj_k(
    const float* __restrict__ A, const float* __restrict__ A2,
    const TBe* __restrict__ B1, const TBe* __restrict__ B2,
    const float* __restrict__ bias, const float* __restrict__ bias2,
    bf16* __restrict__ Cm, bf16* __restrict__ qkt,
    int M, int N, int K, long bbat, long cbat, int nchunk)
{
  __shared__ bf16 a_s[64][40];
  __shared__ bf16 b_s[64][40];
  const int tid = threadIdx.x;
  const int z = blockIdx.z, stage = z >> 1, bat = z & 1;
  const float* Au = stage ? A2 : A;
  const float* biasu = stage ? bias2 : bias;
  const TBe* Bm = (stage ? B2 : B1) + bat * bbat;
  Cm += z * cbat;
  if (QKT) qkt += z * QKTSTR;
  const int m0 = blockIdx.y * 64, n0 = blockIdx.x * 64;
  const int w = tid >> 6, lane = tid & 63;
  const int l15 = lane & 15, oct = lane >> 4;

  f4v acc[4];
  #pragma unroll
  for (int i = 0; i < 4; ++i) acc[i] = (f4v){0.f, 0.f, 0.f, 0.f};

  const int a_i0 = tid >> 2, a_i1 = (tid & 3) * 8;
  const int b_i0 = tid >> 3, b_i1 = (tid & 7) * 8;

  s8v pa, pb;
  auto ldA = [&](int kc, s8v& d) {
    if (m0 + a_i0 < M) d = ld8(Au + (long)(m0 + a_i0) * K + kc * 32 + a_i1);
    else d = (s8v){0,0,0,0,0,0,0,0};
  };
  auto ldB = [&](int kc, s8v& d) {
    d = ld8(Bm + (long)(kc * 32 + b_i0) * N + n0 + b_i1);
  };

  ldA(0, pa); ldB(0, pb);
  for (int kc = 0; kc < nchunk; ++kc) {
    *(s8v*)&a_s[a_i0][a_i1] = pa;
    {
      const bf16* e = (const bf16*)&pb;
      #pragma unroll
      for (int j = 0; j < 8; ++j) b_s[b_i1 + j][b_i0] = e[j];
    }
    __syncthreads();
    if (kc + 1 < nchunk) { ldA(kc + 1, pa); ldB(kc + 1, pb); }
    s8v af = *(const s8v*)&a_s[w * 16 + l15][oct * 8];
    #pragma unroll
    for (int nt = 0; nt < 4; ++nt) {
      s8v bfr = *(const s8v*)&b_s[nt * 16 + l15][oct * 8];
      acc[nt] = __builtin_amdgcn_mfma_f32_16x16x32_bf16(af, bfr, acc[nt], 0, 0, 0);
    }
    __syncthreads();
  }
  const int gm_base = m0 + w * 16 + oct * 4;
  #pragma unroll
  for (int nt = 0; nt < 4; ++nt) {
    const int gn = n0 + nt * 16 + l15;
    #pragma unroll
    for (int r = 0; r < 4; ++r) {
      int gm = gm_base + r;
      if (gm < M) {
        float vv = acc[nt][r] + biasu[gm];
        if (QKT && gm < 64) {
          float vv2 = (gm < 32) ? vv * 1.44269504f : vv;   // q *= log2(e)
          qkt[(long)gn * 64 + gm] = __float2bfloat16(vv2);
        } else {
          Cm[(long)gm * N + gn] = __float2bfloat16(vv);
        }
      }
    }
  }
}

// ---- concat q/k(/v) weights+biases into fp32 [M][256] + [M] -----------------
__global__ __launch_bounds__(256) void cat_k(
    const float* __restrict__ wq, const float* __restrict__ bq,
    const float* __restrict__ wk, const float* __restrict__ bk,
    const float* __restrict__ wv, const float* __restrict__ bv,
    float* __restrict__ wcat, float* __restrict__ bcat, int M)
{
  int idx = blockIdx.x * 256 + threadIdx.x;
  int total = M << 8;
  if (idx < total) {
    int r = idx >> 8, c = idx & 255;
    float v;
    if (r < 32) v = wq[r * 256 + c];
    else if (r < 64) v = wk[(r - 32) * 256 + c];
    else v = wv[(r - 64) * 256 + c];
    wcat[idx] = v;
  } else if (idx < total + M) {
    int r = idx - total;
    bcat[r] = (r < 32) ? bq[r] : (r < 64) ? bk[r - 32] : bv[r - 64];
  }
}

// ---- both convs' weights: fp32 [O][C][9] -> bf16 [O][j*256+c] ---------------
__global__ __launch_bounds__(256) void cvtw2_k(
    const float* __restrict__ w1, const float* __restrict__ w2,
    bf16* __restrict__ o1, bf16* __restrict__ o2)
{
  const float* in = blockIdx.y ? w2 : w1;
  bf16* out = blockIdx.y ? o2 : o1;
  int idx = blockIdx.x * 256 + threadIdx.x;
  int o = idx / 2304, r = idx % 2304;
  int j = r >> 8, c = r & 255;
  out[idx] = __float2bfloat16(in[(o * 256 + c) * 9 + j]);
}

// ---- 16-elem row load/store helpers ----------------------------------------
__device__ inline void ld16(const bf16* p, float* v) {
  s8v r0 = *(const s8v*)p, r1 = *(const s8v*)(p + 8);
  const bf16* e0 = (const bf16*)&r0; const bf16* e1 = (const bf16*)&r1;
  #pragma unroll
  for (int j = 0; j < 8; ++j) { v[j] = __bfloat162float(e0[j]); v[8 + j] = __bfloat162float(e1[j]); }
}
__device__ inline void ld16(const float* p, float* v) {
  #pragma unroll
  for (int q = 0; q < 4; ++q) {
    float4 f = *(const float4*)(p + q * 4);
    v[q * 4 + 0] = f.x; v[q * 4 + 1] = f.y; v[q * 4 + 2] = f.z; v[q * 4 + 3] = f.w;
  }
}
__device__ inline void st16(bf16* p, const float* v) {
  s8v o0, o1v; bf16* f0 = (bf16*)&o0; bf16* f1 = (bf16*)&o1v;
  #pragma unroll
  for (int j = 0; j < 8; ++j) { f0[j] = __float2bfloat16(v[j]); f1[j] = __float2bfloat16(v[8 + j]); }
  *(s8v*)p = o0; *(s8v*)(p + 8) = o1v;
}
__device__ inline void st16(float* p, const float* v) {
  #pragma unroll
  for (int q = 0; q < 4; ++q) {
    float4 f; f.x = v[q * 4 + 0]; f.y = v[q * 4 + 1]; f.z = v[q * 4 + 2]; f.w = v[q * 4 + 3];
    *(float4*)(p + q * 4) = f;
  }
}

// ---- fused InstanceNorm: out = inorm(g*a + b) per row of 4096 --------------
template<typename TAe, typename TBe, typename TOe, int G>
__global__ __launch_bounds__(256) void inorm_k(
    const TAe* __restrict__ a, const TBe* __restrict__ b,
    const float* __restrict__ g, TOe* __restrict__ out)
{
  __shared__ float red[8];
  const int tid = threadIdx.x;
  const long base = (long)blockIdx.x * NPIX + tid * 16;
  float gv = G ? *g : 1.f;
  float va[16], vbv[16], v[16];
  ld16(a + base, va);
  ld16(b + base, vbv);
  #pragma unroll
  for (int j = 0; j < 16; ++j) v[j] = gv * va[j] + vbv[j];
  float sum = 0.f, sq = 0.f;
  #pragma unroll
  for (int j = 0; j < 16; ++j) { sum += v[j]; sq += v[j] * v[j]; }
  #pragma unroll
  for (int s = 32; s; s >>= 1) { sum += __shfl_xor(sum, s); sq += __shfl_xor(sq, s); }
  if ((tid & 63) == 0) { red[tid >> 6] = sum; red[4 + (tid >> 6)] = sq; }
  __syncthreads();
  sum = red[0] + red[1] + red[2] + red[3];
  sq  = red[4] + red[5] + red[6] + red[7];
  float mean = sum * (1.f / NPIX);
  float var  = fmaxf(sq * (1.f / NPIX) - mean * mean, 0.f);
  float rstd = rsqrtf(var + 1e-5f);
  float o[16];
  #pragma unroll
  for (int j = 0; j < 16; ++j) o[j] = (v[j] - mean) * rstd;
  st16(out + base, o);
}

// ---- host-side helpers ------------------------------------------------------
static const long CN = (long)CDIM * NPIX;

// fused flash attention: CB picked so both launches are 512 blocks (2/CU).
static void attn_core(int nb, bf16* qkv, bf16* qkt, bf16* t0, hipStream_t stream)
{
  if (nb == 4)
    fattn_k<128><<<dim3(64, 2, 4), dim3(512), 0, stream>>>(qkt, qkv + 64 * NPIX, t0);
  else
    fattn_k<64><<<dim3(64, 4, 2), dim3(512), 0, stream>>>(qkt, qkv + 64 * NPIX, t0);
}

static void run_conv(const bf16* src, const bf16* wcvt, const float* cb,
                     bf16* dst, hipStream_t stream)
{
  conv_k<<<dim3(64, 2, 2), dim3(512), 0, stream>>>(src, wcvt, cb, dst);
}

// ---------------------------------------------------------------------------
extern "C" void kernel_launch(void* const* d_in, const int* in_sizes, int n_in,
                              void* d_out, int out_size, void* d_ws, size_t ws_size,
                              hipStream_t stream)
{
  (void)in_sizes; (void)n_in; (void)out_size; (void)ws_size;
  const float* x = (const float*)d_in[0];
  const float* y = (const float*)d_in[1];
  auto W = [&](int i) { return (const float*)d_in[i]; };

  char* wp = (char*)d_ws;
  auto take = [&](size_t nbytes) { char* p = wp; wp += (nbytes + 255) & ~(size_t)255; return p; };
  bf16*  qkv   = (bf16*)take((size_t)4 * QKVSTR * 2);
  bf16*  qkt   = (bf16*)take((size_t)4 * QKTSTR * 2);
  bf16*  t0    = (bf16*)take((size_t)4 * CN * 2);
  bf16*  u1    = (bf16*)take(2 * CN * 2);
  bf16*  u2    = (bf16*)take(2 * CN * 2);
  bf16*  u3    = (bf16*)take(2 * CN * 2);
  bf16*  u4    = (bf16*)take(2 * CN * 2);
  bf16*  wcvt1 = (bf16*)take((size_t)589824 * 2);
  bf16*  wcvt2 = (bf16*)take((size_t)589824 * 2);
  float* wcat1 = (float*)take((size_t)81920 * 4);
  float* bcat1 = (float*)take(320 * 4);
  float* wcat2 = (float*)take((size_t)81920 * 4);
  float* bcat2 = (float*)take(320 * 4);
  float* wqk   = (float*)take((size_t)16384 * 4);
  float* bqk   = (float*)take(64 * 4);
  bf16*  cvout = qkv;                                         // conv out (aliased)

  dim3 TB(256);

  // ---- prep: weight concat/convert ----
  cat_k<<<dim3(322), TB, 0, stream>>>(W(2), W(3), W(4), W(5), W(6), W(7), wcat1, bcat1, 320);
  cat_k<<<dim3(322), TB, 0, stream>>>(W(9), W(10), W(11), W(12), W(13), W(14), wcat2, bcat2, 320);
  cat_k<<<dim3(65),  TB, 0, stream>>>(W(16), W(17), W(18), W(19), nullptr, nullptr, wqk, bqk, 64);
  cvtw2_k<<<dim3(2304, 2), TB, 0, stream>>>(W(23), W(25), wcvt1, wcvt2);

  // ---- stages A+B attention together: z = stage*2 + batch ----
  proj_k<1,float><<<dim3(64,5,4), TB, 0, stream>>>(
      wcat1, wcat2, x, y, bcat1, bcat2, qkv, qkt, 320, NPIX, 256, CN, QKVSTR, 8);
  attn_core(4, qkv, qkt, t0, stream);

  // ---- out_1 / out_3 inorms ----
  inorm_k<bf16,float,bf16,1><<<dim3(512), TB, 0, stream>>>(t0, x, W(8), u1);
  inorm_k<bf16,float,bf16,1><<<dim3(512), TB, 0, stream>>>(t0 + 2 * CN, y, W(15), u3);

  // ---- conv1 -> out_2 ----
  run_conv(u1, wcvt1, W(24), cvout, stream);
  inorm_k<bf16,bf16,bf16,0><<<dim3(512), TB, 0, stream>>>(u1, cvout, nullptr, u2);

  // ---- stage C: q/k from out_2 (transposed), v from out_3 ----
  proj_k<1,bf16><<<dim3(64,1,2), TB, 0, stream>>>(
      wqk, wqk, u2, u2, bqk, bqk, qkv, qkt, 64, NPIX, 256, CN, QKVSTR, 8);
  proj_k<0,bf16><<<dim3(64,4,2), TB, 0, stream>>>(
      W(20), W(20), u3, u3, W(21), W(21), qkv + 64 * NPIX, qkt, 256, NPIX, 256, CN, QKVSTR, 8);
  attn_core(2, qkv, qkt, t0, stream);
  inorm_k<bf16,float,bf16,1><<<dim3(512), TB, 0, stream>>>(t0, y, W(22), u1);   // o1
  inorm_k<bf16,bf16,bf16,0><<<dim3(512), TB, 0, stream>>>(u1, u3, nullptr, u4); // o2
  run_conv(u4, wcvt2, W(26), cvout, stream);
  inorm_k<bf16,bf16,float,0><<<dim3(512), TB, 0, stream>>>(u4, cvout, nullptr, (float*)d_out);
}

// Round 11
// 337.656 us; speedup vs baseline: 1.2391x; 1.0449x over previous
//
#include <hip/hip_runtime.h>
#include <hip/hip_bf16.h>

typedef __hip_bfloat16 bf16;
typedef __attribute__((ext_vector_type(8))) short s8v;   // 8 bf16 = 4 VGPRs
typedef __attribute__((ext_vector_type(4))) short s4v;   // 4 bf16 = 8 bytes
typedef __attribute__((ext_vector_type(4))) float f4v;

#define NPIX 4096
#define CDIM 256
#define MN_ELEMS (1 << 20)        // CDIM * NPIX
#define QKVSTR (320L * NPIX)      // qkv per-slot stride (elems)
#define QKTSTR (64L * NPIX)       // qkt per-slot stride (elems)
#define CNL ((long)CDIM * NPIX)

#if __has_builtin(__builtin_amdgcn_exp2f)
#define EXP2F(x) __builtin_amdgcn_exp2f(x)
#else
#define EXP2F(x) exp2f(x)
#endif

// ---- async global->LDS, 16B per lane (dest = wave-uniform base + lane*16) ---
typedef __attribute__((address_space(1))) const unsigned int g_u32;
typedef __attribute__((address_space(3))) unsigned int l_u32;
__device__ __forceinline__ void glds16(const void* g, void* l) {
  __builtin_amdgcn_global_load_lds((g_u32*)g, (l_u32*)l, 16, 0, 0);
}

// ---- 8-element loaders -> bf16x8 (s8v) --------------------------------------
__device__ inline s8v ld8(const bf16* p) { return *(const s8v*)p; }
__device__ inline s8v ld8(const float* p) {
  float4 f0 = *(const float4*)p;
  float4 f1 = *(const float4*)(p + 4);
  s8v r; bf16* e = (bf16*)&r;
  e[0] = __float2bfloat16(f0.x); e[1] = __float2bfloat16(f0.y);
  e[2] = __float2bfloat16(f0.z); e[3] = __float2bfloat16(f0.w);
  e[4] = __float2bfloat16(f1.x); e[5] = __float2bfloat16(f1.y);
  e[6] = __float2bfloat16(f1.z); e[7] = __float2bfloat16(f1.w);
  return r;
}

// ---------------------------------------------------------------------------
// Fused flash-style attention — 8 thin waves (512 thr), all LDS streams
// XOR-swizzled, counted-vmcnt pipeline (2 raw barriers/iter, K dbuf).
// (R10 kernel, verified: 66.5 us merged, 2.1M bank conflicts.)
// ---------------------------------------------------------------------------
template<int CB>
__global__ __launch_bounds__(512) void fattn_k(
    const bf16* __restrict__ qkt, const bf16* __restrict__ Vg,
    bf16* __restrict__ out)
{
  constexpr int SC = CB / 64;          // PV c-frags per wave
  __shared__ bf16 k_s[2][128 * 32];    // [buf][m 128][32] (swizzled rows)
  __shared__ bf16 v_s[4 * CB * 32];    // [kk][c CB][32] (swizzled rows)
  __shared__ bf16 p_s[4 * 64 * 32];    // [kk][n 64][32 m] (swizzled rows)
  __shared__ float sums[4 * 64];       // [m-quarter][n]

  const int tid = threadIdx.x;
  const int z = blockIdx.z;
  const int w = tid >> 6, lane = tid & 63;
  const int l15 = lane & 15, oct = lane >> 4;
  const int wr2 = w >> 2, wc2 = w & 3;     // S roles
  const int pc = w >> 1, pn = w & 1;       // PV roles
  const int n0 = blockIdx.x * 64, c0 = blockIdx.y * CB;
  const bf16* qk = qkt + (long)z * QKTSTR;
  const bf16* Vz = Vg + (long)z * QKVSTR;

  // staging source column pre-swizzle: row = tid>>2, quarter = tid&3
  const int t2 = tid >> 2;
  const int kq3 = ((tid & 3) ^ ((t2 >> 1) & 3)) * 8;      // for k_s / Q (row=t2)
  const int vrow = t2 & (CB - 1);                          // v_s row
  const int vq3 = ((tid & 3) ^ ((vrow >> 1) & 3)) * 8;     // for v_s

  auto stageK = [&](int m, int buf) {
    glds16(qk + (long)(m + t2) * 64 + 32 + kq3, &k_s[buf][tid * 8]);
  };
  auto stageV = [&](int m) {
    #pragma unroll
    for (int it = 0; it < CB / 32; ++it) {
      const int flat = it * 4096 + tid * 8;
      const int g = flat / (CB * 32);
      glds16(Vz + (long)(c0 + vrow) * 4096 + m + g * 32 + vq3, v_s + flat);
    }
  };

  // ---- prologue: stage Q (tid<256 -> p_s rows 0..63, swizzled), K(0), V(0) --
  if (tid < 256)
    glds16(qk + (long)(n0 + t2) * 64 + kq3, p_s + tid * 8);
  stageK(0, 0);
  stageV(0);
  __syncthreads();   // full drain once (prologue)

  s8v qf[2];
  #pragma unroll
  for (int st = 0; st < 2; ++st) {
    const int row = wr2 * 32 + st * 16 + l15;
    int byte = row * 64 + oct * 16;
    byte ^= ((row >> 1) & 3) << 4;
    qf[st] = *(const s8v*)((const char*)p_s + byte);
  }
  __syncthreads();   // all qf reads done before p_s is overwritten by P(0)

  f4v acc[SC][2];
  #pragma unroll
  for (int i = 0; i < SC; ++i)
    #pragma unroll
    for (int j = 0; j < 2; ++j) acc[i][j] = (f4v){0.f, 0.f, 0.f, 0.f};
  float rs[2] = {0.f, 0.f};

  for (int i = 0; i < 32; ++i) {
    const int cur = i & 1;
    if (i < 31) stageK((i + 1) * 128, cur ^ 1);   // in flight across this iter

    // ---- S^T phase: S[m][n] = k.q (q pre-scaled by log2e), exp2, pack -----
    s8v kf[2];
    #pragma unroll
    for (int nt = 0; nt < 2; ++nt) {
      const int row = wc2 * 32 + nt * 16 + l15;
      int byte = row * 64 + oct * 16;
      byte ^= ((row >> 1) & 3) << 4;
      kf[nt] = *(const s8v*)((const char*)&k_s[cur][0] + byte);
    }
    #pragma unroll
    for (int st = 0; st < 2; ++st) {
      const int n = wr2 * 32 + st * 16 + l15;          // P row (lane-fixed)
      const int sw = ((n >> 1) & 3) << 4;              // intra-row byte XOR
      f4v sa[2];
      __builtin_amdgcn_s_setprio(1);
      #pragma unroll
      for (int nt = 0; nt < 2; ++nt) {
        f4v zz = (f4v){0.f, 0.f, 0.f, 0.f};
        sa[nt] = __builtin_amdgcn_mfma_f32_16x16x32_bf16(kf[nt], qf[st], zz, 0, 0, 0);
      }
      __builtin_amdgcn_s_setprio(0);
      #pragma unroll
      for (int nt = 0; nt < 2; ++nt) {
        // m = wc2*32 + nt*16 + oct*4 + r  ->  kk = wc2
        int byte = wc2 * 4096 + n * 64 + nt * 32 + oct * 8;
        byte ^= sw;
        s4v pk; bf16* pe = (bf16*)&pk;
        float rsum = 0.f;
        #pragma unroll
        for (int r = 0; r < 4; ++r) {
          float e = EXP2F(sa[nt][r]);
          rsum += e;
          pe[r] = __float2bfloat16(e);
        }
        rs[st] += rsum;
        *(s4v*)((char*)p_s + byte) = pk;
      }
    }
    // ---- W1: V(i) landed + P visible; K(i+1) stays in flight --------------
    if (i < 31) asm volatile("s_waitcnt vmcnt(1) lgkmcnt(0)" ::: "memory");
    else        asm volatile("s_waitcnt vmcnt(0) lgkmcnt(0)" ::: "memory");
    __builtin_amdgcn_sched_barrier(0);
    __builtin_amdgcn_s_barrier();

    // ---- PV phase: acc[c][n] += V[c][m] * P[n][m], K=128 ------------------
    #pragma unroll
    for (int kk = 0; kk < 4; ++kk) {
      s8v vf[SC], pf[2];
      #pragma unroll
      for (int st = 0; st < SC; ++st) {
        const int row = pc * (CB / 4) + st * 16 + l15;
        int byte = kk * (CB * 64) + row * 64 + oct * 16;
        byte ^= ((row >> 1) & 3) << 4;
        vf[st] = *(const s8v*)((const char*)v_s + byte);
      }
      #pragma unroll
      for (int nt = 0; nt < 2; ++nt) {
        const int n = pn * 32 + nt * 16 + l15;
        int byte = kk * 4096 + n * 64 + oct * 16;
        byte ^= ((n >> 1) & 3) << 4;
        pf[nt] = *(const s8v*)((const char*)p_s + byte);
      }
      __builtin_amdgcn_s_setprio(1);
      #pragma unroll
      for (int st = 0; st < SC; ++st)
        #pragma unroll
        for (int nt = 0; nt < 2; ++nt)
          acc[st][nt] = __builtin_amdgcn_mfma_f32_16x16x32_bf16(vf[st], pf[nt], acc[st][nt], 0, 0, 0);
      __builtin_amdgcn_s_setprio(0);
    }
    // ---- W2: K(i+1) landed (cover = S+PV); then restage V -----------------
    asm volatile("s_waitcnt vmcnt(0)" ::: "memory");
    __builtin_amdgcn_sched_barrier(0);
    __builtin_amdgcn_s_barrier();

    if (i < 31) stageV((i + 1) * 128);   // drains at next iter's W1
  }

  // ---- row-sum: reduce over octs, combine 4 m-quarters via LDS ------------
  #pragma unroll
  for (int st = 0; st < 2; ++st) {
    rs[st] += __shfl_xor(rs[st], 16);
    rs[st] += __shfl_xor(rs[st], 32);
  }
  if (lane < 16) {
    #pragma unroll
    for (int st = 0; st < 2; ++st)
      sums[wc2 * 64 + wr2 * 32 + st * 16 + l15] = rs[st];
  }
  __syncthreads();

  float rinv[2];
  #pragma unroll
  for (int nt = 0; nt < 2; ++nt) {
    const int n = pn * 32 + nt * 16 + l15;
    rinv[nt] = 1.f / (sums[n] + sums[64 + n] + sums[128 + n] + sums[192 + n]);
  }
  bf16* op = out + (long)z * CNL;
  #pragma unroll
  for (int st = 0; st < SC; ++st) {
    const int gc = c0 + pc * (CB / 4) + st * 16 + oct * 4;
    #pragma unroll
    for (int nt = 0; nt < 2; ++nt) {
      const int gn = n0 + pn * 32 + nt * 16 + l15;
      #pragma unroll
      for (int r = 0; r < 4; ++r)
        op[(long)(gc + r) * NPIX + gn] = __float2bfloat16(acc[st][nt][r] * rinv[nt]);
    }
  }
}

// ---------------------------------------------------------------------------
// Fused direct 3x3 conv (R7 kernel, verified).
// ---------------------------------------------------------------------------
__global__ __launch_bounds__(512) void conv_k(
    const bf16* __restrict__ x, const bf16* __restrict__ wcvt,
    const float* __restrict__ bias, bf16* __restrict__ out)
{
  __shared__ bf16 lds[3 * 66 * 66];   // [row][wpos][c(64, 2 pad)]
  const int tid = threadIdx.x;
  const int h = blockIdx.x;
  const int o0 = blockIdx.y * 128;
  x   += (long)blockIdx.z * CDIM * NPIX;
  out += (long)blockIdx.z * CDIM * NPIX;

  const int w = tid >> 6, lane = tid & 63;
  const int l15 = lane & 15, oct = lane >> 4;

  // zero the w-pad columns once (wpos 0 and 65; never overwritten by staging)
  if (tid < 192) {
    int row = tid >> 6, c = tid & 63;
    lds[(row * 66 + 0) * 66 + c] = __float2bfloat16(0.f);
    lds[(row * 66 + 65) * 66 + c] = __float2bfloat16(0.f);
  }

  f4v acc[4];
  #pragma unroll
  for (int nf = 0; nf < 4; ++nf) acc[nf] = (f4v){0.f, 0.f, 0.f, 0.f};

  const int w2 = tid & 31, chi = tid >> 5;   // staging: w2 pixel-pair, chi c-sub
  const long arow = (long)(o0 + w * 16 + l15) * 2304;

  for (int cg = 0; cg < 4; ++cg) {
    __syncthreads();   // pad/compute(cg-1) reads done before overwrite
    #pragma unroll
    for (int it = 0; it < 12; ++it) {
      int row = it >> 2, cgi = it & 3;
      int c = cgi * 16 + chi;
      int hh = h + row - 1;
      unsigned int pix = 0;
      if ((unsigned)hh < 64u)
        pix = *(const unsigned int*)(x + (long)(cg * 64 + c) * 4096 + hh * 64 + w2 * 2);
      const bf16* pp = (const bf16*)&pix;
      lds[(row * 66 + (w2 * 2 + 1)) * 66 + c] = pp[0];
      lds[(row * 66 + (w2 * 2 + 2)) * 66 + c] = pp[1];
    }
    __syncthreads();   // tile(cg) ready

    #pragma unroll
    for (int j = 0; j < 9; ++j) {
      const int dy = j / 3, dx = j % 3;
      #pragma unroll
      for (int kc = 0; kc < 2; ++kc) {
        s8v af = *(const s8v*)(wcvt + arow + j * 256 + cg * 64 + kc * 32 + oct * 8);
        s8v bfv[4];
        #pragma unroll
        for (int nf = 0; nf < 4; ++nf)
          bfv[nf] = *(const s8v*)&lds[(dy * 66 + (nf * 16 + l15 + dx)) * 66 + kc * 32 + oct * 8];
        #pragma unroll
        for (int nf = 0; nf < 4; ++nf)
          acc[nf] = __builtin_amdgcn_mfma_f32_16x16x32_bf16(af, bfv[nf], acc[nf], 0, 0, 0);
      }
    }
  }

  // ---- epilogue: + bias, store ----
  #pragma unroll
  for (int nf = 0; nf < 4; ++nf) {
    const int gn = h * 64 + nf * 16 + l15;
    const int go = o0 + w * 16 + oct * 4;
    #pragma unroll
    for (int r = 0; r < 4; ++r)
      out[(long)(go + r) * NPIX + gn] = __float2bfloat16(acc[nf][r] + bias[go + r]);
  }
}

// ---------------------------------------------------------------------------
// Projection GEMM (A+B stages). z = slot; stage = z>>1 selects param set;
// batch = z&1 offsets B. QKT=1: rows gm<64 -> qkt transposed, q rows scaled
// by log2(e).
// ---------------------------------------------------------------------------
template<int QKT, typename TBe>
__global__ __launch_bounds__(256) void proj_k(
    const float* __restrict__ A, const float* __restrict__ A2,
    const TBe* __restrict__ B1, const TBe* __restrict__ B2,
    const float* __restrict__ bias, const float* __restrict__ bias2,
    bf16* __restrict__ Cm, bf16* __restrict__ qkt,
    int M, int N, int K, long bbat, long cbat, int nchunk)
{
  __shared__ bf16 a_s[64][40];
  __shared__ bf16 b_s[64][40];
  const int tid = threadIdx.x;
  const int z = blockIdx.z, stage = z >> 1, bat = z & 1;
  const float* Au = stage ? A2 : A;
  const float* biasu = stage ? bias2 : bias;
  const TBe* Bm = (stage ? B2 : B1) + bat * bbat;
  Cm += z * cbat;
  if (QKT) qkt += z * QKTSTR;
  const int m0 = blockIdx.y * 64, n0 = blockIdx.x * 64;
  const int w = tid >> 6, lane = tid & 63;
  const int l15 = lane & 15, oct = lane >> 4;

  f4v acc[4];
  #pragma unroll
  for (int i = 0; i < 4; ++i) acc[i] = (f4v){0.f, 0.f, 0.f, 0.f};

  const int a_i0 = tid >> 2, a_i1 = (tid & 3) * 8;
  const int b_i0 = tid >> 3, b_i1 = (tid & 7) * 8;

  s8v pa, pb;
  auto ldA = [&](int kc, s8v& d) {
    if (m0 + a_i0 < M) d = ld8(Au + (long)(m0 + a_i0) * K + kc * 32 + a_i1);
    else d = (s8v){0,0,0,0,0,0,0,0};
  };
  auto ldB = [&](int kc, s8v& d) {
    d = ld8(Bm + (long)(kc * 32 + b_i0) * N + n0 + b_i1);
  };

  ldA(0, pa); ldB(0, pb);
  for (int kc = 0; kc < nchunk; ++kc) {
    *(s8v*)&a_s[a_i0][a_i1] = pa;
    {
      const bf16* e = (const bf16*)&pb;
      #pragma unroll
      for (int j = 0; j < 8; ++j) b_s[b_i1 + j][b_i0] = e[j];
    }
    __syncthreads();
    if (kc + 1 < nchunk) { ldA(kc + 1, pa); ldB(kc + 1, pb); }
    s8v af = *(const s8v*)&a_s[w * 16 + l15][oct * 8];
    #pragma unroll
    for (int nt = 0; nt < 4; ++nt) {
      s8v bfr = *(const s8v*)&b_s[nt * 16 + l15][oct * 8];
      acc[nt] = __builtin_amdgcn_mfma_f32_16x16x32_bf16(af, bfr, acc[nt], 0, 0, 0);
    }
    __syncthreads();
  }
  const int gm_base = m0 + w * 16 + oct * 4;
  #pragma unroll
  for (int nt = 0; nt < 4; ++nt) {
    const int gn = n0 + nt * 16 + l15;
    #pragma unroll
    for (int r = 0; r < 4; ++r) {
      int gm = gm_base + r;
      if (gm < M) {
        float vv = acc[nt][r] + biasu[gm];
        if (QKT && gm < 64) {
          float vv2 = (gm < 32) ? vv * 1.44269504f : vv;   // q *= log2(e)
          qkt[(long)gn * 64 + gm] = __float2bfloat16(vv2);
        } else {
          Cm[(long)gm * N + gn] = __float2bfloat16(vv);
        }
      }
    }
  }
}

// ---------------------------------------------------------------------------
// Stage-C projection, merged: grid (64 n, 5, 2 batch).
// y==0: qk-proj  (A=wqk fp32 [64][256], B=u2 bf16) -> qkt (transposed, q
//        rows scaled by log2e).
// y>=1: v-proj   (A=wv fp32 [256][256], B=u3 bf16, m0=(y-1)*64) -> qkv V rows.
// Same body/layout as proj_k (K=256, 8 chunks).
// ---------------------------------------------------------------------------
__global__ __launch_bounds__(256) void projc_k(
    const float* __restrict__ wqk, const float* __restrict__ bqk,
    const bf16* __restrict__ u2,
    const float* __restrict__ wv, const float* __restrict__ bvv,
    const bf16* __restrict__ u3,
    bf16* __restrict__ qkv, bf16* __restrict__ qkt)
{
  __shared__ bf16 a_s[64][40];
  __shared__ bf16 b_s[64][40];
  const int tid = threadIdx.x;
  const int bat = blockIdx.z;
  const int qkmode = (blockIdx.y == 0);
  const float* Au    = qkmode ? wqk : wv;
  const float* biasu = qkmode ? bqk : bvv;
  const bf16* Bm     = (qkmode ? u2 : u3) + (long)bat * CNL;
  const int M  = qkmode ? 64 : 256;
  const int m0 = qkmode ? 0 : (blockIdx.y - 1) * 64;
  const int n0 = blockIdx.x * 64;
  const int w = tid >> 6, lane = tid & 63;
  const int l15 = lane & 15, oct = lane >> 4;

  f4v acc[4];
  #pragma unroll
  for (int i = 0; i < 4; ++i) acc[i] = (f4v){0.f, 0.f, 0.f, 0.f};

  const int a_i0 = tid >> 2, a_i1 = (tid & 3) * 8;
  const int b_i0 = tid >> 3, b_i1 = (tid & 7) * 8;

  s8v pa, pb;
  auto ldA = [&](int kc, s8v& d) {
    if (m0 + a_i0 < M) d = ld8(Au + (long)(m0 + a_i0) * 256 + kc * 32 + a_i1);
    else d = (s8v){0,0,0,0,0,0,0,0};
  };
  auto ldB = [&](int kc, s8v& d) {
    d = ld8(Bm + (long)(kc * 32 + b_i0) * NPIX + n0 + b_i1);
  };

  ldA(0, pa); ldB(0, pb);
  for (int kc = 0; kc < 8; ++kc) {
    *(s8v*)&a_s[a_i0][a_i1] = pa;
    {
      const bf16* e = (const bf16*)&pb;
      #pragma unroll
      for (int j = 0; j < 8; ++j) b_s[b_i1 + j][b_i0] = e[j];
    }
    __syncthreads();
    if (kc + 1 < 8) { ldA(kc + 1, pa); ldB(kc + 1, pb); }
    s8v af = *(const s8v*)&a_s[w * 16 + l15][oct * 8];
    #pragma unroll
    for (int nt = 0; nt < 4; ++nt) {
      s8v bfr = *(const s8v*)&b_s[nt * 16 + l15][oct * 8];
      acc[nt] = __builtin_amdgcn_mfma_f32_16x16x32_bf16(af, bfr, acc[nt], 0, 0, 0);
    }
    __syncthreads();
  }
  const int gm_base = m0 + w * 16 + oct * 4;
  #pragma unroll
  for (int nt = 0; nt < 4; ++nt) {
    const int gn = n0 + nt * 16 + l15;
    #pragma unroll
    for (int r = 0; r < 4; ++r) {
      int gm = gm_base + r;
      if (gm < M) {
        float vv = acc[nt][r] + biasu[gm];
        if (qkmode) {
          float vv2 = (gm < 32) ? vv * 1.44269504f : vv;   // q *= log2(e)
          qkt[(long)bat * QKTSTR + (long)gn * 64 + gm] = __float2bfloat16(vv2);
        } else {
          qkv[64 * NPIX + (long)bat * QKVSTR + (long)gm * NPIX + gn] = __float2bfloat16(vv);
        }
      }
    }
  }
}

// ---------------------------------------------------------------------------
// Merged prep: cvtw2 (both convs) + cat x2 (320-row) + cat qk (64-row).
// Flat index regions: [0,589824) wcvt1; [589824,1179648) wcvt2;
// then 82240 cat1, 82240 cat2, 16448 catqk.  Grid 5315 x 256.
// ---------------------------------------------------------------------------
__global__ __launch_bounds__(256) void prep_k(
    const float* __restrict__ cw1, const float* __restrict__ cw2,
    bf16* __restrict__ o1, bf16* __restrict__ o2,
    const float* __restrict__ q1, const float* __restrict__ qb1,
    const float* __restrict__ k1, const float* __restrict__ kb1,
    const float* __restrict__ v1, const float* __restrict__ vb1,
    float* __restrict__ wcat1, float* __restrict__ bcat1,
    const float* __restrict__ q2, const float* __restrict__ qb2,
    const float* __restrict__ k2, const float* __restrict__ kb2,
    const float* __restrict__ v2, const float* __restrict__ vb2,
    float* __restrict__ wcat2, float* __restrict__ bcat2,
    const float* __restrict__ qq, const float* __restrict__ qqb,
    const float* __restrict__ kk, const float* __restrict__ kkb,
    float* __restrict__ wqk, float* __restrict__ bqk)
{
  long idx = (long)blockIdx.x * 256 + threadIdx.x;
  if (idx < 1179648) {
    const float* in = (idx < 589824) ? cw1 : cw2;
    bf16* out = (idx < 589824) ? o1 : o2;
    long i = (idx < 589824) ? idx : idx - 589824;
    int o = (int)(i / 2304), r = (int)(i % 2304);
    int j = r >> 8, c = r & 255;
    out[i] = __float2bfloat16(in[(o * 256 + c) * 9 + j]);
    return;
  }
  idx -= 1179648;
  const float *wq, *bq, *wk, *bk, *wv, *bv;
  float *wcat, *bcat; int M;
  if (idx < 82240) {
    wq = q1; bq = qb1; wk = k1; bk = kb1; wv = v1; bv = vb1;
    wcat = wcat1; bcat = bcat1; M = 320;
  } else if (idx < 164480) {
    idx -= 82240;
    wq = q2; bq = qb2; wk = k2; bk = kb2; wv = v2; bv = vb2;
    wcat = wcat2; bcat = bcat2; M = 320;
  } else if (idx < 180928) {
    idx -= 164480;
    wq = qq; bq = qqb; wk = kk; bk = kkb; wv = nullptr; bv = nullptr;
    wcat = wqk; bcat = bqk; M = 64;
  } else return;
  int total = M << 8;
  if (idx < total) {
    int r = (int)(idx >> 8), c = (int)(idx & 255);
    float v;
    if (r < 32) v = wq[r * 256 + c];
    else if (r < 64) v = wk[(r - 32) * 256 + c];
    else v = wv[(r - 64) * 256 + c];
    wcat[idx] = v;
  } else if (idx < total + M) {
    int r = (int)(idx - total);
    bcat[r] = (r < 32) ? bq[r] : (r < 64) ? bk[r - 32] : bv[r - 64];
  }
}

// ---- 16-elem row load/store helpers ----------------------------------------
__device__ inline void ld16(const bf16* p, float* v) {
  s8v r0 = *(const s8v*)p, r1 = *(const s8v*)(p + 8);
  const bf16* e0 = (const bf16*)&r0; const bf16* e1 = (const bf16*)&r1;
  #pragma unroll
  for (int j = 0; j < 8; ++j) { v[j] = __bfloat162float(e0[j]); v[8 + j] = __bfloat162float(e1[j]); }
}
__device__ inline void ld16(const float* p, float* v) {
  #pragma unroll
  for (int q = 0; q < 4; ++q) {
    float4 f = *(const float4*)(p + q * 4);
    v[q * 4 + 0] = f.x; v[q * 4 + 1] = f.y; v[q * 4 + 2] = f.z; v[q * 4 + 3] = f.w;
  }
}
__device__ inline void st16(bf16* p, const float* v) {
  s8v o0, o1v; bf16* f0 = (bf16*)&o0; bf16* f1 = (bf16*)&o1v;
  #pragma unroll
  for (int j = 0; j < 8; ++j) { f0[j] = __float2bfloat16(v[j]); f1[j] = __float2bfloat16(v[8 + j]); }
  *(s8v*)p = o0; *(s8v*)(p + 8) = o1v;
}
__device__ inline void st16(float* p, const float* v) {
  #pragma unroll
  for (int q = 0; q < 4; ++q) {
    float4 f; f.x = v[q * 4 + 0]; f.y = v[q * 4 + 1]; f.z = v[q * 4 + 2]; f.w = v[q * 4 + 3];
    *(float4*)(p + q * 4) = f;
  }
}

// ---- fused InstanceNorm: out = inorm(g*a + b) per row of 4096 --------------
template<typename TAe, typename TBe, typename TOe, int G>
__global__ __launch_bounds__(256) void inorm_k(
    const TAe* __restrict__ a, const TBe* __restrict__ b,
    const float* __restrict__ g, TOe* __restrict__ out)
{
  __shared__ float red[8];
  const int tid = threadIdx.x;
  const long base = (long)blockIdx.x * NPIX + tid * 16;
  float gv = G ? *g : 1.f;
  float va[16], vbv[16], v[16];
  ld16(a + base, va);
  ld16(b + base, vbv);
  #pragma unroll
  for (int j = 0; j < 16; ++j) v[j] = gv * va[j] + vbv[j];
  float sum = 0.f, sq = 0.f;
  #pragma unroll
  for (int j = 0; j < 16; ++j) { sum += v[j]; sq += v[j] * v[j]; }
  #pragma unroll
  for (int s = 32; s; s >>= 1) { sum += __shfl_xor(sum, s); sq += __shfl_xor(sq, s); }
  if ((tid & 63) == 0) { red[tid >> 6] = sum; red[4 + (tid >> 6)] = sq; }
  __syncthreads();
  sum = red[0] + red[1] + red[2] + red[3];
  sq  = red[4] + red[5] + red[6] + red[7];
  float mean = sum * (1.f / NPIX);
  float var  = fmaxf(sq * (1.f / NPIX) - mean * mean, 0.f);
  float rstd = rsqrtf(var + 1e-5f);
  float o[16];
  #pragma unroll
  for (int j = 0; j < 16; ++j) o[j] = (v[j] - mean) * rstd;
  st16(out + base, o);
}

// ---- two independent InstanceNorms in one launch (both bf16+float, G=1) ----
__global__ __launch_bounds__(256) void inorm2_k(
    const bf16* __restrict__ a0, const float* __restrict__ b0,
    const float* __restrict__ g0, bf16* __restrict__ o0,
    const bf16* __restrict__ a1, const float* __restrict__ b1,
    const float* __restrict__ g1, bf16* __restrict__ o1)
{
  __shared__ float red[8];
  const int tid = threadIdx.x;
  const int sel = blockIdx.x >> 9;
  const int row = blockIdx.x & 511;
  const bf16* a = sel ? a1 : a0;
  const float* b = sel ? b1 : b0;
  const float* g = sel ? g1 : g0;
  bf16* out = sel ? o1 : o0;
  const long base = (long)row * NPIX + tid * 16;
  float gv = *g;
  float va[16], vbv[16], v[16];
  ld16(a + base, va);
  ld16(b + base, vbv);
  #pragma unroll
  for (int j = 0; j < 16; ++j) v[j] = gv * va[j] + vbv[j];
  float sum = 0.f, sq = 0.f;
  #pragma unroll
  for (int j = 0; j < 16; ++j) { sum += v[j]; sq += v[j] * v[j]; }
  #pragma unroll
  for (int s = 32; s; s >>= 1) { sum += __shfl_xor(sum, s); sq += __shfl_xor(sq, s); }
  if ((tid & 63) == 0) { red[tid >> 6] = sum; red[4 + (tid >> 6)] = sq; }
  __syncthreads();
  sum = red[0] + red[1] + red[2] + red[3];
  sq  = red[4] + red[5] + red[6] + red[7];
  float mean = sum * (1.f / NPIX);
  float var  = fmaxf(sq * (1.f / NPIX) - mean * mean, 0.f);
  float rstd = rsqrtf(var + 1e-5f);
  float o[16];
  #pragma unroll
  for (int j = 0; j < 16; ++j) o[j] = (v[j] - mean) * rstd;
  st16(out + base, o);
}

// ---- host-side helpers ------------------------------------------------------
static const long CN = CNL;

// fused flash attention: CB picked so both launches are 512 blocks (2/CU).
static void attn_core(int nb, bf16* qkv, bf16* qkt, bf16* t0, hipStream_t stream)
{
  if (nb == 4)
    fattn_k<128><<<dim3(64, 2, 4), dim3(512), 0, stream>>>(qkt, qkv + 64 * NPIX, t0);
  else
    fattn_k<64><<<dim3(64, 4, 2), dim3(512), 0, stream>>>(qkt, qkv + 64 * NPIX, t0);
}

static void run_conv(const bf16* src, const bf16* wcvt, const float* cb,
                     bf16* dst, hipStream_t stream)
{
  conv_k<<<dim3(64, 2, 2), dim3(512), 0, stream>>>(src, wcvt, cb, dst);
}

// ---------------------------------------------------------------------------
extern "C" void kernel_launch(void* const* d_in, const int* in_sizes, int n_in,
                              void* d_out, int out_size, void* d_ws, size_t ws_size,
                              hipStream_t stream)
{
  (void)in_sizes; (void)n_in; (void)out_size; (void)ws_size;
  const float* x = (const float*)d_in[0];
  const float* y = (const float*)d_in[1];
  auto W = [&](int i) { return (const float*)d_in[i]; };

  char* wp = (char*)d_ws;
  auto take = [&](size_t nbytes) { char* p = wp; wp += (nbytes + 255) & ~(size_t)255; return p; };
  bf16*  qkv   = (bf16*)take((size_t)4 * QKVSTR * 2);
  bf16*  qkt   = (bf16*)take((size_t)4 * QKTSTR * 2);
  bf16*  t0    = (bf16*)take((size_t)4 * CN * 2);
  bf16*  u1    = (bf16*)take(2 * CN * 2);
  bf16*  u2    = (bf16*)take(2 * CN * 2);
  bf16*  u3    = (bf16*)take(2 * CN * 2);
  bf16*  u4    = (bf16*)take(2 * CN * 2);
  bf16*  wcvt1 = (bf16*)take((size_t)589824 * 2);
  bf16*  wcvt2 = (bf16*)take((size_t)589824 * 2);
  float* wcat1 = (float*)take((size_t)81920 * 4);
  float* bcat1 = (float*)take(320 * 4);
  float* wcat2 = (float*)take((size_t)81920 * 4);
  float* bcat2 = (float*)take(320 * 4);
  float* wqk   = (float*)take((size_t)16384 * 4);
  float* bqk   = (float*)take(64 * 4);
  bf16*  cvout = qkv;                                         // conv out (aliased)

  dim3 TB(256);

  // ---- prep: all weight concat/convert in one launch ----
  prep_k<<<dim3(5315), TB, 0, stream>>>(
      W(23), W(25), wcvt1, wcvt2,
      W(2), W(3), W(4), W(5), W(6), W(7), wcat1, bcat1,
      W(9), W(10), W(11), W(12), W(13), W(14), wcat2, bcat2,
      W(16), W(17), W(18), W(19), wqk, bqk);

  // ---- stages A+B attention together: z = stage*2 + batch ----
  proj_k<1,float><<<dim3(64,5,4), TB, 0, stream>>>(
      wcat1, wcat2, x, y, bcat1, bcat2, qkv, qkt, 320, NPIX, 256, CN, QKVSTR, 8);
  attn_core(4, qkv, qkt, t0, stream);

  // ---- out_1 / out_3 inorms (merged) ----
  inorm2_k<<<dim3(1024), TB, 0, stream>>>(t0, x, W(8), u1,
                                          t0 + 2 * CN, y, W(15), u3);

  // ---- conv1 -> out_2 ----
  run_conv(u1, wcvt1, W(24), cvout, stream);
  inorm_k<bf16,bf16,bf16,0><<<dim3(512), TB, 0, stream>>>(u1, cvout, nullptr, u2);

  // ---- stage C: merged projection (qk from out_2, v from out_3) ----
  projc_k<<<dim3(64, 5, 2), TB, 0, stream>>>(
      wqk, bqk, u2, W(20), W(21), u3, qkv, qkt);
  attn_core(2, qkv, qkt, t0, stream);
  inorm_k<bf16,float,bf16,1><<<dim3(512), TB, 0, stream>>>(t0, y, W(22), u1);   // o1
  inorm_k<bf16,bf16,bf16,0><<<dim3(512), TB, 0, stream>>>(u1, u3, nullptr, u4); // o2
  run_conv(u4, wcvt2, W(26), cvout, stream);
  inorm_k<bf16,bf16,float,0><<<dim3(512), TB, 0, stream>>>(u4, cvout, nullptr, (float*)d_out);
}